// Round 4
// baseline (1511.084 us; speedup 1.0000x reference)
//
#include <hip/hip_runtime.h>
#include <math.h>

#define Bc 2
#define Sc 2048
#define Dc 1024
#define Hc 16
#define HDc 64
#define FPOLY 4160
#define MHID 2048
#define FFNH 2730
#define FFNHP 2752   // FFNH padded to mult of 32 (K pad, zero-filled)
#define GGH 64
#define NTOK 4096
#define NACT 128
#define MCH 2048     // memory-forward M chunk

typedef __bf16 bf16;
typedef __attribute__((ext_vector_type(8))) __bf16 bf16x8;
typedef __attribute__((ext_vector_type(4))) float f32x4;

#define AS1 __attribute__((address_space(1)))
#define AS3 __attribute__((address_space(3)))

__device__ __forceinline__ void gload16(const void* g, void* l) {
    __builtin_amdgcn_global_load_lds((AS1 const void*)g, (AS3 void*)l, 16, 0, 0);
}

__device__ __forceinline__ float fexp2(float x) { return __builtin_amdgcn_exp2f(x); }

// ---------------------------------------------------------------- bf16 MFMA GEMM (LDS, big tiles)
// C = act(alpha*[sptr]*A@Bt^T + beta*Cin).  A:(M,K) bf16 row-major, Bt:(N,K) bf16.
// K%32==0, M%128==0. N arbitrary; Bt rows allocated to ceil(N/128)*128.
// 2-phase stage-ahead pipeline: stage tile k+1 into buf^1 while computing buf; the
// __syncthreads() vmcnt drain then lands AFTER a full compute phase (T3-min recipe).
template<int OUTBF, int CINBF>
__global__ __launch_bounds__(256) void gemm_bt(
    const bf16* __restrict__ A, const bf16* __restrict__ Bt,
    const void* __restrict__ Cin, void* __restrict__ Cout,
    int M, int N, int K, int ldc,
    float alpha, float beta, int act, const float* __restrict__ sptr)
{
    __shared__ bf16 As[2][128 * 32];
    __shared__ bf16 Bs[2][128 * 32];
    const int tid = threadIdx.x;
    const int w = tid >> 6, lane = tid & 63;
    const int bm = blockIdx.y * 128, bn = blockIdx.x * 128;
    const int wm = (w >> 1) * 64, wn = (w & 1) * 64;
    f32x4 acc[4][4];
#pragma unroll
    for (int i = 0; i < 4; ++i)
#pragma unroll
        for (int j = 0; j < 4; ++j) { acc[i][j][0] = 0.f; acc[i][j][1] = 0.f; acc[i][j][2] = 0.f; acc[i][j][3] = 0.f; }
    const int idx0 = tid, idx1 = tid + 256;
    const int r0 = idx0 >> 2, r1 = idx1 >> 2;
    const int g0 = ((idx0 & 3) ^ ((r0 >> 1) & 3)) * 8;
    const int g1 = ((idx1 & 3) ^ ((r1 >> 1) & 3)) * 8;
    const int lrow = lane & 15;
    const int q = lane >> 4;
    int aoff[4], boff[4];
#pragma unroll
    for (int t = 0; t < 4; ++t) {
        int ar = wm + t * 16 + lrow;
        aoff[t] = ar * 32 + ((q ^ ((ar >> 1) & 3)) * 8);
        int br = wn + t * 16 + lrow;
        boff[t] = br * 32 + ((q ^ ((br >> 1) & 3)) * 8);
    }
    const bf16* Arow0 = A + (size_t)(bm + r0) * K + g0;
    const bf16* Arow1 = A + (size_t)(bm + r1) * K + g1;
    const bf16* Brow0 = Bt + (size_t)(bn + r0) * K + g0;
    const bf16* Brow1 = Bt + (size_t)(bn + r1) * K + g1;
    auto stage = [&](int bi, int k0) {
        char* la = (char*)&As[bi][0] + w * 1024;
        char* lb = (char*)&Bs[bi][0] + w * 1024;
        gload16(Arow0 + k0, la);
        gload16(Arow1 + k0, la + 4096);
        gload16(Brow0 + k0, lb);
        gload16(Brow1 + k0, lb + 4096);
    };
    auto compute = [&](int bi) {
        bf16x8 af[4], bfr[4];
#pragma unroll
        for (int t = 0; t < 4; ++t) af[t] = *(const bf16x8*)&As[bi][aoff[t]];
#pragma unroll
        for (int t = 0; t < 4; ++t) bfr[t] = *(const bf16x8*)&Bs[bi][boff[t]];
#pragma unroll
        for (int mt = 0; mt < 4; ++mt)
#pragma unroll
            for (int nt = 0; nt < 4; ++nt)
                acc[mt][nt] = __builtin_amdgcn_mfma_f32_16x16x32_bf16(af[mt], bfr[nt], acc[mt][nt], 0, 0, 0);
    };
    stage(0, 0);
    __syncthreads();
    int buf = 0;
    for (int k0 = 32; k0 < K; k0 += 32) {
        stage(buf ^ 1, k0);     // next tile in flight during compute
        compute(buf);
        __syncthreads();        // drains vmcnt AFTER compute phase
        buf ^= 1;
    }
    compute(buf);
    const float amul = alpha * (sptr ? *sptr : 1.f);
#pragma unroll
    for (int nt = 0; nt < 4; ++nt) {
        const int col = bn + wn + nt * 16 + lrow;
        if (col >= N) continue;
#pragma unroll
        for (int mt = 0; mt < 4; ++mt) {
            const int rbase = bm + wm + mt * 16 + q * 4;
#pragma unroll
            for (int r = 0; r < 4; ++r) {
                const size_t o = (size_t)(rbase + r) * ldc + col;
                float v = amul * acc[mt][nt][r];
                if (beta != 0.f)
                    v += beta * (CINBF ? (float)((const bf16*)Cin)[o] : ((const float*)Cin)[o]);
                if (act == 1) v = v / (1.f + __expf(-v));
                if (OUTBF) ((bf16*)Cout)[o] = (bf16)v;
                else       ((float*)Cout)[o] = v;
            }
        }
    }
}

// ---------------------------------------------------------------- barrier-free direct MFMA GEMM
// Block = 128 rows (4 waves x 32) x 128 cols. Rows beyond M/N must be ALLOCATED readable.
template<int OUTBF, int CINBF>
__global__ __launch_bounds__(256) void gemm_direct(
    const bf16* __restrict__ A, const bf16* __restrict__ Bt,
    const void* __restrict__ Cin, void* __restrict__ Cout,
    int M, int N, int K, int ldc,
    float alpha, float beta, int act, const float* __restrict__ sptr)
{
    const int tid = threadIdx.x, w = tid >> 6, lane = tid & 63;
    const int lrow = lane & 15, quad = lane >> 4;
    const int bm = blockIdx.y * 128 + w * 32;
    const int bn = blockIdx.x * 128;
    f32x4 acc[2][8];
#pragma unroll
    for (int mt = 0; mt < 2; ++mt)
#pragma unroll
        for (int nt = 0; nt < 8; ++nt) { acc[mt][nt][0] = 0.f; acc[mt][nt][1] = 0.f; acc[mt][nt][2] = 0.f; acc[mt][nt][3] = 0.f; }
    const bf16* Abase = A + (size_t)(bm + lrow) * K + quad * 8;
    const bf16* Bbase = Bt + (size_t)(bn + lrow) * K + quad * 8;
#pragma unroll 2
    for (int k0 = 0; k0 < K; k0 += 32) {
        bf16x8 af0 = *(const bf16x8*)(Abase + k0);
        bf16x8 af1 = *(const bf16x8*)(Abase + (size_t)16 * K + k0);
#pragma unroll
        for (int nt = 0; nt < 8; ++nt) {
            bf16x8 bfr = *(const bf16x8*)(Bbase + (size_t)nt * 16 * K + k0);
            acc[0][nt] = __builtin_amdgcn_mfma_f32_16x16x32_bf16(af0, bfr, acc[0][nt], 0, 0, 0);
            acc[1][nt] = __builtin_amdgcn_mfma_f32_16x16x32_bf16(af1, bfr, acc[1][nt], 0, 0, 0);
        }
    }
    const float amul = alpha * (sptr ? *sptr : 1.f);
#pragma unroll
    for (int nt = 0; nt < 8; ++nt) {
        const int col = bn + nt * 16 + lrow;
        if (col >= N) continue;
#pragma unroll
        for (int mt = 0; mt < 2; ++mt) {
            const int rbase = bm + mt * 16 + quad * 4;
#pragma unroll
            for (int r = 0; r < 4; ++r) {
                const int row = rbase + r;
                if (row >= M) continue;
                const size_t o = (size_t)row * ldc + col;
                float v = amul * acc[mt][nt][r];
                if (beta != 0.f)
                    v += beta * (CINBF ? (float)((const bf16*)Cin)[o] : ((const float*)Cin)[o]);
                if (act == 1) v = v / (1.f + __expf(-v));
                if (OUTBF) ((bf16*)Cout)[o] = (bf16)v;
                else       ((float*)Cout)[o] = v;
            }
        }
    }
}

// ---------------------------------------------------------------- split-K direct GEMM
// part[z] = A @ Bt^T over K-chunk z (KC wide, KC%32==0). fp32 partials, no epilogue.
__global__ __launch_bounds__(256) void gemm_skp(
    const bf16* __restrict__ A, const bf16* __restrict__ Bt,
    float* __restrict__ part, int M, int N, int K, int KC)
{
    const int tid = threadIdx.x, w = tid >> 6, lane = tid & 63;
    const int lrow = lane & 15, quad = lane >> 4;
    const int bm = blockIdx.y * 128 + w * 32;
    const int bn = blockIdx.x * 128;
    const int z = blockIdx.z;
    const int kb = z * KC;
    int ke = kb + KC; if (ke > K) ke = K;
    f32x4 acc[2][8];
#pragma unroll
    for (int mt = 0; mt < 2; ++mt)
#pragma unroll
        for (int nt = 0; nt < 8; ++nt) { acc[mt][nt][0] = 0.f; acc[mt][nt][1] = 0.f; acc[mt][nt][2] = 0.f; acc[mt][nt][3] = 0.f; }
    const bf16* Abase = A + (size_t)(bm + lrow) * K + quad * 8;
    const bf16* Bbase = Bt + (size_t)(bn + lrow) * K + quad * 8;
#pragma unroll 2
    for (int k0 = kb; k0 < ke; k0 += 32) {
        bf16x8 af0 = *(const bf16x8*)(Abase + k0);
        bf16x8 af1 = *(const bf16x8*)(Abase + (size_t)16 * K + k0);
#pragma unroll
        for (int nt = 0; nt < 8; ++nt) {
            bf16x8 bfr = *(const bf16x8*)(Bbase + (size_t)nt * 16 * K + k0);
            acc[0][nt] = __builtin_amdgcn_mfma_f32_16x16x32_bf16(af0, bfr, acc[0][nt], 0, 0, 0);
            acc[1][nt] = __builtin_amdgcn_mfma_f32_16x16x32_bf16(af1, bfr, acc[1][nt], 0, 0, 0);
        }
    }
    float* po = part + (size_t)z * M * N;
#pragma unroll
    for (int nt = 0; nt < 8; ++nt) {
        const int col = bn + nt * 16 + lrow;
        if (col >= N) continue;
#pragma unroll
        for (int mt = 0; mt < 2; ++mt) {
            const int rbase = bm + mt * 16 + quad * 4;
#pragma unroll
            for (int r = 0; r < 4; ++r) {
                const int row = rbase + r;
                if (row >= M) continue;
                po[(size_t)row * N + col] = acc[mt][nt][r];
            }
        }
    }
}

__global__ void skred(const float* __restrict__ part, float* __restrict__ out,
                      int SK, int MN)
{
    int i = blockIdx.x * 256 + threadIdx.x;
    if (i >= MN) return;
    float s = 0.f;
    for (int z = 0; z < SK; ++z) s += part[(size_t)z * MN + i];
    out[i] = s;
}

// ---------------------------------------------------------------- polynomial-kernel gram
// S = G + G^2/64 where G = za@za^T, za (128x64) fp32. phi(x).phi(y) = x.y + (x.y)^2/64.
__global__ __launch_bounds__(256) void gram_trick(
    const float* __restrict__ za, float* __restrict__ S)
{
    __shared__ float z[128 * 65];
    for (int i = threadIdx.x; i < 8192; i += 256) {
        int r = i >> 6, d = i & 63;
        z[r * 65 + d] = za[i];
    }
    __syncthreads();
    for (int idx = threadIdx.x; idx < 16384; idx += 256) {
        int i = idx >> 7, j = idx & 127;
        float dot = 0.f;
#pragma unroll
        for (int d = 0; d < 64; ++d) dot += z[i * 65 + d] * z[j * 65 + d];
        S[idx] = dot + dot * dot * 0.015625f;
    }
}

// per-batch: n2 = <S[z],C[z]>; Cb=bf16(C/n2); Sb=bf16(S); invn[z] = 1/(sqrt(n2)+1e-7)
__global__ __launch_bounds__(256) void ns_norm_kernel(
    const float* __restrict__ S, const float* __restrict__ C,
    bf16* __restrict__ Sb, bf16* __restrict__ Cb, float* __restrict__ invn)
{
    const int z = blockIdx.x;
    const float* s = S + (size_t)z * 16384;
    const float* c = C + (size_t)z * 16384;
    float acc = 0.f;
    for (int i = threadIdx.x; i < 16384; i += 256) acc += s[i] * c[i];
    __shared__ float red[256];
    red[threadIdx.x] = acc; __syncthreads();
    for (int st = 128; st; st >>= 1) {
        if (threadIdx.x < st) red[threadIdx.x] += red[threadIdx.x + st];
        __syncthreads();
    }
    float inv = 1.f / (sqrtf(red[0]) + 1e-7f);
    float inv2 = inv * inv;
    for (int i = threadIdx.x; i < 16384; i += 256) {
        Cb[(size_t)z * 16384 + i] = (bf16)(c[i] * inv2);
        Sb[(size_t)z * 16384 + i] = (bf16)s[i];
    }
    if (threadIdx.x == 0) invn[z] = inv;
}

// ---------------------------------------------------------------- fused Newton-Schulz (batched z=3)
__device__ __forceinline__ int swz(int row, int col) {
    return row * 128 + ((((col >> 3) ^ (row & 7)) << 3) | (col & 7));
}

__global__ __launch_bounds__(256) void ns_fused(
    const bf16* __restrict__ Sg, const bf16* __restrict__ Cg,
    bf16* __restrict__ Fcg, bf16* __restrict__ FcTg)
{
    __shared__ bf16 Cl[16384], Ml[16384], MTl[16384], FTl[16384];
    const int z = blockIdx.x;
    const bf16* S = Sg + (size_t)z * 16384;
    bf16* Fc = Fcg + (size_t)z * 16384;
    bf16* FcT = FcTg + (size_t)z * 16384;
    const int tid = threadIdx.x, w = tid >> 6, lane = tid & 63;
    const int lrow = lane & 15, quad = lane >> 4;
    const int bm = w * 32;
    for (int i = tid; i < 2048; i += 256) {
        const int row = i >> 4, c = i & 15;
        *(bf16x8*)&Cl[row * 128 + ((c ^ (row & 7)) << 3)] =
            *(const bf16x8*)(Cg + (size_t)z * 16384 + (size_t)row * 128 + c * 8);
    }
    __syncthreads();
    const int r0 = bm + lrow, r1 = r0 + 16;
    const int rx = lrow & 7;
    f32x4 acc[2][8];
    auto zacc = [&]() {
#pragma unroll
        for (int mt = 0; mt < 2; ++mt)
#pragma unroll
            for (int nt = 0; nt < 8; ++nt) { acc[mt][nt][0] = 0.f; acc[mt][nt][1] = 0.f; acc[mt][nt][2] = 0.f; acc[mt][nt][3] = 0.f; }
    };
    auto inner = [&](bf16x8 af0, bf16x8 af1, const bf16* Bt, int c) {
#pragma unroll
        for (int nt = 0; nt < 8; ++nt) {
            const int br = nt * 16 + lrow;
            bf16x8 bfr = *(const bf16x8*)&Bt[br * 128 + ((c ^ (br & 7)) << 3)];
            acc[0][nt] = __builtin_amdgcn_mfma_f32_16x16x32_bf16(af0, bfr, acc[0][nt], 0, 0, 0);
            acc[1][nt] = __builtin_amdgcn_mfma_f32_16x16x32_bf16(af1, bfr, acc[1][nt], 0, 0, 0);
        }
    };
    auto gemm_ll = [&](const bf16* Al, const bf16* Bt) {
        zacc();
#pragma unroll
        for (int k0 = 0; k0 < 128; k0 += 32) {
            const int c = (k0 >> 3) + quad;
            bf16x8 af0 = *(const bf16x8*)&Al[r0 * 128 + ((c ^ rx) << 3)];
            bf16x8 af1 = *(const bf16x8*)&Al[r1 * 128 + ((c ^ rx) << 3)];
            inner(af0, af1, Bt, c);
        }
    };
    auto gemm_gl = [&](const bf16* Ag, const bf16* Bt) {
        zacc();
#pragma unroll
        for (int k0 = 0; k0 < 128; k0 += 32) {
            const int c = (k0 >> 3) + quad;
            bf16x8 af0 = *(const bf16x8*)(Ag + (size_t)r0 * 128 + k0 + quad * 8);
            bf16x8 af1 = *(const bf16x8*)(Ag + (size_t)r1 * 128 + k0 + quad * 8);
            inner(af0, af1, Bt, c);
        }
    };

    for (int t = 0; t < 5; ++t) {
        gemm_gl(S, Cl);
#pragma unroll
        for (int mt = 0; mt < 2; ++mt)
#pragma unroll
            for (int nt = 0; nt < 8; ++nt)
#pragma unroll
                for (int r = 0; r < 4; ++r) {
                    const int row = bm + mt * 16 + quad * 4 + r, col = nt * 16 + lrow;
                    const bf16 v = (bf16)acc[mt][nt][r];
                    Ml[swz(row, col)] = v;
                    MTl[swz(col, row)] = v;
                }
        __syncthreads();
        gemm_ll(Ml, MTl);
#pragma unroll
        for (int mt = 0; mt < 2; ++mt)
#pragma unroll
            for (int nt = 0; nt < 8; ++nt)
#pragma unroll
                for (int r = 0; r < 4; ++r) {
                    const int row = bm + mt * 16 + quad * 4 + r, col = nt * 16 + lrow;
                    float v = 2.0315f * acc[mt][nt][r] - 4.775f * (float)Ml[swz(row, col)];
                    if (row == col) v += 3.4445f;
                    FTl[swz(col, row)] = (bf16)v;
                    if (t == 0) Fc[(size_t)row * 128 + col] = (bf16)v;
                }
        __syncthreads();
        if (t > 0) {
            gemm_gl(Fc, FTl);
            if (t == 4) {
#pragma unroll
                for (int mt = 0; mt < 2; ++mt)
#pragma unroll
                    for (int nt = 0; nt < 8; ++nt)
#pragma unroll
                        for (int r = 0; r < 4; ++r) {
                            const int row = bm + mt * 16 + quad * 4 + r, col = nt * 16 + lrow;
                            FcT[(size_t)col * 128 + row] = (bf16)acc[mt][nt][r];
                        }
                return;
            }
#pragma unroll
            for (int mt = 0; mt < 2; ++mt)
#pragma unroll
                for (int nt = 0; nt < 8; ++nt)
#pragma unroll
                    for (int r = 0; r < 4; ++r) {
                        const int row = bm + mt * 16 + quad * 4 + r, col = nt * 16 + lrow;
                        Fc[(size_t)row * 128 + col] = (bf16)acc[mt][nt][r];
                    }
        }
        gemm_ll(Cl, FTl);
#pragma unroll
        for (int mt = 0; mt < 2; ++mt)
#pragma unroll
            for (int nt = 0; nt < 8; ++nt)
#pragma unroll
                for (int r = 0; r < 4; ++r) {
                    const int row = bm + mt * 16 + quad * 4 + r, col = nt * 16 + lrow;
                    Ml[swz(col, row)] = (bf16)acc[mt][nt][r];
                }
        __syncthreads();
        gemm_ll(Ml, FTl);
#pragma unroll
        for (int mt = 0; mt < 2; ++mt)
#pragma unroll
            for (int nt = 0; nt < 8; ++nt)
#pragma unroll
                for (int r = 0; r < 4; ++r) {
                    const int row = bm + mt * 16 + quad * 4 + r, col = nt * 16 + lrow;
                    Cl[swz(row, col)] = (bf16)acc[mt][nt][r];
                }
        __syncthreads();
    }
}

// ---------------------------------------------------------------- converts
__global__ __launch_bounds__(256) void tconv_kernel(
    const float* __restrict__ W, bf16* __restrict__ Wt, int K, int N, int Kpad)
{
    __shared__ float t[32][33];
    const int k0 = blockIdx.x * 32, n0 = blockIdx.y * 32;
    const int tx = threadIdx.x & 31, ty = threadIdx.x >> 5;
#pragma unroll
    for (int r = 0; r < 4; ++r) {
        int gk = k0 + ty + r * 8, gn = n0 + tx;
        t[ty + r * 8][tx] = (gk < K && gn < N) ? W[(size_t)gk * N + gn] : 0.f;
    }
    __syncthreads();
#pragma unroll
    for (int r = 0; r < 4; ++r) {
        int gn = n0 + ty + r * 8, gk = k0 + tx;
        if (gn < N && gk < Kpad) Wt[(size_t)gn * Kpad + gk] = (bf16)t[tx][ty + r * 8];
    }
}

__global__ void cvt_kernel(const float* __restrict__ in, bf16* __restrict__ out, int n)
{
    for (int i = blockIdx.x * 256 + threadIdx.x; i < n; i += gridDim.x * 256)
        out[i] = (bf16)in[i];
}

// vb (b,s,h,d) -> vt (b,h,d,s)
__global__ __launch_bounds__(256) void vtrans_kernel(
    const bf16* __restrict__ vb, bf16* __restrict__ vt)
{
    __shared__ bf16 t[32][33];
    const int s0 = blockIdx.x * 32, d0 = blockIdx.y * 32, bh = blockIdx.z;
    const int b = bh >> 4, h = bh & 15;
    const int tx = threadIdx.x & 31, ty = threadIdx.x >> 5;
#pragma unroll
    for (int r = 0; r < 4; ++r) {
        int s = s0 + ty + r * 8;
        t[ty + r * 8][tx] = vb[((size_t)b * Sc + s) * Dc + h * 64 + d0 + tx];
    }
    __syncthreads();
#pragma unroll
    for (int r = 0; r < 4; ++r) {
        int d = d0 + ty + r * 8;
        vt[((size_t)bh * 64 + d) * Sc + s0 + tx] = t[tx][ty + r * 8];
    }
}

// ---------------------------------------------------------------- small kernels
__global__ __launch_bounds__(256) void rms_rows(
    const float* __restrict__ in, const float* __restrict__ w,
    bf16* __restrict__ out, int D)
{
    const int row = blockIdx.x;
    const float* r = in + (size_t)row * D;
    bf16* o = out + (size_t)row * D;
    float s = 0.f;
    for (int i = threadIdx.x; i < D; i += 256) { float v = r[i]; s += v * v; }
    __shared__ float red[256];
    red[threadIdx.x] = s;
    __syncthreads();
    for (int st = 128; st; st >>= 1) {
        if (threadIdx.x < st) red[threadIdx.x] += red[threadIdx.x + st];
        __syncthreads();
    }
    float rs = rsqrtf(red[0] / (float)D + 1e-6f);
    for (int i = threadIdx.x; i < D; i += 256) o[i] = (bf16)(r[i] * rs * w[i]);
}

__global__ __launch_bounds__(256) void gamma_kernel(
    const float* __restrict__ gg1, const float* __restrict__ w2,
    float* __restrict__ gamma)
{
    const int tid = threadIdx.x, w = tid >> 6, lane = tid & 63;
    const int t = blockIdx.x * 4 + w;
    float v = gg1[(size_t)t * GGH + lane];
    v = v / (1.f + expf(-v));
    v *= w2[lane];
#pragma unroll
    for (int off = 32; off; off >>= 1) v += __shfl_xor(v, off);
    if (lane == 0) gamma[t] = 1.f / (1.f + expf(-v));
}

__global__ __launch_bounds__(256) void snr_one(
    const bf16* __restrict__ src, const float* __restrict__ w,
    bf16* __restrict__ dst)
{
    const int tid = threadIdx.x, wv = tid >> 6, lane = tid & 63;
    const int s = blockIdx.x * 4 + wv;
    const int h = blockIdx.y, b = blockIdx.z;
    const size_t row = ((size_t)b * Sc + s) * Dc + h * 64;
    float v = (float)src[row + lane];
    float ss = v * v;
#pragma unroll
    for (int off = 32; off; off >>= 1) ss += __shfl_xor(ss, off);
    v = v * rsqrtf(ss / 64.f + 1e-6f) * w[lane];
    const int j = lane & 31;
    float inv = powf(10000.f, -(float)j / 32.f);
    float ang = (float)s * inv;
    float sn = sinf(ang), cs = cosf(ang);
    float p = __shfl_xor(v, 32);
    float o;
    if (lane < 32) o = v * cs - p * sn;
    else           o = p * sn + v * cs;
    const size_t od = (((size_t)b * Hc + h) * Sc + s) * 64 + lane;
    dst[od] = (bf16)o;
}

__global__ void kpsum_kernel(const bf16* __restrict__ kn, float* __restrict__ psum)
{
    const int bh = blockIdx.x, c = blockIdx.y, d = threadIdx.x;
    const size_t base = (size_t)bh * Sc * 64 + (size_t)c * 128 * 64 + d;
    float s = 0.f;
    for (int i = 0; i < 128; ++i) s += (float)kn[base + (size_t)i * 64];
    psum[((size_t)bh * 16 + c) * 64 + d] = s;
}

__global__ void qmem2_kernel(
    const bf16* __restrict__ qn, const bf16* __restrict__ kn,
    const float* __restrict__ gamma, const float* __restrict__ psum,
    float* __restrict__ qmem)
{
    const int bh = blockIdx.x, c = blockIdx.y;
    const int b = bh >> 4, hh = bh & 15;
    const int d = threadIdx.x;
    const size_t base = (size_t)bh * Sc * 64;
    float run = 0.f;
    for (int cc = 0; cc < c; ++cc) run += psum[((size_t)bh * 16 + cc) * 64 + d];
    for (int s = c * 128; s < c * 128 + 128; ++s) {
        run += (float)kn[base + (size_t)s * 64 + d];
        float cm = run / (float)(s + 1);
        float g = gamma[b * Sc + s];
        float qv = (float)qn[base + (size_t)s * 64 + d];
        qmem[((size_t)(b * Sc + s)) * Dc + hh * 64 + d] = g * qv + (1.f - g) * cm;
    }
}

// ---------------------------------------------------------------- MFMA flash attention
// 32-row Q tiles, pairs (z, 63-z) sequential; 4 waves cooperate via 2-way k-parity
// split of 128-wide chunks. FIXED-BOUND softmax: q,k are per-head RMS-normalized so
// |score*0.125*log2e| < 11.55 -> p = exp2(s*SC - 12) needs NO online max, NO per-chunk
// reductions, NO oacc rescale. Lane-partial sums accumulate in regs; one 16-lane
// reduce per tile at the end; parity merge = simple add (same fixed max).
__global__ __launch_bounds__(256, 4) void attn_mfma(
    const bf16* __restrict__ qn, const bf16* __restrict__ kn,
    const bf16* __restrict__ vt, bf16* __restrict__ outp)
{
    const int h = blockIdx.y, b = blockIdx.z;
    const int bh = b * Hc + h;
    const int tid = threadIdx.x, w = tid >> 6, lane = tid & 63;
    const int lrow = lane & 15, quad = lane >> 4;
    const int rhalf = w & 1, pgrp = w >> 1;
    __shared__ bf16 Ps[4][16][136];
    __shared__ float Ob[2][16][68];
    __shared__ float Lb[2][16];
    const bf16* kbase = kn + (size_t)bh * Sc * 64;
    const bf16* vtb = vt + (size_t)bh * 64 * Sc;
    const float SC = 0.1803368801f;   // 0.125 * log2(e)
#pragma unroll 1
    for (int ti = 0; ti < 2; ++ti) {
        const int zt = ti ? (63 - blockIdx.x) : blockIdx.x;
        const int qb = zt * 32;
        const int nc = (qb >> 7) + 1;         // # of 128-wide k-chunks (causal)
        const int par = pgrp ^ ti;            // this wave's chunk parity
        const int rowg = qb + rhalf * 16 + quad * 4;   // +r = global row
        bf16x8 qf[2];
        const bf16* qbase = qn + ((size_t)bh * Sc + qb + rhalf * 16) * 64;
#pragma unroll
        for (int ks = 0; ks < 2; ++ks)
            qf[ks] = *(const bf16x8*)(qbase + (size_t)lrow * 64 + ks * 32 + quad * 8);
        f32x4 oacc[4];
#pragma unroll
        for (int nt = 0; nt < 4; ++nt) { oacc[nt][0] = 0.f; oacc[nt][1] = 0.f; oacc[nt][2] = 0.f; oacc[nt][3] = 0.f; }
        float lsum[4] = {0.f, 0.f, 0.f, 0.f};
        for (int ci = par; ci < nc; ci += 2) {
            const int k0 = ci << 7;
            f32x4 sacc[8];
#pragma unroll
            for (int nt = 0; nt < 8; ++nt) { sacc[nt][0] = 0.f; sacc[nt][1] = 0.f; sacc[nt][2] = 0.f; sacc[nt][3] = 0.f; }
            __builtin_amdgcn_s_setprio(1);
#pragma unroll
            for (int ks = 0; ks < 2; ++ks) {
#pragma unroll
                for (int nh = 0; nh < 2; ++nh) {
                    bf16x8 kf[4];
#pragma unroll
                    for (int j = 0; j < 4; ++j)
                        kf[j] = *(const bf16x8*)(kbase + (size_t)(k0 + (nh * 4 + j) * 16 + lrow) * 64 + ks * 32 + quad * 8);
#pragma unroll
                    for (int j = 0; j < 4; ++j)
                        sacc[nh * 4 + j] = __builtin_amdgcn_mfma_f32_16x16x32_bf16(qf[ks], kf[j], sacc[nh * 4 + j], 0, 0, 0);
                }
            }
            __builtin_amdgcn_s_setprio(0);
            // fixed-bound softmax weights + causal mask; lane-partial sums
#pragma unroll
            for (int nt = 0; nt < 8; ++nt) {
                const int kc = k0 + nt * 16 + lrow;
#pragma unroll
                for (int r = 0; r < 4; ++r) {
                    float p = (kc > rowg + r) ? 0.f : fexp2(fmaf(sacc[nt][r], SC, -12.f));
                    sacc[nt][r] = p;
                    lsum[r] += p;
                }
            }
#pragma unroll
            for (int nt = 0; nt < 8; ++nt)
#pragma unroll
                for (int r = 0; r < 4; ++r)
                    Ps[w][quad * 4 + r][nt * 16 + lrow] = (bf16)sacc[nt][r];
            __builtin_amdgcn_s_setprio(1);
#pragma unroll
            for (int ks2 = 0; ks2 < 4; ++ks2) {
                bf16x8 pf = *(const bf16x8*)&Ps[w][lrow][ks2 * 32 + quad * 8];
#pragma unroll
                for (int nt = 0; nt < 4; ++nt) {
                    bf16x8 vf = *(const bf16x8*)(vtb + (size_t)(nt * 16 + lrow) * Sc + k0 + ks2 * 32 + quad * 8);
                    oacc[nt] = __builtin_amdgcn_mfma_f32_16x16x32_bf16(pf, vf, oacc[nt], 0, 0, 0);
                }
            }
            __builtin_amdgcn_s_setprio(0);
        }
        // one 16-lane reduce per tile for the row sums
#pragma unroll
        for (int r = 0; r < 4; ++r)
#pragma unroll
            for (int off = 1; off < 16; off <<= 1) lsum[r] += __shfl_xor(lsum[r], off);
        // merge parity partials: plain add (same fixed max for both)
        if (pgrp == 1) {
#pragma unroll
            for (int nt = 0; nt < 4; ++nt)
#pragma unroll
                for (int r = 0; r < 4; ++r)
                    Ob[rhalf][quad * 4 + r][nt * 16 + lrow] = oacc[nt][r];
            if (lrow == 0)
#pragma unroll
                for (int r = 0; r < 4; ++r) Lb[rhalf][quad * 4 + r] = lsum[r];
        }
        __syncthreads();
        if (pgrp == 0) {
            float linv[4];
#pragma unroll
            for (int r = 0; r < 4; ++r)
                linv[r] = 1.f / (lsum[r] + Lb[rhalf][quad * 4 + r]);
#pragma unroll
            for (int nt = 0; nt < 4; ++nt)
#pragma unroll
                for (int r = 0; r < 4; ++r) {
                    const float o2 = Ob[rhalf][quad * 4 + r][nt * 16 + lrow];
                    outp[((size_t)b * Sc + rowg + r) * Dc + h * 64 + nt * 16 + lrow] =
                        (bf16)((oacc[nt][r] + o2) * linv[r]);
                }
        }
        __syncthreads();
    }
}

__global__ __launch_bounds__(256) void gather_active(
    const float* __restrict__ qmem, const bf16* __restrict__ vbuf,
    float* __restrict__ xa, bf16* __restrict__ xab, float* __restrict__ va)
{
    const int t = blockIdx.x;
    const int b = t >> 6;
    const int s = Sc - 64 + (t & 63);
    const float* qrow = qmem + ((size_t)(b * Sc + s)) * Dc;
    const bf16* vrow = vbuf + ((size_t)(b * Sc + s)) * Dc;
    for (int i = threadIdx.x; i < Dc; i += 256) {
        float q = qrow[i];
        xa[(size_t)t * Dc + i] = q;
        xab[(size_t)t * Dc + i] = (bf16)q;
        va[(size_t)t * Dc + i] = (float)vrow[i];
    }
}

__global__ void wvec_kernel(const float* __restrict__ gamma,
                            float* __restrict__ wvec, float* __restrict__ wsum)
{
    const int t = threadIdx.x;
    const int b = t >> 6, si = t & 63;
    const int s = Sc - 64 + si;
    float v = gamma[b * Sc + s] * powf(0.95f, (float)(Sc - 1 - s));
    wvec[t] = v;
    __shared__ float red[128];
    red[t] = v; __syncthreads();
    for (int st = 64; st; st >>= 1) { if (t < st) red[t] += red[t + st]; __syncthreads(); }
    if (t == 0) wsum[0] = red[0];
}

__global__ __launch_bounds__(256) void phi2_f32(
    const float* __restrict__ z, float* __restrict__ feat, bf16* __restrict__ featb)
{
    const int f = blockIdx.x * 256 + threadIdx.x;
    const int t = blockIdx.y;
    if (f >= FPOLY) return;
    const float* zr = z + (size_t)t * 64;
    float v;
    if (f < 64) v = zr[f];
    else { int i = (f - 64) >> 6, j = (f - 64) & 63; v = zr[i] * zr[j] * 0.125f; }
    feat[(size_t)t * FPOLY + f] = v;
    featb[(size_t)t * FPOLY + f] = (bf16)v;
}

__global__ __launch_bounds__(256) void phi2_bf16(
    const float* __restrict__ z, bf16* __restrict__ feat)
{
    const int f = blockIdx.x * 256 + threadIdx.x;
    const int t = blockIdx.y;
    if (f >= FPOLY) return;
    const float* zr = z + (size_t)t * 64;
    float v;
    if (f < 64) v = zr[f];
    else { int i = (f - 64) >> 6, j = (f - 64) & 63; v = zr[i] * zr[j] * 0.125f; }
    feat[(size_t)t * FPOLY + f] = (bf16)v;
}

__global__ void silu_kernel(const float* __restrict__ in, float* __restrict__ out,
                            bf16* __restrict__ outb, int n)
{
    int i = blockIdx.x * 256 + threadIdx.x;
    if (i < n) {
        float v = in[i];
        float s = v / (1.f + expf(-v));
        out[i] = s; outb[i] = (bf16)s;
    }
}

__global__ void dpred_kernel(const float* __restrict__ pred, const float* __restrict__ va,
                             const float* __restrict__ wvec, const float* __restrict__ wsum,
                             float* __restrict__ dpred, bf16* __restrict__ dpredb)
{
    int i = blockIdx.x * 256 + threadIdx.x;
    if (i < NACT * Dc) {
        int t = i >> 10;
        float v = 2.f * wvec[t] / (wsum[0] + 1e-8f) * (pred[i] - va[i]);
        dpred[i] = v; dpredb[i] = (bf16)v;
    }
}

__global__ void dsilu_kernel(const float* __restrict__ dsu, const float* __restrict__ u,
                             float* __restrict__ du, bf16* __restrict__ dub, int n)
{
    int i = blockIdx.x * 256 + threadIdx.x;
    if (i < n) {
        float uv = u[i];
        float sg = 1.f / (1.f + expf(-uv));
        float v = dsu[i] * sg * (1.f + uv * (1.f - sg));
        du[i] = v; dub[i] = (bf16)v;
    }
}

__global__ void dz_kernel(const float* __restrict__ dfeat, const float* __restrict__ za,
                          float* __restrict__ dz, bf16* __restrict__ dzb)
{
    const int t = blockIdx.x;
    const int k = threadIdx.x;
    const float* df = dfeat + (size_t)t * FPOLY;
    const float* z = za + (size_t)t * 64;
    float s1 = 0.f, s2 = 0.f;
    for (int j = 0; j < 64; ++j) {
        float zj = z[j];
        s1 += df[64 + k * 64 + j] * zj;
        s2 += df[64 + j * 64 + k] * zj;
    }
    float v = df[k] + 0.125f * (s1 + s2);
    dz[(size_t)t * 64 + k] = v;
    dzb[(size_t)t * 64 + k] = (bf16)v;
}

__global__ void sgate_kernel(const float* __restrict__ mg, float* __restrict__ out)
{
    out[0] = 1.f / (1.f + expf(-mg[0]));
}

__global__ void mulpad_kernel(bf16* __restrict__ a, const bf16* __restrict__ b)
{
    int i = blockIdx.x * 256 + threadIdx.x;
    if (i >= NTOK * FFNHP) return;
    int k = i % FFNHP;
    if (k >= FFNH) { a[i] = (bf16)0.f; return; }
    a[i] = (bf16)((float)a[i] * (float)b[i]);
}

// ---------------------------------------------------------------- launch
extern "C" void kernel_launch(void* const* d_in, const int* in_sizes, int n_in,
                              void* d_out, int out_size, void* d_ws, size_t ws_size,
                              hipStream_t stream)
{
    const float* x     = (const float*)d_in[0];
    const float* n1w   = (const float*)d_in[1];
    const float* n2w   = (const float*)d_in[2];
    const float* qkvw  = (const float*)d_in[3];
    const float* qnw   = (const float*)d_in[4];
    const float* knw   = (const float*)d_in[5];
    const float* gw1   = (const float*)d_in[6];
    const float* gw2   = (const float*)d_in[7];
    const float* mwk   = (const float*)d_in[8];
    const float* mw1   = (const float*)d_in[9];
    const float* mw2   = (const float*)d_in[10];
    const float* mgate = (const float*)d_in[11];
    const float* wow   = (const float*)d_in[12];
    const float* fw1   = (const float*)d_in[13];
    const float* fw2   = (const float*)d_in[14];
    const float* fw3   = (const float*)d_in[15];
    float* outp = (float*)d_out;

    char* base = (char*)d_ws;
    size_t off = 0;
    auto takeB = [&](size_t bytes) { char* p = base + off; off += (bytes + 255) & ~(size_t)255; return p; };

    // slabs (liveness-overlaid)
    char* slabA  = takeB(22544384);  // partials (stages 2,5,6) / vt (stage 3) -> featC -> ff1b
    char* slabBC = takeB(16777216);  // qnb+knb -> x2 fp32
    char* slabD  = takeB(8388608);   // vb -> t1b
    char* slabE  = takeB(22544384);  // qmem fp32 (16.8M) -> ff3b (22.5M)
    char* slabF  = takeB(8388608);   // qtb -> attnb -> qmemb
    char* slabG  = takeB(17301504);  // hb (8.4M) -> mw1b (17.3M, 4224 rows) -> w1uT (17.04M) -> h2b
    float* partA = (float*)slabA;
    bf16* vt    = (bf16*)slabA;  bf16* featC = (bf16*)slabA;  bf16* ff1b = (bf16*)slabA;
    bf16* qnb = (bf16*)slabBC;   bf16* knb = (bf16*)(slabBC + 8388608);
    float* x2 = (float*)slabBC;
    bf16* vb = (bf16*)slabD;     bf16* t1b = (bf16*)slabD;
    float* qmem = (float*)slabE; bf16* ff3b = (bf16*)slabE;
    bf16* qtb = (bf16*)slabF;    bf16* attnb = (bf16*)slabF;  bf16* qmemb = (bf16*)slabF;
    bf16* hb = (bf16*)slabG;     bf16* mw1b = (bf16*)slabG;
    bf16* w1uT = (bf16*)slabG;   bf16* h2b = (bf16*)slabG;

    // bf16 weights
    bf16* qkvwT = (bf16*)takeB(6291456);
    bf16* gw1T  = (bf16*)takeB(262144);    // 128 rows alloc / 64 real
    bf16* wowT  = (bf16*)takeB(2097152);
    bf16* mw1T  = (bf16*)takeB(17039360);
    bf16* mw2T  = (bf16*)takeB(4194304);
    bf16* fw1T  = (bf16*)takeB(5767168);
    bf16* fw3T  = (bf16*)takeB(5767168);
    bf16* fw2T  = (bf16*)takeB(5636096);
    bf16* mw2b  = (bf16*)takeB(4194304);   // straight copy (2048,1024)
    bf16* mwkTb = (bf16*)takeB(262144);    // (64 real/128 alloc, 1024)
    bf16* wkuTb = (bf16*)takeB(262144);
    bf16* w2uT  = (bf16*)takeB(4194304);   // (1024, 2048)

    // fp32 misc
    float* zf    = (float*)takeB(1048576);
    float* gg1   = (float*)takeB(1048576);
    float* gamma = (float*)takeB(16384);
    float* wvec  = (float*)takeB(512);
    float* scal  = (float*)takeB(256);     // [0]=wsum [2]=sig(gate) [8..10]=invn
    float* psum  = (float*)takeB(131072);
    float* xa    = (float*)takeB(524288);
    float* va    = (float*)takeB(524288);
    float* za    = (float*)takeB(32768);
    float* featA = (float*)takeB(2129920);
    float* ua    = (float*)takeB(1048576);
    float* sua   = (float*)takeB(1048576);
    float* preda = (float*)takeB(524288);
    float* dpreda= (float*)takeB(524288);
    float* dsua  = (float*)takeB(1048576);
    float* dua   = (float*)takeB(1048576);
    float* dfeata= (float*)takeB(2129920);
    float* dza   = (float*)takeB(32768);
    float* SA    = (float*)takeB(196608);  // 3 x 128x128 fp32
    float* CA    = (float*)takeB(196608);
    // bf16 misc
    bf16* featAb = (bf16*)takeB(1064960);
    bf16* suab   = (bf16*)takeB(524288);
    bf16* xab    = (bf16*)takeB(262144);
    bf16* duab   = (bf16*)takeB(524288);
    bf16* dpredab= (bf16*)takeB(262144);
    bf16* dzab   = (bf16*)takeB(16384);
    bf16* PT1Tb  = (bf16*)takeB(524288);   // (2048,128) = P5 for w1
    bf16* PT2Tb  = (bf16*)takeB(262144);   // (1024,128) = P5 for w2
    bf16* PT3Tb  = (bf16*)takeB(32768);
    bf16* duaTb  = (bf16*)takeB(524288);
    bf16* dpredaTb=(bf16*)takeB(262144);
    bf16* dzaTb  = (bf16*)takeB(32768);
    bf16* xaTb   = (bf16*)takeB(262144);
    bf16* featATb= (bf16*)takeB(1081344);  // (4224 alloc/4160 real, 128)
    bf16* suaTb  = (bf16*)takeB(524288);   // (2048, 128)
    // NS bf16
    bf16* Sb16  = (bf16*)takeB(98304);
    bf16* Cb16  = (bf16*)takeB(98304);
    bf16* FcAb  = (bf16*)takeB(98304);     // Fc cumulative (global ping for ns_fused)
    bf16* FcTAb = (bf16*)takeB(98304);     // final Fc^T (consumed by P5 gdirs)

    auto gemmB = [&](int outbf, int cinbf, const bf16* A, const bf16* Bt,
                     const void* Cin, void* C, int M, int N, int K, int ldc,
                     float alpha, float beta, int act, const float* sptr) {
        dim3 grid((N + 127) / 128, M / 128);
        if (outbf && cinbf) gemm_bt<1, 1><<<grid, 256, 0, stream>>>(A, Bt, Cin, C, M, N, K, ldc, alpha, beta, act, sptr);
        else if (outbf)     gemm_bt<1, 0><<<grid, 256, 0, stream>>>(A, Bt, Cin, C, M, N, K, ldc, alpha, beta, act, sptr);
        else                gemm_bt<0, 0><<<grid, 256, 0, stream>>>(A, Bt, Cin, C, M, N, K, ldc, alpha, beta, act, sptr);
    };
    auto gdir = [&](int outbf, int cinbf, const bf16* A, const bf16* Bt,
                    const void* Cin, void* C, int M, int N, int K, int ldc,
                    float alpha, float beta, int act, const float* sptr) {
        dim3 grid((N + 127) / 128, (M + 127) / 128);
        if (outbf && cinbf)      gemm_direct<1, 1><<<grid, 256, 0, stream>>>(A, Bt, Cin, C, M, N, K, ldc, alpha, beta, act, sptr);
        else if (outbf)          gemm_direct<1, 0><<<grid, 256, 0, stream>>>(A, Bt, Cin, C, M, N, K, ldc, alpha, beta, act, sptr);
        else if (cinbf)          gemm_direct<0, 1><<<grid, 256, 0, stream>>>(A, Bt, Cin, C, M, N, K, ldc, alpha, beta, act, sptr);
        else                     gemm_direct<0, 0><<<grid, 256, 0, stream>>>(A, Bt, Cin, C, M, N, K, ldc, alpha, beta, act, sptr);
    };
    // split-K: partials into partA (slabA), reduce into fp32 out
    auto skp = [&](const bf16* A, const bf16* Bt, float* out,
                   int M, int N, int K, int KC) {
        int SK = (K + KC - 1) / KC;
        gemm_skp<<<dim3((N + 127) / 128, (M + 127) / 128, SK), 256, 0, stream>>>(A, Bt, partA, M, N, K, KC);
        int MN = M * N;
        skred<<<(MN + 255) / 256, 256, 0, stream>>>(partA, out, SK, MN);
    };
    auto tconv = [&](const float* W, bf16* Wt, int K, int N, int Kpad) {
        tconv_kernel<<<dim3((Kpad + 31) / 32, (N + 31) / 32), 256, 0, stream>>>(W, Wt, K, N, Kpad);
    };

    // 0. weight converts
    tconv(qkvw, qkvwT, Dc, 3 * Dc, Dc);
    tconv(gw1, gw1T, Dc, GGH, Dc);
    tconv(wow, wowT, Dc, Dc, Dc);
    tconv(mw1, mw1T, FPOLY, MHID, FPOLY);
    tconv(mw2, mw2T, MHID, Dc, MHID);
    tconv(fw1, fw1T, Dc, FFNH, Dc);
    tconv(fw3, fw3T, Dc, FFNH, Dc);
    tconv(fw2, fw2T, FFNH, Dc, FFNHP);
    tconv(mwk, mwkTb, Dc, HDc, Dc);
    cvt_kernel<<<2048, 256, 0, stream>>>(mw2, mw2b, MHID * Dc);
    sgate_kernel<<<1, 1, 0, stream>>>(mgate, scal + 2);

    // 1-2. rmsnorm, q/k/v, gamma  (gg1 via split-K before vt occupies slabA)
    rms_rows<<<NTOK, 256, 0, stream>>>(x, n1w, hb, Dc);
    gemmB(1, 0, hb, qkvwT,          nullptr, qtb, NTOK, Dc, Dc, Dc, 1.f, 0.f, 0, nullptr);
    snr_one<<<dim3(Sc / 4, Hc, Bc), 256, 0, stream>>>(qtb, qnw, qnb);
    gemmB(1, 0, hb, qkvwT + (size_t)1024 * Dc, nullptr, qtb, NTOK, Dc, Dc, Dc, 1.f, 0.f, 0, nullptr);
    snr_one<<<dim3(Sc / 4, Hc, Bc), 256, 0, stream>>>(qtb, knw, knb);
    gemmB(1, 0, hb, qkvwT + (size_t)2048 * Dc, nullptr, vb, NTOK, Dc, Dc, Dc, 1.f, 0.f, 0, nullptr);
    skp(hb, gw1T, gg1, NTOK, GGH, Dc, 256);        // SK=4, 128 blocks
    gamma_kernel<<<NTOK / 4, 256, 0, stream>>>(gg1, gw2, gamma);
    cvt_kernel<<<2048, 256, 0, stream>>>(mw1, mw1b, FPOLY * MHID);   // hb dead

    // 3. V transpose, q_mem, attention (k-split cooperative, balanced pairs)
    vtrans_kernel<<<dim3(Sc / 32, 2, Bc * Hc), 256, 0, stream>>>(vb, vt);
    kpsum_kernel<<<dim3(Bc * Hc, 16), 64, 0, stream>>>(knb, psum);
    qmem2_kernel<<<dim3(Bc * Hc, 16), 64, 0, stream>>>(qnb, knb, gamma, psum, qmem);
    attn_mfma<<<dim3(32, Hc, Bc), 256, 0, stream>>>(qnb, knb, vt, attnb);

    // 4. actives (vt dead -> slabA reusable as partials)
    gather_active<<<NACT, 256, 0, stream>>>(qmem, vb, xa, xab, va);
    wvec_kernel<<<1, 128, 0, stream>>>(gamma, wvec, scal);

    // 5. gradient chain (128 active tokens) -- split-K MFMA
    skp(xab, mwkTb, za, NACT, HDc, Dc, 64);                         // SK=16
    phi2_f32<<<dim3((FPOLY + 255) / 256, NACT), 256, 0, stream>>>(za, featA, featAb);
    skp(featAb, mw1T, ua, NACT, MHID, FPOLY, 288);                  // SK=15, 240 blocks
    silu_kernel<<<(NACT * MHID + 255) / 256, 256, 0, stream>>>(ua, sua, suab, NACT * MHID);
    skp(suab, mw2T, preda, NACT, Dc, MHID, 128);                    // SK=16, 128 blocks
    dpred_kernel<<<(NACT * Dc + 255) / 256, 256, 0, stream>>>(preda, va, wvec, scal, dpreda, dpredab);
    skp(dpredab, mw2b, dsua, NACT, MHID, Dc, 128);                  // SK=8, 128 blocks
    dsilu_kernel<<<(NACT * MHID + 255) / 256, 256, 0, stream>>>(dsua, ua, dua, duab, NACT * MHID);
    skp(duab, mw1b, dfeata, NACT, FPOLY, MHID, 256);                // SK=8, 264 blocks
    dz_kernel<<<NACT, 64, 0, stream>>>(dfeata, za, dza, dzab);

    // transposed bf16 copies for the NS/PT/weight-update path
    tconv(dua, duaTb, 128, MHID, 128);
    tconv(dpreda, dpredaTb, 128, Dc, 128);
    tconv(dza, dzaTb, 128, HDc, 128);
    tconv(xa, xaTb, 128, Dc, 128);
    tconv(featA, featATb, 128, FPOLY, 128);
    tconv(sua, suaTb, 128, MHID, 128);

    // 6. Newton-Schulz in 128x128 space: fused 5-iteration chain (1 launch, 3 blocks)
    gram_trick<<<1, 256, 0, stream>>>(za, SA);                      // S1 = poly-kernel of za
    skp(suab, suab, SA + 16384, 128, 128, MHID, 64);                // SK=32
    skp(xab, xab, SA + 32768, 128, 128, Dc, 64);                    // SK=16
    skp(duab, duab, CA, 128, 128, MHID, 64);
    skp(dpredab, dpredab, CA + 16384, 128, 128, Dc, 64);
    gdir(0, 0, dzab, dzab, nullptr, CA + 32768, 128, 128, HDc, 128, 1.f, 0.f, 0, nullptr);
    ns_norm_kernel<<<3, 256, 0, stream>>>(SA, CA, Sb16, Cb16, scal + 8);
    ns_fused<<<3, 256, 0, stream>>>(Sb16, Cb16, FcAb, FcTAb);
    // P5 = PTraw^T @ Fc * invn
    gdir(1, 0, duaTb,    FcTAb,         nullptr, PT1Tb, MHID, 128, 128, 128, 1.f, 0.f, 0, scal + 8);
    gdir(1, 0, dpredaTb, FcTAb + 16384, nullptr, PT2Tb, Dc,   128, 128, 128, 1.f, 0.f, 0, scal + 9);
    gdir(1, 0, dzaTb,    FcTAb + 32768, nullptr, PT3Tb, HDc,  128, 128, 128, 1.f, 0.f, 0, scal + 10);

    // wkuT = 0.999*mwkT - 0.01*PT3T@xa
    gdir(1, 1, PT3Tb, xaTb, mwkTb, wkuTb, HDc, Dc, 128, Dc, -0.01f, 0.999f, 0, nullptr);
    // materialize updated memory weights (transposed, bf16):
    //   w1uT = 0.999*mw1T - 0.01*PT1T@featA   (mw1b dead -> slabG reuse)
    gemmB(1, 1, PT1Tb, featATb, mw1T, w1uT, MHID, FPOLY, 128, FPOLY, -0.01f, 0.999f, 0, nullptr);
    //   w2uT = 0.999*mw2T - 0.01*PT2T@sua
    gemmB(1, 1, PT2Tb, suaTb, mw2T, w2uT, Dc, MHID, 128, MHID, -0.01f, 0.999f, 0, nullptr);

    // 7. x2 = x + attn@wo; zf = qmem@wku
    gemmB(0, 0, attnb, wowT, x, x2, NTOK, Dc, Dc, Dc, 1.f, 1.f, 0, nullptr);
    cvt_kernel<<<2048, 256, 0, stream>>>(qmem, qmemb, NTOK * Dc);
    gdir(0, 0, qmemb, wkuTb, nullptr, zf, NTOK, HDc, Dc, HDc, 1.f, 0.f, 0, nullptr);

    // 8. memory forward with materialized updated weights, 2 chunks
    for (int c = 0; c < NTOK / MCH; ++c) {
        const int R = c * MCH;
        phi2_bf16<<<dim3((FPOLY + 255) / 256, MCH), 256, 0, stream>>>(zf + (size_t)R * HDc, featC);
        gemmB(1, 0, featC, w1uT, nullptr, t1b, MCH, MHID, FPOLY, MHID, 1.f, 0.f, 1, nullptr);
        gemmB(0, 0, t1b, w2uT, x2 + (size_t)R * Dc, x2 + (size_t)R * Dc,
              MCH, Dc, MHID, Dc, 1.f, 1.f, 0, scal + 2);
    }
    // 9. FFN (swiglu)
    rms_rows<<<NTOK, 256, 0, stream>>>(x2, n2w, h2b, Dc);
    gemmB(1, 0, h2b, fw1T, nullptr, ff1b, NTOK, FFNH, Dc, FFNHP, 1.f, 0.f, 1, nullptr);
    gemmB(1, 0, h2b, fw3T, nullptr, ff3b, NTOK, FFNH, Dc, FFNHP, 1.f, 0.f, 0, nullptr);
    mulpad_kernel<<<(NTOK * FFNHP + 255) / 256, 256, 0, stream>>>(ff1b, ff3b);
    gemmB(0, 0, ff1b, fw2T, x2, outp, NTOK, Dc, FFNHP, Dc, 1.f, 1.f, 0, nullptr);
}

// Round 5
// 1369.345 us; speedup vs baseline: 1.1035x; 1.1035x over previous
//
#include <hip/hip_runtime.h>
#include <math.h>

#define Bc 2
#define Sc 2048
#define Dc 1024
#define Hc 16
#define HDc 64
#define FPOLY 4160
#define MHID 2048
#define FFNH 2730
#define FFNHP 2752   // FFNH padded to mult of 32 (K pad, zero-filled)
#define GGH 64
#define NTOK 4096
#define NACT 128

typedef __bf16 bf16;
typedef __attribute__((ext_vector_type(8))) __bf16 bf16x8;
typedef __attribute__((ext_vector_type(4))) float f32x4;

#define AS1 __attribute__((address_space(1)))
#define AS3 __attribute__((address_space(3)))

__device__ __forceinline__ void gload16(const void* g, void* l) {
    __builtin_amdgcn_global_load_lds((AS1 const void*)g, (AS3 void*)l, 16, 0, 0);
}

__device__ __forceinline__ float fexp2(float x) { return __builtin_amdgcn_exp2f(x); }

// ---------------------------------------------------------------- bf16 MFMA GEMM (LDS, big tiles)
// C = act(alpha*[sptr]*A@Bt^T + beta*Cin).  A:(M,K) bf16 row-major, Bt:(N,K) bf16.
// K%32==0, M%128==0. N arbitrary; Bt rows allocated to ceil(N/128)*128.
// 2-phase stage-ahead pipeline (T3-min recipe).
template<int OUTBF, int CINBF>
__global__ __launch_bounds__(256) void gemm_bt(
    const bf16* __restrict__ A, const bf16* __restrict__ Bt,
    const void* __restrict__ Cin, void* __restrict__ Cout,
    int M, int N, int K, int ldc,
    float alpha, float beta, int act, const float* __restrict__ sptr)
{
    __shared__ bf16 As[2][128 * 32];
    __shared__ bf16 Bs[2][128 * 32];
    const int tid = threadIdx.x;
    const int w = tid >> 6, lane = tid & 63;
    const int bm = blockIdx.y * 128, bn = blockIdx.x * 128;
    const int wm = (w >> 1) * 64, wn = (w & 1) * 64;
    f32x4 acc[4][4];
#pragma unroll
    for (int i = 0; i < 4; ++i)
#pragma unroll
        for (int j = 0; j < 4; ++j) { acc[i][j][0] = 0.f; acc[i][j][1] = 0.f; acc[i][j][2] = 0.f; acc[i][j][3] = 0.f; }
    const int idx0 = tid, idx1 = tid + 256;
    const int r0 = idx0 >> 2, r1 = idx1 >> 2;
    const int g0 = ((idx0 & 3) ^ ((r0 >> 1) & 3)) * 8;
    const int g1 = ((idx1 & 3) ^ ((r1 >> 1) & 3)) * 8;
    const int lrow = lane & 15;
    const int q = lane >> 4;
    int aoff[4], boff[4];
#pragma unroll
    for (int t = 0; t < 4; ++t) {
        int ar = wm + t * 16 + lrow;
        aoff[t] = ar * 32 + ((q ^ ((ar >> 1) & 3)) * 8);
        int br = wn + t * 16 + lrow;
        boff[t] = br * 32 + ((q ^ ((br >> 1) & 3)) * 8);
    }
    const bf16* Arow0 = A + (size_t)(bm + r0) * K + g0;
    const bf16* Arow1 = A + (size_t)(bm + r1) * K + g1;
    const bf16* Brow0 = Bt + (size_t)(bn + r0) * K + g0;
    const bf16* Brow1 = Bt + (size_t)(bn + r1) * K + g1;
    auto stage = [&](int bi, int k0) {
        char* la = (char*)&As[bi][0] + w * 1024;
        char* lb = (char*)&Bs[bi][0] + w * 1024;
        gload16(Arow0 + k0, la);
        gload16(Arow1 + k0, la + 4096);
        gload16(Brow0 + k0, lb);
        gload16(Brow1 + k0, lb + 4096);
    };
    auto compute = [&](int bi) {
        bf16x8 af[4], bfr[4];
#pragma unroll
        for (int t = 0; t < 4; ++t) af[t] = *(const bf16x8*)&As[bi][aoff[t]];
#pragma unroll
        for (int t = 0; t < 4; ++t) bfr[t] = *(const bf16x8*)&Bs[bi][boff[t]];
#pragma unroll
        for (int mt = 0; mt < 4; ++mt)
#pragma unroll
            for (int nt = 0; nt < 4; ++nt)
                acc[mt][nt] = __builtin_amdgcn_mfma_f32_16x16x32_bf16(af[mt], bfr[nt], acc[mt][nt], 0, 0, 0);
    };
    stage(0, 0);
    __syncthreads();
    int buf = 0;
    for (int k0 = 32; k0 < K; k0 += 32) {
        stage(buf ^ 1, k0);
        compute(buf);
        __syncthreads();
        buf ^= 1;
    }
    compute(buf);
    const float amul = alpha * (sptr ? *sptr : 1.f);
#pragma unroll
    for (int nt = 0; nt < 4; ++nt) {
        const int col = bn + wn + nt * 16 + lrow;
        if (col >= N) continue;
#pragma unroll
        for (int mt = 0; mt < 4; ++mt) {
            const int rbase = bm + wm + mt * 16 + q * 4;
#pragma unroll
            for (int r = 0; r < 4; ++r) {
                const size_t o = (size_t)(rbase + r) * ldc + col;
                float v = amul * acc[mt][nt][r];
                if (beta != 0.f)
                    v += beta * (CINBF ? (float)((const bf16*)Cin)[o] : ((const float*)Cin)[o]);
                if (act == 1) v = v / (1.f + __expf(-v));
                if (OUTBF) ((bf16*)Cout)[o] = (bf16)v;
                else       ((float*)Cout)[o] = v;
            }
        }
    }
}

// ---------------------------------------------------------------- barrier-free direct MFMA GEMM
template<int OUTBF, int CINBF>
__global__ __launch_bounds__(256) void gemm_direct(
    const bf16* __restrict__ A, const bf16* __restrict__ Bt,
    const void* __restrict__ Cin, void* __restrict__ Cout,
    int M, int N, int K, int ldc,
    float alpha, float beta, int act, const float* __restrict__ sptr)
{
    const int tid = threadIdx.x, w = tid >> 6, lane = tid & 63;
    const int lrow = lane & 15, quad = lane >> 4;
    const int bm = blockIdx.y * 128 + w * 32;
    const int bn = blockIdx.x * 128;
    f32x4 acc[2][8];
#pragma unroll
    for (int mt = 0; mt < 2; ++mt)
#pragma unroll
        for (int nt = 0; nt < 8; ++nt) { acc[mt][nt][0] = 0.f; acc[mt][nt][1] = 0.f; acc[mt][nt][2] = 0.f; acc[mt][nt][3] = 0.f; }
    const bf16* Abase = A + (size_t)(bm + lrow) * K + quad * 8;
    const bf16* Bbase = Bt + (size_t)(bn + lrow) * K + quad * 8;
#pragma unroll 2
    for (int k0 = 0; k0 < K; k0 += 32) {
        bf16x8 af0 = *(const bf16x8*)(Abase + k0);
        bf16x8 af1 = *(const bf16x8*)(Abase + (size_t)16 * K + k0);
#pragma unroll
        for (int nt = 0; nt < 8; ++nt) {
            bf16x8 bfr = *(const bf16x8*)(Bbase + (size_t)nt * 16 * K + k0);
            acc[0][nt] = __builtin_amdgcn_mfma_f32_16x16x32_bf16(af0, bfr, acc[0][nt], 0, 0, 0);
            acc[1][nt] = __builtin_amdgcn_mfma_f32_16x16x32_bf16(af1, bfr, acc[1][nt], 0, 0, 0);
        }
    }
    const float amul = alpha * (sptr ? *sptr : 1.f);
#pragma unroll
    for (int nt = 0; nt < 8; ++nt) {
        const int col = bn + nt * 16 + lrow;
        if (col >= N) continue;
#pragma unroll
        for (int mt = 0; mt < 2; ++mt) {
            const int rbase = bm + mt * 16 + quad * 4;
#pragma unroll
            for (int r = 0; r < 4; ++r) {
                const int row = rbase + r;
                if (row >= M) continue;
                const size_t o = (size_t)row * ldc + col;
                float v = amul * acc[mt][nt][r];
                if (beta != 0.f)
                    v += beta * (CINBF ? (float)((const bf16*)Cin)[o] : ((const float*)Cin)[o]);
                if (act == 1) v = v / (1.f + __expf(-v));
                if (OUTBF) ((bf16*)Cout)[o] = (bf16)v;
                else       ((float*)Cout)[o] = v;
            }
        }
    }
}

// ---------------------------------------------------------------- split-K direct GEMM
__global__ __launch_bounds__(256) void gemm_skp(
    const bf16* __restrict__ A, const bf16* __restrict__ Bt,
    float* __restrict__ part, int M, int N, int K, int KC)
{
    const int tid = threadIdx.x, w = tid >> 6, lane = tid & 63;
    const int lrow = lane & 15, quad = lane >> 4;
    const int bm = blockIdx.y * 128 + w * 32;
    const int bn = blockIdx.x * 128;
    const int z = blockIdx.z;
    const int kb = z * KC;
    int ke = kb + KC; if (ke > K) ke = K;
    f32x4 acc[2][8];
#pragma unroll
    for (int mt = 0; mt < 2; ++mt)
#pragma unroll
        for (int nt = 0; nt < 8; ++nt) { acc[mt][nt][0] = 0.f; acc[mt][nt][1] = 0.f; acc[mt][nt][2] = 0.f; acc[mt][nt][3] = 0.f; }
    const bf16* Abase = A + (size_t)(bm + lrow) * K + quad * 8;
    const bf16* Bbase = Bt + (size_t)(bn + lrow) * K + quad * 8;
#pragma unroll 2
    for (int k0 = kb; k0 < ke; k0 += 32) {
        bf16x8 af0 = *(const bf16x8*)(Abase + k0);
        bf16x8 af1 = *(const bf16x8*)(Abase + (size_t)16 * K + k0);
#pragma unroll
        for (int nt = 0; nt < 8; ++nt) {
            bf16x8 bfr = *(const bf16x8*)(Bbase + (size_t)nt * 16 * K + k0);
            acc[0][nt] = __builtin_amdgcn_mfma_f32_16x16x32_bf16(af0, bfr, acc[0][nt], 0, 0, 0);
            acc[1][nt] = __builtin_amdgcn_mfma_f32_16x16x32_bf16(af1, bfr, acc[1][nt], 0, 0, 0);
        }
    }
    float* po = part + (size_t)z * M * N;
#pragma unroll
    for (int nt = 0; nt < 8; ++nt) {
        const int col = bn + nt * 16 + lrow;
        if (col >= N) continue;
#pragma unroll
        for (int mt = 0; mt < 2; ++mt) {
            const int rbase = bm + mt * 16 + quad * 4;
#pragma unroll
            for (int r = 0; r < 4; ++r) {
                const int row = rbase + r;
                if (row >= M) continue;
                po[(size_t)row * N + col] = acc[mt][nt][r];
            }
        }
    }
}

__global__ void skred(const float* __restrict__ part, float* __restrict__ out,
                      int SK, int MN)
{
    int i = blockIdx.x * 256 + threadIdx.x;
    if (i >= MN) return;
    float s = 0.f;
    for (int z = 0; z < SK; ++z) s += part[(size_t)z * MN + i];
    out[i] = s;
}

// ---------------------------------------------------------------- polynomial-kernel gram
__global__ __launch_bounds__(256) void gram_trick(
    const float* __restrict__ za, float* __restrict__ S)
{
    __shared__ float z[128 * 65];
    for (int i = threadIdx.x; i < 8192; i += 256) {
        int r = i >> 6, d = i & 63;
        z[r * 65 + d] = za[i];
    }
    __syncthreads();
    for (int idx = threadIdx.x; idx < 16384; idx += 256) {
        int i = idx >> 7, j = idx & 127;
        float dot = 0.f;
#pragma unroll
        for (int d = 0; d < 64; ++d) dot += z[i * 65 + d] * z[j * 65 + d];
        S[idx] = dot + dot * dot * 0.015625f;
    }
}

__global__ __launch_bounds__(256) void ns_norm_kernel(
    const float* __restrict__ S, const float* __restrict__ C,
    bf16* __restrict__ Sb, bf16* __restrict__ Cb, float* __restrict__ invn)
{
    const int z = blockIdx.x;
    const float* s = S + (size_t)z * 16384;
    const float* c = C + (size_t)z * 16384;
    float acc = 0.f;
    for (int i = threadIdx.x; i < 16384; i += 256) acc += s[i] * c[i];
    __shared__ float red[256];
    red[threadIdx.x] = acc; __syncthreads();
    for (int st = 128; st; st >>= 1) {
        if (threadIdx.x < st) red[threadIdx.x] += red[threadIdx.x + st];
        __syncthreads();
    }
    float inv = 1.f / (sqrtf(red[0]) + 1e-7f);
    float inv2 = inv * inv;
    for (int i = threadIdx.x; i < 16384; i += 256) {
        Cb[(size_t)z * 16384 + i] = (bf16)(c[i] * inv2);
        Sb[(size_t)z * 16384 + i] = (bf16)s[i];
    }
    if (threadIdx.x == 0) invn[z] = inv;
}

// ---------------------------------------------------------------- fused Newton-Schulz (batched z=3)
__device__ __forceinline__ int swz(int row, int col) {
    return row * 128 + ((((col >> 3) ^ (row & 7)) << 3) | (col & 7));
}

__global__ __launch_bounds__(256) void ns_fused(
    const bf16* __restrict__ Sg, const bf16* __restrict__ Cg,
    bf16* __restrict__ Fcg, bf16* __restrict__ FcTg)
{
    __shared__ bf16 Cl[16384], Ml[16384], MTl[16384], FTl[16384];
    const int z = blockIdx.x;
    const bf16* S = Sg + (size_t)z * 16384;
    bf16* Fc = Fcg + (size_t)z * 16384;
    bf16* FcT = FcTg + (size_t)z * 16384;
    const int tid = threadIdx.x, w = tid >> 6, lane = tid & 63;
    const int lrow = lane & 15, quad = lane >> 4;
    const int bm = w * 32;
    for (int i = tid; i < 2048; i += 256) {
        const int row = i >> 4, c = i & 15;
        *(bf16x8*)&Cl[row * 128 + ((c ^ (row & 7)) << 3)] =
            *(const bf16x8*)(Cg + (size_t)z * 16384 + (size_t)row * 128 + c * 8);
    }
    __syncthreads();
    const int r0 = bm + lrow, r1 = r0 + 16;
    const int rx = lrow & 7;
    f32x4 acc[2][8];
    auto zacc = [&]() {
#pragma unroll
        for (int mt = 0; mt < 2; ++mt)
#pragma unroll
            for (int nt = 0; nt < 8; ++nt) { acc[mt][nt][0] = 0.f; acc[mt][nt][1] = 0.f; acc[mt][nt][2] = 0.f; acc[mt][nt][3] = 0.f; }
    };
    auto inner = [&](bf16x8 af0, bf16x8 af1, const bf16* Bt, int c) {
#pragma unroll
        for (int nt = 0; nt < 8; ++nt) {
            const int br = nt * 16 + lrow;
            bf16x8 bfr = *(const bf16x8*)&Bt[br * 128 + ((c ^ (br & 7)) << 3)];
            acc[0][nt] = __builtin_amdgcn_mfma_f32_16x16x32_bf16(af0, bfr, acc[0][nt], 0, 0, 0);
            acc[1][nt] = __builtin_amdgcn_mfma_f32_16x16x32_bf16(af1, bfr, acc[1][nt], 0, 0, 0);
        }
    };
    auto gemm_ll = [&](const bf16* Al, const bf16* Bt) {
        zacc();
#pragma unroll
        for (int k0 = 0; k0 < 128; k0 += 32) {
            const int c = (k0 >> 3) + quad;
            bf16x8 af0 = *(const bf16x8*)&Al[r0 * 128 + ((c ^ rx) << 3)];
            bf16x8 af1 = *(const bf16x8*)&Al[r1 * 128 + ((c ^ rx) << 3)];
            inner(af0, af1, Bt, c);
        }
    };
    auto gemm_gl = [&](const bf16* Ag, const bf16* Bt) {
        zacc();
#pragma unroll
        for (int k0 = 0; k0 < 128; k0 += 32) {
            const int c = (k0 >> 3) + quad;
            bf16x8 af0 = *(const bf16x8*)(Ag + (size_t)r0 * 128 + k0 + quad * 8);
            bf16x8 af1 = *(const bf16x8*)(Ag + (size_t)r1 * 128 + k0 + quad * 8);
            inner(af0, af1, Bt, c);
        }
    };

    for (int t = 0; t < 5; ++t) {
        gemm_gl(S, Cl);
#pragma unroll
        for (int mt = 0; mt < 2; ++mt)
#pragma unroll
            for (int nt = 0; nt < 8; ++nt)
#pragma unroll
                for (int r = 0; r < 4; ++r) {
                    const int row = bm + mt * 16 + quad * 4 + r, col = nt * 16 + lrow;
                    const bf16 v = (bf16)acc[mt][nt][r];
                    Ml[swz(row, col)] = v;
                    MTl[swz(col, row)] = v;
                }
        __syncthreads();
        gemm_ll(Ml, MTl);
#pragma unroll
        for (int mt = 0; mt < 2; ++mt)
#pragma unroll
            for (int nt = 0; nt < 8; ++nt)
#pragma unroll
                for (int r = 0; r < 4; ++r) {
                    const int row = bm + mt * 16 + quad * 4 + r, col = nt * 16 + lrow;
                    float v = 2.0315f * acc[mt][nt][r] - 4.775f * (float)Ml[swz(row, col)];
                    if (row == col) v += 3.4445f;
                    FTl[swz(col, row)] = (bf16)v;
                    if (t == 0) Fc[(size_t)row * 128 + col] = (bf16)v;
                }
        __syncthreads();
        if (t > 0) {
            gemm_gl(Fc, FTl);
            if (t == 4) {
#pragma unroll
                for (int mt = 0; mt < 2; ++mt)
#pragma unroll
                    for (int nt = 0; nt < 8; ++nt)
#pragma unroll
                        for (int r = 0; r < 4; ++r) {
                            const int row = bm + mt * 16 + quad * 4 + r, col = nt * 16 + lrow;
                            FcT[(size_t)col * 128 + row] = (bf16)acc[mt][nt][r];
                        }
                return;
            }
#pragma unroll
            for (int mt = 0; mt < 2; ++mt)
#pragma unroll
                for (int nt = 0; nt < 8; ++nt)
#pragma unroll
                    for (int r = 0; r < 4; ++r) {
                        const int row = bm + mt * 16 + quad * 4 + r, col = nt * 16 + lrow;
                        Fc[(size_t)row * 128 + col] = (bf16)acc[mt][nt][r];
                    }
        }
        gemm_ll(Cl, FTl);
#pragma unroll
        for (int mt = 0; mt < 2; ++mt)
#pragma unroll
            for (int nt = 0; nt < 8; ++nt)
#pragma unroll
                for (int r = 0; r < 4; ++r) {
                    const int row = bm + mt * 16 + quad * 4 + r, col = nt * 16 + lrow;
                    Ml[swz(col, row)] = (bf16)acc[mt][nt][r];
                }
        __syncthreads();
        gemm_ll(Ml, FTl);
#pragma unroll
        for (int mt = 0; mt < 2; ++mt)
#pragma unroll
            for (int nt = 0; nt < 8; ++nt)
#pragma unroll
                for (int r = 0; r < 4; ++r) {
                    const int row = bm + mt * 16 + quad * 4 + r, col = nt * 16 + lrow;
                    Cl[swz(row, col)] = (bf16)acc[mt][nt][r];
                }
        __syncthreads();
    }
}

// ---------------------------------------------------------------- converts
__global__ __launch_bounds__(256) void tconv_kernel(
    const float* __restrict__ W, bf16* __restrict__ Wt, int K, int N, int Kpad)
{
    __shared__ float t[32][33];
    const int k0 = blockIdx.x * 32, n0 = blockIdx.y * 32;
    const int tx = threadIdx.x & 31, ty = threadIdx.x >> 5;
#pragma unroll
    for (int r = 0; r < 4; ++r) {
        int gk = k0 + ty + r * 8, gn = n0 + tx;
        t[ty + r * 8][tx] = (gk < K && gn < N) ? W[(size_t)gk * N + gn] : 0.f;
    }
    __syncthreads();
#pragma unroll
    for (int r = 0; r < 4; ++r) {
        int gn = n0 + ty + r * 8, gk = k0 + tx;
        if (gn < N && gk < Kpad) Wt[(size_t)gn * Kpad + gk] = (bf16)t[tx][ty + r * 8];
    }
}

__global__ void cvt_kernel(const float* __restrict__ in, bf16* __restrict__ out, int n)
{
    for (int i = blockIdx.x * 256 + threadIdx.x; i < n; i += gridDim.x * 256)
        out[i] = (bf16)in[i];
}

// qkv (b,s,3072) v-part -> vt (b,h,d,s)
__global__ __launch_bounds__(256) void vtrans_kernel(
    const bf16* __restrict__ qkv, bf16* __restrict__ vt)
{
    __shared__ bf16 t[32][33];
    const int s0 = blockIdx.x * 32, d0 = blockIdx.y * 32, bh = blockIdx.z;
    const int b = bh >> 4, h = bh & 15;
    const int tx = threadIdx.x & 31, ty = threadIdx.x >> 5;
#pragma unroll
    for (int r = 0; r < 4; ++r) {
        int s = s0 + ty + r * 8;
        t[ty + r * 8][tx] = qkv[((size_t)b * Sc + s) * 3072 + 2048 + h * 64 + d0 + tx];
    }
    __syncthreads();
#pragma unroll
    for (int r = 0; r < 4; ++r) {
        int d = d0 + ty + r * 8;
        vt[((size_t)bh * 64 + d) * Sc + s0 + tx] = t[tx][ty + r * 8];
    }
}

// ---------------------------------------------------------------- small kernels
__global__ __launch_bounds__(256) void rms_rows(
    const float* __restrict__ in, const float* __restrict__ w,
    bf16* __restrict__ out, int D)
{
    const int row = blockIdx.x;
    const float* r = in + (size_t)row * D;
    bf16* o = out + (size_t)row * D;
    float s = 0.f;
    for (int i = threadIdx.x; i < D; i += 256) { float v = r[i]; s += v * v; }
    __shared__ float red[256];
    red[threadIdx.x] = s;
    __syncthreads();
    for (int st = 128; st; st >>= 1) {
        if (threadIdx.x < st) red[threadIdx.x] += red[threadIdx.x + st];
        __syncthreads();
    }
    float rs = rsqrtf(red[0] / (float)D + 1e-6f);
    for (int i = threadIdx.x; i < D; i += 256) o[i] = (bf16)(r[i] * rs * w[i]);
}

__global__ __launch_bounds__(256) void gamma_kernel(
    const float* __restrict__ gg1, const float* __restrict__ w2,
    float* __restrict__ gamma)
{
    const int tid = threadIdx.x, w = tid >> 6, lane = tid & 63;
    const int t = blockIdx.x * 4 + w;
    float v = gg1[(size_t)t * GGH + lane];
    v = v / (1.f + expf(-v));
    v *= w2[lane];
#pragma unroll
    for (int off = 32; off; off >>= 1) v += __shfl_xor(v, off);
    if (lane == 0) gamma[t] = 1.f / (1.f + expf(-v));
}

// rmsnorm+rope one head-row; src = qkv buffer (ldc 3072), co = column offset (0=q,1024=k)
__global__ __launch_bounds__(256) void snr_one(
    const bf16* __restrict__ src, const float* __restrict__ w,
    bf16* __restrict__ dst, int co)
{
    const int tid = threadIdx.x, wv = tid >> 6, lane = tid & 63;
    const int s = blockIdx.x * 4 + wv;
    const int h = blockIdx.y, b = blockIdx.z;
    const size_t row = ((size_t)b * Sc + s) * 3072 + co + h * 64;
    float v = (float)src[row + lane];
    float ss = v * v;
#pragma unroll
    for (int off = 32; off; off >>= 1) ss += __shfl_xor(ss, off);
    v = v * rsqrtf(ss / 64.f + 1e-6f) * w[lane];
    const int j = lane & 31;
    float inv = powf(10000.f, -(float)j / 32.f);
    float ang = (float)s * inv;
    float sn = sinf(ang), cs = cosf(ang);
    float p = __shfl_xor(v, 32);
    float o;
    if (lane < 32) o = v * cs - p * sn;
    else           o = p * sn + v * cs;
    const size_t od = (((size_t)b * Hc + h) * Sc + s) * 64 + lane;
    dst[od] = (bf16)o;
}

__global__ void kpsum_kernel(const bf16* __restrict__ kn, float* __restrict__ psum)
{
    const int bh = blockIdx.x, c = blockIdx.y, d = threadIdx.x;
    const size_t base = (size_t)bh * Sc * 64 + (size_t)c * 128 * 64 + d;
    float s = 0.f;
    for (int i = 0; i < 128; ++i) s += (float)kn[base + (size_t)i * 64];
    psum[((size_t)bh * 16 + c) * 64 + d] = s;
}

__global__ void qmem2_kernel(
    const bf16* __restrict__ qn, const bf16* __restrict__ kn,
    const float* __restrict__ gamma, const float* __restrict__ psum,
    float* __restrict__ qmem)
{
    const int bh = blockIdx.x, c = blockIdx.y;
    const int b = bh >> 4, hh = bh & 15;
    const int d = threadIdx.x;
    const size_t base = (size_t)bh * Sc * 64;
    float run = 0.f;
    for (int cc = 0; cc < c; ++cc) run += psum[((size_t)bh * 16 + cc) * 64 + d];
    for (int s = c * 128; s < c * 128 + 128; ++s) {
        run += (float)kn[base + (size_t)s * 64 + d];
        float cm = run / (float)(s + 1);
        float g = gamma[b * Sc + s];
        float qv = (float)qn[base + (size_t)s * 64 + d];
        qmem[((size_t)(b * Sc + s)) * Dc + hh * 64 + d] = g * qv + (1.f - g) * cm;
    }
}

// ---------------------------------------------------------------- MFMA flash attention
// Same structure as R4 (fixed-bound softmax, balanced pairs, k-parity split) PLUS
// XCD-clustering block swizzle: 1D grid 1024 = 8 xcd-slots x 128; all 32 q-tile blocks
// of one (b,h) share flat%8 -> same XCD -> K/V stay resident in that XCD's 4MB L2
// (4 groups x ~0.75MB per XCD). Bijective: 1024 = 8*128 exactly.
__global__ __launch_bounds__(256, 4) void attn_mfma(
    const bf16* __restrict__ qn, const bf16* __restrict__ kn,
    const bf16* __restrict__ vt, bf16* __restrict__ outp)
{
    const int flat = blockIdx.x;
    const int glow = flat & 7, t2 = flat >> 3;
    const int xq = t2 & 31, ghigh = t2 >> 5;
    const int g = glow | (ghigh << 3);
    const int h = g & 15, b = g >> 4;
    const int bh = b * Hc + h;
    const int tid = threadIdx.x, w = tid >> 6, lane = tid & 63;
    const int lrow = lane & 15, quad = lane >> 4;
    const int rhalf = w & 1, pgrp = w >> 1;
    __shared__ bf16 Ps[4][16][136];
    __shared__ float Ob[2][16][68];
    __shared__ float Lb[2][16];
    const bf16* kbase = kn + (size_t)bh * Sc * 64;
    const bf16* vtb = vt + (size_t)bh * 64 * Sc;
    const float SC = 0.1803368801f;   // 0.125 * log2(e)
#pragma unroll 1
    for (int ti = 0; ti < 2; ++ti) {
        const int zt = ti ? (63 - xq) : xq;
        const int qb = zt * 32;
        const int nc = (qb >> 7) + 1;         // # of 128-wide k-chunks (causal)
        const int par = pgrp ^ ti;            // this wave's chunk parity
        const int rowg = qb + rhalf * 16 + quad * 4;   // +r = global row
        bf16x8 qf[2];
        const bf16* qbase = qn + ((size_t)bh * Sc + qb + rhalf * 16) * 64;
#pragma unroll
        for (int ks = 0; ks < 2; ++ks)
            qf[ks] = *(const bf16x8*)(qbase + (size_t)lrow * 64 + ks * 32 + quad * 8);
        f32x4 oacc[4];
#pragma unroll
        for (int nt = 0; nt < 4; ++nt) { oacc[nt][0] = 0.f; oacc[nt][1] = 0.f; oacc[nt][2] = 0.f; oacc[nt][3] = 0.f; }
        float lsum[4] = {0.f, 0.f, 0.f, 0.f};
        for (int ci = par; ci < nc; ci += 2) {
            const int k0 = ci << 7;
            f32x4 sacc[8];
#pragma unroll
            for (int nt = 0; nt < 8; ++nt) { sacc[nt][0] = 0.f; sacc[nt][1] = 0.f; sacc[nt][2] = 0.f; sacc[nt][3] = 0.f; }
            __builtin_amdgcn_s_setprio(1);
#pragma unroll
            for (int ks = 0; ks < 2; ++ks) {
#pragma unroll
                for (int nh = 0; nh < 2; ++nh) {
                    bf16x8 kf[4];
#pragma unroll
                    for (int j = 0; j < 4; ++j)
                        kf[j] = *(const bf16x8*)(kbase + (size_t)(k0 + (nh * 4 + j) * 16 + lrow) * 64 + ks * 32 + quad * 8);
#pragma unroll
                    for (int j = 0; j < 4; ++j)
                        sacc[nh * 4 + j] = __builtin_amdgcn_mfma_f32_16x16x32_bf16(qf[ks], kf[j], sacc[nh * 4 + j], 0, 0, 0);
                }
            }
            __builtin_amdgcn_s_setprio(0);
#pragma unroll
            for (int nt = 0; nt < 8; ++nt) {
                const int kc = k0 + nt * 16 + lrow;
#pragma unroll
                for (int r = 0; r < 4; ++r) {
                    float p = (kc > rowg + r) ? 0.f : fexp2(fmaf(sacc[nt][r], SC, -12.f));
                    sacc[nt][r] = p;
                    lsum[r] += p;
                }
            }
#pragma unroll
            for (int nt = 0; nt < 8; ++nt)
#pragma unroll
                for (int r = 0; r < 4; ++r)
                    Ps[w][quad * 4 + r][nt * 16 + lrow] = (bf16)sacc[nt][r];
            __builtin_amdgcn_s_setprio(1);
#pragma unroll
            for (int ks2 = 0; ks2 < 4; ++ks2) {
                bf16x8 pf = *(const bf16x8*)&Ps[w][lrow][ks2 * 32 + quad * 8];
#pragma unroll
                for (int nt = 0; nt < 4; ++nt) {
                    bf16x8 vf = *(const bf16x8*)(vtb + (size_t)(nt * 16 + lrow) * Sc + k0 + ks2 * 32 + quad * 8);
                    oacc[nt] = __builtin_amdgcn_mfma_f32_16x16x32_bf16(pf, vf, oacc[nt], 0, 0, 0);
                }
            }
            __builtin_amdgcn_s_setprio(0);
        }
#pragma unroll
        for (int r = 0; r < 4; ++r)
#pragma unroll
            for (int off = 1; off < 16; off <<= 1) lsum[r] += __shfl_xor(lsum[r], off);
        if (pgrp == 1) {
#pragma unroll
            for (int nt = 0; nt < 4; ++nt)
#pragma unroll
                for (int r = 0; r < 4; ++r)
                    Ob[rhalf][quad * 4 + r][nt * 16 + lrow] = oacc[nt][r];
            if (lrow == 0)
#pragma unroll
                for (int r = 0; r < 4; ++r) Lb[rhalf][quad * 4 + r] = lsum[r];
        }
        __syncthreads();
        if (pgrp == 0) {
            float linv[4];
#pragma unroll
            for (int r = 0; r < 4; ++r)
                linv[r] = 1.f / (lsum[r] + Lb[rhalf][quad * 4 + r]);
#pragma unroll
            for (int nt = 0; nt < 4; ++nt)
#pragma unroll
                for (int r = 0; r < 4; ++r) {
                    const float o2 = Ob[rhalf][quad * 4 + r][nt * 16 + lrow];
                    outp[((size_t)b * Sc + rowg + r) * Dc + h * 64 + nt * 16 + lrow] =
                        (bf16)((oacc[nt][r] + o2) * linv[r]);
                }
        }
        __syncthreads();
    }
}

__global__ __launch_bounds__(256) void gather_active(
    const float* __restrict__ qmem, const bf16* __restrict__ qkv,
    float* __restrict__ xa, bf16* __restrict__ xab, float* __restrict__ va)
{
    const int t = blockIdx.x;
    const int b = t >> 6;
    const int s = Sc - 64 + (t & 63);
    const float* qrow = qmem + ((size_t)(b * Sc + s)) * Dc;
    const bf16* vrow = qkv + ((size_t)(b * Sc + s)) * 3072 + 2048;
    for (int i = threadIdx.x; i < Dc; i += 256) {
        float q = qrow[i];
        xa[(size_t)t * Dc + i] = q;
        xab[(size_t)t * Dc + i] = (bf16)q;
        va[(size_t)t * Dc + i] = (float)vrow[i];
    }
}

__global__ void wvec_kernel(const float* __restrict__ gamma,
                            float* __restrict__ wvec, float* __restrict__ wsum)
{
    const int t = threadIdx.x;
    const int b = t >> 6, si = t & 63;
    const int s = Sc - 64 + si;
    float v = gamma[b * Sc + s] * powf(0.95f, (float)(Sc - 1 - s));
    wvec[t] = v;
    __shared__ float red[128];
    red[t] = v; __syncthreads();
    for (int st = 64; st; st >>= 1) { if (t < st) red[t] += red[t + st]; __syncthreads(); }
    if (t == 0) wsum[0] = red[0];
}

__global__ __launch_bounds__(256) void phi2_f32(
    const float* __restrict__ z, float* __restrict__ feat, bf16* __restrict__ featb)
{
    const int f = blockIdx.x * 256 + threadIdx.x;
    const int t = blockIdx.y;
    if (f >= FPOLY) return;
    const float* zr = z + (size_t)t * 64;
    float v;
    if (f < 64) v = zr[f];
    else { int i = (f - 64) >> 6, j = (f - 64) & 63; v = zr[i] * zr[j] * 0.125f; }
    feat[(size_t)t * FPOLY + f] = v;
    featb[(size_t)t * FPOLY + f] = (bf16)v;
}

__global__ __launch_bounds__(256) void phi2_bf16(
    const float* __restrict__ z, bf16* __restrict__ feat)
{
    const int f = blockIdx.x * 256 + threadIdx.x;
    const int t = blockIdx.y;
    if (f >= FPOLY) return;
    const float* zr = z + (size_t)t * 64;
    float v;
    if (f < 64) v = zr[f];
    else { int i = (f - 64) >> 6, j = (f - 64) & 63; v = zr[i] * zr[j] * 0.125f; }
    feat[(size_t)t * FPOLY + f] = (bf16)v;
}

__global__ void silu_kernel(const float* __restrict__ in, float* __restrict__ out,
                            bf16* __restrict__ outb, int n)
{
    int i = blockIdx.x * 256 + threadIdx.x;
    if (i < n) {
        float v = in[i];
        float s = v / (1.f + expf(-v));
        out[i] = s; outb[i] = (bf16)s;
    }
}

__global__ void dpred_kernel(const float* __restrict__ pred, const float* __restrict__ va,
                             const float* __restrict__ wvec, const float* __restrict__ wsum,
                             float* __restrict__ dpred, bf16* __restrict__ dpredb)
{
    int i = blockIdx.x * 256 + threadIdx.x;
    if (i < NACT * Dc) {
        int t = i >> 10;
        float v = 2.f * wvec[t] / (wsum[0] + 1e-8f) * (pred[i] - va[i]);
        dpred[i] = v; dpredb[i] = (bf16)v;
    }
}

__global__ void dsilu_kernel(const float* __restrict__ dsu, const float* __restrict__ u,
                             float* __restrict__ du, bf16* __restrict__ dub, int n)
{
    int i = blockIdx.x * 256 + threadIdx.x;
    if (i < n) {
        float uv = u[i];
        float sg = 1.f / (1.f + expf(-uv));
        float v = dsu[i] * sg * (1.f + uv * (1.f - sg));
        du[i] = v; dub[i] = (bf16)v;
    }
}

__global__ void dz_kernel(const float* __restrict__ dfeat, const float* __restrict__ za,
                          float* __restrict__ dz, bf16* __restrict__ dzb)
{
    const int t = blockIdx.x;
    const int k = threadIdx.x;
    const float* df = dfeat + (size_t)t * FPOLY;
    const float* z = za + (size_t)t * 64;
    float s1 = 0.f, s2 = 0.f;
    for (int j = 0; j < 64; ++j) {
        float zj = z[j];
        s1 += df[64 + k * 64 + j] * zj;
        s2 += df[64 + j * 64 + k] * zj;
    }
    float v = df[k] + 0.125f * (s1 + s2);
    dz[(size_t)t * 64 + k] = v;
    dzb[(size_t)t * 64 + k] = (bf16)v;
}

__global__ void sgate_kernel(const float* __restrict__ mg, float* __restrict__ out)
{
    out[0] = 1.f / (1.f + expf(-mg[0]));
}

__global__ void mulpad_kernel(bf16* __restrict__ a, const bf16* __restrict__ b)
{
    int i = blockIdx.x * 256 + threadIdx.x;
    if (i >= NTOK * FFNHP) return;
    int k = i % FFNHP;
    if (k >= FFNH) { a[i] = (bf16)0.f; return; }
    a[i] = (bf16)((float)a[i] * (float)b[i]);
}

// ---------------------------------------------------------------- launch
extern "C" void kernel_launch(void* const* d_in, const int* in_sizes, int n_in,
                              void* d_out, int out_size, void* d_ws, size_t ws_size,
                              hipStream_t stream)
{
    const float* x     = (const float*)d_in[0];
    const float* n1w   = (const float*)d_in[1];
    const float* n2w   = (const float*)d_in[2];
    const float* qkvw  = (const float*)d_in[3];
    const float* qnw   = (const float*)d_in[4];
    const float* knw   = (const float*)d_in[5];
    const float* gw1   = (const float*)d_in[6];
    const float* gw2   = (const float*)d_in[7];
    const float* mwk   = (const float*)d_in[8];
    const float* mw1   = (const float*)d_in[9];
    const float* mw2   = (const float*)d_in[10];
    const float* mgate = (const float*)d_in[11];
    const float* wow   = (const float*)d_in[12];
    const float* fw1   = (const float*)d_in[13];
    const float* fw2   = (const float*)d_in[14];
    const float* fw3   = (const float*)d_in[15];
    float* outp = (float*)d_out;

    char* base = (char*)d_ws;
    size_t off = 0;
    auto takeB = [&](size_t bytes) { char* p = base + off; off += (bytes + 255) & ~(size_t)255; return p; };

    // slabs (liveness-overlaid). Order matters: A+E adjacent (featC4 34MB spans both),
    // D+F adjacent (t1b4 16.8MB spans both).
    char* slabA  = takeB(22544384);  // partials (st 2,5,6) / vt (st 3) -> featC4(lo) -> ff1b
    char* slabE  = takeB(22544384);  // qmem fp32 (st 3-7) -> featC4(hi) -> ff3b
    char* slabBC = takeB(16777216);  // qnb+knb (st 3) -> x2 fp32 (st 7+)
    char* slabD  = takeB(8388608);   // qmemb (st 7) -> t1b4(lo)
    char* slabF  = takeB(8388608);   // attnb (st 3-7) -> t1b4(hi)
    char* slabG  = takeB(17301504);  // hb (8.4M) -> mw1b (17.3M) -> w1uT (17.04M) -> h2b
    float* partA = (float*)slabA;
    bf16* vt     = (bf16*)slabA;  bf16* ff1b = (bf16*)slabA;
    bf16* featC4 = (bf16*)slabA;  // 4096x4160x2 = 34.1MB, spans slabA+slabE
    float* qmem  = (float*)slabE; bf16* ff3b = (bf16*)slabE;
    bf16* qnb = (bf16*)slabBC;    bf16* knb = (bf16*)(slabBC + 8388608);
    float* x2 = (float*)slabBC;
    bf16* qmemb = (bf16*)slabD;
    bf16* t1b4  = (bf16*)slabD;   // 4096x2048x2 = 16.8MB, spans slabD+slabF
    bf16* attnb = (bf16*)slabF;
    bf16* hb = (bf16*)slabG;      bf16* mw1b = (bf16*)slabG;
    bf16* w1uT = (bf16*)slabG;    bf16* h2b = (bf16*)slabG;
    // merged qkv output (b,s,3072): q cols 0-1023, k 1024-2047, v 2048-3071
    bf16* qkvb = (bf16*)takeB(25165824);

    // bf16 weights
    bf16* qkvwT = (bf16*)takeB(6291456);
    bf16* gw1T  = (bf16*)takeB(262144);    // 128 rows alloc / 64 real
    bf16* wowT  = (bf16*)takeB(2097152);
    bf16* mw1T  = (bf16*)takeB(17039360);
    bf16* mw2T  = (bf16*)takeB(4194304);
    bf16* fw1T  = (bf16*)takeB(5767168);
    bf16* fw3T  = (bf16*)takeB(5767168);
    bf16* fw2T  = (bf16*)takeB(5636096);
    bf16* mw2b  = (bf16*)takeB(4194304);   // straight copy (2048,1024)
    bf16* mwkTb = (bf16*)takeB(262144);    // (64 real/128 alloc, 1024)
    bf16* wkuTb = (bf16*)takeB(262144);
    bf16* w2uT  = (bf16*)takeB(4194304);   // (1024, 2048)

    // fp32 misc
    float* zf    = (float*)takeB(1048576);
    float* gg1   = (float*)takeB(1048576);
    float* gamma = (float*)takeB(16384);
    float* wvec  = (float*)takeB(512);
    float* scal  = (float*)takeB(256);     // [0]=wsum [2]=sig(gate) [8..10]=invn
    float* psum  = (float*)takeB(131072);
    float* xa    = (float*)takeB(524288);
    float* va    = (float*)takeB(524288);
    float* za    = (float*)takeB(32768);
    float* featA = (float*)takeB(2129920);
    float* ua    = (float*)takeB(1048576);
    float* sua   = (float*)takeB(1048576);
    float* preda = (float*)takeB(524288);
    float* dpreda= (float*)takeB(524288);
    float* dsua  = (float*)takeB(1048576);
    float* dua   = (float*)takeB(1048576);
    float* dfeata= (float*)takeB(2129920);
    float* dza   = (float*)takeB(32768);
    float* SA    = (float*)takeB(196608);  // 3 x 128x128 fp32
    float* CA    = (float*)takeB(196608);
    // bf16 misc
    bf16* featAb = (bf16*)takeB(1064960);
    bf16* suab   = (bf16*)takeB(524288);
    bf16* xab    = (bf16*)takeB(262144);
    bf16* duab   = (bf16*)takeB(524288);
    bf16* dpredab= (bf16*)takeB(262144);
    bf16* dzab   = (bf16*)takeB(16384);
    bf16* PT1Tb  = (bf16*)takeB(524288);   // (2048,128) = P5 for w1
    bf16* PT2Tb  = (bf16*)takeB(262144);   // (1024,128) = P5 for w2
    bf16* PT3Tb  = (bf16*)takeB(32768);
    bf16* duaTb  = (bf16*)takeB(524288);
    bf16* dpredaTb=(bf16*)takeB(262144);
    bf16* dzaTb  = (bf16*)takeB(32768);
    bf16* xaTb   = (bf16*)takeB(262144);
    bf16* featATb= (bf16*)takeB(1081344);  // (4224 alloc/4160 real, 128)
    bf16* suaTb  = (bf16*)takeB(524288);   // (2048, 128)
    // NS bf16
    bf16* Sb16  = (bf16*)takeB(98304);
    bf16* Cb16  = (bf16*)takeB(98304);
    bf16* FcAb  = (bf16*)takeB(98304);
    bf16* FcTAb = (bf16*)takeB(98304);

    auto gemmB = [&](int outbf, int cinbf, const bf16* A, const bf16* Bt,
                     const void* Cin, void* C, int M, int N, int K, int ldc,
                     float alpha, float beta, int act, const float* sptr) {
        dim3 grid((N + 127) / 128, M / 128);
        if (outbf && cinbf) gemm_bt<1, 1><<<grid, 256, 0, stream>>>(A, Bt, Cin, C, M, N, K, ldc, alpha, beta, act, sptr);
        else if (outbf)     gemm_bt<1, 0><<<grid, 256, 0, stream>>>(A, Bt, Cin, C, M, N, K, ldc, alpha, beta, act, sptr);
        else                gemm_bt<0, 0><<<grid, 256, 0, stream>>>(A, Bt, Cin, C, M, N, K, ldc, alpha, beta, act, sptr);
    };
    auto gdir = [&](int outbf, int cinbf, const bf16* A, const bf16* Bt,
                    const void* Cin, void* C, int M, int N, int K, int ldc,
                    float alpha, float beta, int act, const float* sptr) {
        dim3 grid((N + 127) / 128, (M + 127) / 128);
        if (outbf && cinbf)      gemm_direct<1, 1><<<grid, 256, 0, stream>>>(A, Bt, Cin, C, M, N, K, ldc, alpha, beta, act, sptr);
        else if (outbf)          gemm_direct<1, 0><<<grid, 256, 0, stream>>>(A, Bt, Cin, C, M, N, K, ldc, alpha, beta, act, sptr);
        else if (cinbf)          gemm_direct<0, 1><<<grid, 256, 0, stream>>>(A, Bt, Cin, C, M, N, K, ldc, alpha, beta, act, sptr);
        else                     gemm_direct<0, 0><<<grid, 256, 0, stream>>>(A, Bt, Cin, C, M, N, K, ldc, alpha, beta, act, sptr);
    };
    auto skp = [&](const bf16* A, const bf16* Bt, float* out,
                   int M, int N, int K, int KC) {
        int SK = (K + KC - 1) / KC;
        gemm_skp<<<dim3((N + 127) / 128, (M + 127) / 128, SK), 256, 0, stream>>>(A, Bt, partA, M, N, K, KC);
        int MN = M * N;
        skred<<<(MN + 255) / 256, 256, 0, stream>>>(partA, out, SK, MN);
    };
    auto tconv = [&](const float* W, bf16* Wt, int K, int N, int Kpad) {
        tconv_kernel<<<dim3((Kpad + 31) / 32, (N + 31) / 32), 256, 0, stream>>>(W, Wt, K, N, Kpad);
    };

    // 0. weight converts
    tconv(qkvw, qkvwT, Dc, 3 * Dc, Dc);
    tconv(gw1, gw1T, Dc, GGH, Dc);
    tconv(wow, wowT, Dc, Dc, Dc);
    tconv(mw1, mw1T, FPOLY, MHID, FPOLY);
    tconv(mw2, mw2T, MHID, Dc, MHID);
    tconv(fw1, fw1T, Dc, FFNH, Dc);
    tconv(fw3, fw3T, Dc, FFNH, Dc);
    tconv(fw2, fw2T, FFNH, Dc, FFNHP);
    tconv(mwk, mwkTb, Dc, HDc, Dc);
    cvt_kernel<<<2048, 256, 0, stream>>>(mw2, mw2b, MHID * Dc);
    sgate_kernel<<<1, 1, 0, stream>>>(mgate, scal + 2);

    // 1-2. rmsnorm, merged qkv (one GEMM, 768 blocks = 3/CU), gamma
    rms_rows<<<NTOK, 256, 0, stream>>>(x, n1w, hb, Dc);
    gemmB(1, 0, hb, qkvwT, nullptr, qkvb, NTOK, 3 * Dc, Dc, 3 * Dc, 1.f, 0.f, 0, nullptr);
    snr_one<<<dim3(Sc / 4, Hc, Bc), 256, 0, stream>>>(qkvb, qnw, qnb, 0);
    snr_one<<<dim3(Sc / 4, Hc, Bc), 256, 0, stream>>>(qkvb, knw, knb, 1024);
    skp(hb, gw1T, gg1, NTOK, GGH, Dc, 256);        // SK=4, 128 blocks
    gamma_kernel<<<NTOK / 4, 256, 0, stream>>>(gg1, gw2, gamma);
    cvt_kernel<<<2048, 256, 0, stream>>>(mw1, mw1b, FPOLY * MHID);   // hb dead

    // 3. V transpose, q_mem, attention (XCD-clustered 1D grid)
    vtrans_kernel<<<dim3(Sc / 32, 2, Bc * Hc), 256, 0, stream>>>(qkvb, vt);
    kpsum_kernel<<<dim3(Bc * Hc, 16), 64, 0, stream>>>(knb, psum);
    qmem2_kernel<<<dim3(Bc * Hc, 16), 64, 0, stream>>>(qnb, knb, gamma, psum, qmem);
    attn_mfma<<<dim3(1024), 256, 0, stream>>>(qnb, knb, vt, attnb);

    // 4. actives (vt dead -> slabA reusable as partials)
    gather_active<<<NACT, 256, 0, stream>>>(qmem, qkvb, xa, xab, va);
    wvec_kernel<<<1, 128, 0, stream>>>(gamma, wvec, scal);

    // 5. gradient chain (128 active tokens) -- split-K MFMA
    skp(xab, mwkTb, za, NACT, HDc, Dc, 64);                         // SK=16
    phi2_f32<<<dim3((FPOLY + 255) / 256, NACT), 256, 0, stream>>>(za, featA, featAb);
    skp(featAb, mw1T, ua, NACT, MHID, FPOLY, 288);                  // SK=15, 240 blocks
    silu_kernel<<<(NACT * MHID + 255) / 256, 256, 0, stream>>>(ua, sua, suab, NACT * MHID);
    skp(suab, mw2T, preda, NACT, Dc, MHID, 128);                    // SK=16, 128 blocks
    dpred_kernel<<<(NACT * Dc + 255) / 256, 256, 0, stream>>>(preda, va, wvec, scal, dpreda, dpredab);
    skp(dpredab, mw2b, dsua, NACT, MHID, Dc, 128);                  // SK=8, 128 blocks
    dsilu_kernel<<<(NACT * MHID + 255) / 256, 256, 0, stream>>>(dsua, ua, dua, duab, NACT * MHID);
    skp(duab, mw1b, dfeata, NACT, FPOLY, MHID, 256);                // SK=8, 264 blocks
    dz_kernel<<<NACT, 64, 0, stream>>>(dfeata, za, dza, dzab);

    // transposed bf16 copies for the NS/PT/weight-update path
    tconv(dua, duaTb, 128, MHID, 128);
    tconv(dpreda, dpredaTb, 128, Dc, 128);
    tconv(dza, dzaTb, 128, HDc, 128);
    tconv(xa, xaTb, 128, Dc, 128);
    tconv(featA, featATb, 128, FPOLY, 128);
    tconv(sua, suaTb, 128, MHID, 128);

    // 6. Newton-Schulz: fused 5-iteration chain (1 launch, 3 blocks)
    gram_trick<<<1, 256, 0, stream>>>(za, SA);
    skp(suab, suab, SA + 16384, 128, 128, MHID, 64);                // SK=32
    skp(xab, xab, SA + 32768, 128, 128, Dc, 64);                    // SK=16
    skp(duab, duab, CA, 128, 128, MHID, 64);
    skp(dpredab, dpredab, CA + 16384, 128, 128, Dc, 64);
    gdir(0, 0, dzab, dzab, nullptr, CA + 32768, 128, 128, HDc, 128, 1.f, 0.f, 0, nullptr);
    ns_norm_kernel<<<3, 256, 0, stream>>>(SA, CA, Sb16, Cb16, scal + 8);
    ns_fused<<<3, 256, 0, stream>>>(Sb16, Cb16, FcAb, FcTAb);
    // P5 = PTraw^T @ Fc * invn
    gdir(1, 0, duaTb,    FcTAb,         nullptr, PT1Tb, MHID, 128, 128, 128, 1.f, 0.f, 0, scal + 8);
    gdir(1, 0, dpredaTb, FcTAb + 16384, nullptr, PT2Tb, Dc,   128, 128, 128, 1.f, 0.f, 0, scal + 9);
    gdir(1, 0, dzaTb,    FcTAb + 32768, nullptr, PT3Tb, HDc,  128, 128, 128, 1.f, 0.f, 0, scal + 10);

    // wkuT = 0.999*mwkT - 0.01*PT3T@xa
    gdir(1, 1, PT3Tb, xaTb, mwkTb, wkuTb, HDc, Dc, 128, Dc, -0.01f, 0.999f, 0, nullptr);
    //   w1uT = 0.999*mw1T - 0.01*PT1T@featA   (mw1b dead -> slabG reuse)
    gemmB(1, 1, PT1Tb, featATb, mw1T, w1uT, MHID, FPOLY, 128, FPOLY, -0.01f, 0.999f, 0, nullptr);
    //   w2uT = 0.999*mw2T - 0.01*PT2T@sua
    gemmB(1, 1, PT2Tb, suaTb, mw2T, w2uT, Dc, MHID, 128, MHID, -0.01f, 0.999f, 0, nullptr);

    // 7. x2 = x + attn@wo; zf = qmem@wku
    gemmB(0, 0, attnb, wowT, x, x2, NTOK, Dc, Dc, Dc, 1.f, 1.f, 0, nullptr);
    cvt_kernel<<<2048, 256, 0, stream>>>(qmem, qmemb, NTOK * Dc);
    gdir(0, 0, qmemb, wkuTb, nullptr, zf, NTOK, HDc, Dc, HDc, 1.f, 0.f, 0, nullptr);

    // 8. memory forward, de-chunked: M=4096 in one pass (featC4 spans slabA+slabE,
    //    t1b4 spans slabD+slabF; attnb/qmemb/qmem all dead by here)
    phi2_bf16<<<dim3((FPOLY + 255) / 256, NTOK), 256, 0, stream>>>(zf, featC4);
    gemmB(1, 0, featC4, w1uT, nullptr, t1b4, NTOK, MHID, FPOLY, MHID, 1.f, 0.f, 1, nullptr);
    gemmB(0, 0, t1b4, w2uT, x2, x2, NTOK, Dc, MHID, Dc, 1.f, 1.f, 0, scal + 2);

    // 9. FFN (swiglu)
    rms_rows<<<NTOK, 256, 0, stream>>>(x2, n2w, h2b, Dc);
    gemmB(1, 0, h2b, fw1T, nullptr, ff1b, NTOK, FFNH, Dc, FFNHP, 1.f, 0.f, 1, nullptr);
    gemmB(1, 0, h2b, fw3T, nullptr, ff3b, NTOK, FFNH, Dc, FFNHP, 1.f, 0.f, 0, nullptr);
    mulpad_kernel<<<(NTOK * FFNHP + 255) / 256, 256, 0, stream>>>(ff1b, ff3b);
    gemmB(0, 0, ff1b, fw2T, x2, outp, NTOK, Dc, FFNHP, Dc, 1.f, 1.f, 0, nullptr);
}

// Round 6
// 1280.798 us; speedup vs baseline: 1.1798x; 1.0691x over previous
//
#include <hip/hip_runtime.h>
#include <math.h>

#define Bc 2
#define Sc 2048
#define Dc 1024
#define Hc 16
#define HDc 64
#define FPOLY 4160
#define MHID 2048
#define FFNH 2730
#define FFNHP 2752   // FFNH padded to mult of 32 (K pad, zero-filled)
#define GGH 64
#define NTOK 4096
#define NACT 128

typedef __bf16 bf16;
typedef __attribute__((ext_vector_type(8))) __bf16 bf16x8;
typedef __attribute__((ext_vector_type(4))) float f32x4;

#define AS1 __attribute__((address_space(1)))
#define AS3 __attribute__((address_space(3)))

__device__ __forceinline__ void gload16(const void* g, void* l) {
    __builtin_amdgcn_global_load_lds((AS1 const void*)g, (AS3 void*)l, 16, 0, 0);
}

__device__ __forceinline__ float fexp2(float x) { return __builtin_amdgcn_exp2f(x); }

// ---------------------------------------------------------------- bf16 MFMA GEMM (LDS, big tiles)
// C = act(alpha*[sptr]*A@Bt^T + beta*Cin).  A:(M,K) bf16 row-major, Bt:(N,K) bf16.
// K%32==0, M%128==0. N arbitrary; Bt rows allocated to ceil(N/128)*128.
// 2-phase stage-ahead pipeline (T3-min) + bijective XCD-clustering swizzle (T1/m204):
// consecutive flat block ids land on one XCD -> A/B panel reuse hits that XCD's L2.
template<int OUTBF, int CINBF>
__global__ __launch_bounds__(256) void gemm_bt(
    const bf16* __restrict__ A, const bf16* __restrict__ Bt,
    const void* __restrict__ Cin, void* __restrict__ Cout,
    int M, int N, int K, int ldc,
    float alpha, float beta, int act, const float* __restrict__ sptr)
{
    __shared__ bf16 As[2][128 * 32];
    __shared__ bf16 Bs[2][128 * 32];
    const int tid = threadIdx.x;
    const int w = tid >> 6, lane = tid & 63;
    // m204 bijective XCD swizzle on the flattened block index
    const int gridX = gridDim.x;
    const int nwg = gridX * gridDim.y;
    const int orig = blockIdx.y * gridX + blockIdx.x;
    const int q8 = nwg >> 3, r8 = nwg & 7;
    const int xcd = orig & 7, lid = orig >> 3;
    const int sbase = (xcd < r8) ? xcd * (q8 + 1) : r8 * (q8 + 1) + (xcd - r8) * q8;
    const int swzid = sbase + lid;
    const int bm = (swzid / gridX) * 128, bn = (swzid % gridX) * 128;
    const int wm = (w >> 1) * 64, wn = (w & 1) * 64;
    f32x4 acc[4][4];
#pragma unroll
    for (int i = 0; i < 4; ++i)
#pragma unroll
        for (int j = 0; j < 4; ++j) { acc[i][j][0] = 0.f; acc[i][j][1] = 0.f; acc[i][j][2] = 0.f; acc[i][j][3] = 0.f; }
    const int idx0 = tid, idx1 = tid + 256;
    const int r0 = idx0 >> 2, r1 = idx1 >> 2;
    const int g0 = ((idx0 & 3) ^ ((r0 >> 1) & 3)) * 8;
    const int g1 = ((idx1 & 3) ^ ((r1 >> 1) & 3)) * 8;
    const int lrow = lane & 15;
    const int q = lane >> 4;
    int aoff[4], boff[4];
#pragma unroll
    for (int t = 0; t < 4; ++t) {
        int ar = wm + t * 16 + lrow;
        aoff[t] = ar * 32 + ((q ^ ((ar >> 1) & 3)) * 8);
        int br = wn + t * 16 + lrow;
        boff[t] = br * 32 + ((q ^ ((br >> 1) & 3)) * 8);
    }
    const bf16* Arow0 = A + (size_t)(bm + r0) * K + g0;
    const bf16* Arow1 = A + (size_t)(bm + r1) * K + g1;
    const bf16* Brow0 = Bt + (size_t)(bn + r0) * K + g0;
    const bf16* Brow1 = Bt + (size_t)(bn + r1) * K + g1;
    auto stage = [&](int bi, int k0) {
        char* la = (char*)&As[bi][0] + w * 1024;
        char* lb = (char*)&Bs[bi][0] + w * 1024;
        gload16(Arow0 + k0, la);
        gload16(Arow1 + k0, la + 4096);
        gload16(Brow0 + k0, lb);
        gload16(Brow1 + k0, lb + 4096);
    };
    auto compute = [&](int bi) {
        bf16x8 af[4], bfr[4];
#pragma unroll
        for (int t = 0; t < 4; ++t) af[t] = *(const bf16x8*)&As[bi][aoff[t]];
#pragma unroll
        for (int t = 0; t < 4; ++t) bfr[t] = *(const bf16x8*)&Bs[bi][boff[t]];
#pragma unroll
        for (int mt = 0; mt < 4; ++mt)
#pragma unroll
            for (int nt = 0; nt < 4; ++nt)
                acc[mt][nt] = __builtin_amdgcn_mfma_f32_16x16x32_bf16(af[mt], bfr[nt], acc[mt][nt], 0, 0, 0);
    };
    stage(0, 0);
    __syncthreads();
    int buf = 0;
    for (int k0 = 32; k0 < K; k0 += 32) {
        stage(buf ^ 1, k0);
        compute(buf);
        __syncthreads();
        buf ^= 1;
    }
    compute(buf);
    const float amul = alpha * (sptr ? *sptr : 1.f);
#pragma unroll
    for (int nt = 0; nt < 4; ++nt) {
        const int col = bn + wn + nt * 16 + lrow;
        if (col >= N) continue;
#pragma unroll
        for (int mt = 0; mt < 4; ++mt) {
            const int rbase = bm + wm + mt * 16 + q * 4;
#pragma unroll
            for (int r = 0; r < 4; ++r) {
                const size_t o = (size_t)(rbase + r) * ldc + col;
                float v = amul * acc[mt][nt][r];
                if (beta != 0.f)
                    v += beta * (CINBF ? (float)((const bf16*)Cin)[o] : ((const float*)Cin)[o]);
                if (act == 1) v = v / (1.f + __expf(-v));
                if (OUTBF) ((bf16*)Cout)[o] = (bf16)v;
                else       ((float*)Cout)[o] = v;
            }
        }
    }
}

// ---------------------------------------------------------------- barrier-free direct MFMA GEMM
template<int OUTBF, int CINBF>
__global__ __launch_bounds__(256) void gemm_direct(
    const bf16* __restrict__ A, const bf16* __restrict__ Bt,
    const void* __restrict__ Cin, void* __restrict__ Cout,
    int M, int N, int K, int ldc,
    float alpha, float beta, int act, const float* __restrict__ sptr)
{
    const int tid = threadIdx.x, w = tid >> 6, lane = tid & 63;
    const int lrow = lane & 15, quad = lane >> 4;
    const int bm = blockIdx.y * 128 + w * 32;
    const int bn = blockIdx.x * 128;
    f32x4 acc[2][8];
#pragma unroll
    for (int mt = 0; mt < 2; ++mt)
#pragma unroll
        for (int nt = 0; nt < 8; ++nt) { acc[mt][nt][0] = 0.f; acc[mt][nt][1] = 0.f; acc[mt][nt][2] = 0.f; acc[mt][nt][3] = 0.f; }
    const bf16* Abase = A + (size_t)(bm + lrow) * K + quad * 8;
    const bf16* Bbase = Bt + (size_t)(bn + lrow) * K + quad * 8;
#pragma unroll 2
    for (int k0 = 0; k0 < K; k0 += 32) {
        bf16x8 af0 = *(const bf16x8*)(Abase + k0);
        bf16x8 af1 = *(const bf16x8*)(Abase + (size_t)16 * K + k0);
#pragma unroll
        for (int nt = 0; nt < 8; ++nt) {
            bf16x8 bfr = *(const bf16x8*)(Bbase + (size_t)nt * 16 * K + k0);
            acc[0][nt] = __builtin_amdgcn_mfma_f32_16x16x32_bf16(af0, bfr, acc[0][nt], 0, 0, 0);
            acc[1][nt] = __builtin_amdgcn_mfma_f32_16x16x32_bf16(af1, bfr, acc[1][nt], 0, 0, 0);
        }
    }
    const float amul = alpha * (sptr ? *sptr : 1.f);
#pragma unroll
    for (int nt = 0; nt < 8; ++nt) {
        const int col = bn + nt * 16 + lrow;
        if (col >= N) continue;
#pragma unroll
        for (int mt = 0; mt < 2; ++mt) {
            const int rbase = bm + mt * 16 + quad * 4;
#pragma unroll
            for (int r = 0; r < 4; ++r) {
                const int row = rbase + r;
                if (row >= M) continue;
                const size_t o = (size_t)row * ldc + col;
                float v = amul * acc[mt][nt][r];
                if (beta != 0.f)
                    v += beta * (CINBF ? (float)((const bf16*)Cin)[o] : ((const float*)Cin)[o]);
                if (act == 1) v = v / (1.f + __expf(-v));
                if (OUTBF) ((bf16*)Cout)[o] = (bf16)v;
                else       ((float*)Cout)[o] = v;
            }
        }
    }
}

// ---------------------------------------------------------------- split-K direct GEMM
__global__ __launch_bounds__(256) void gemm_skp(
    const bf16* __restrict__ A, const bf16* __restrict__ Bt,
    float* __restrict__ part, int M, int N, int K, int KC)
{
    const int tid = threadIdx.x, w = tid >> 6, lane = tid & 63;
    const int lrow = lane & 15, quad = lane >> 4;
    const int bm = blockIdx.y * 128 + w * 32;
    const int bn = blockIdx.x * 128;
    const int z = blockIdx.z;
    const int kb = z * KC;
    int ke = kb + KC; if (ke > K) ke = K;
    f32x4 acc[2][8];
#pragma unroll
    for (int mt = 0; mt < 2; ++mt)
#pragma unroll
        for (int nt = 0; nt < 8; ++nt) { acc[mt][nt][0] = 0.f; acc[mt][nt][1] = 0.f; acc[mt][nt][2] = 0.f; acc[mt][nt][3] = 0.f; }
    const bf16* Abase = A + (size_t)(bm + lrow) * K + quad * 8;
    const bf16* Bbase = Bt + (size_t)(bn + lrow) * K + quad * 8;
#pragma unroll 2
    for (int k0 = kb; k0 < ke; k0 += 32) {
        bf16x8 af0 = *(const bf16x8*)(Abase + k0);
        bf16x8 af1 = *(const bf16x8*)(Abase + (size_t)16 * K + k0);
#pragma unroll
        for (int nt = 0; nt < 8; ++nt) {
            bf16x8 bfr = *(const bf16x8*)(Bbase + (size_t)nt * 16 * K + k0);
            acc[0][nt] = __builtin_amdgcn_mfma_f32_16x16x32_bf16(af0, bfr, acc[0][nt], 0, 0, 0);
            acc[1][nt] = __builtin_amdgcn_mfma_f32_16x16x32_bf16(af1, bfr, acc[1][nt], 0, 0, 0);
        }
    }
    float* po = part + (size_t)z * M * N;
#pragma unroll
    for (int nt = 0; nt < 8; ++nt) {
        const int col = bn + nt * 16 + lrow;
        if (col >= N) continue;
#pragma unroll
        for (int mt = 0; mt < 2; ++mt) {
            const int rbase = bm + mt * 16 + quad * 4;
#pragma unroll
            for (int r = 0; r < 4; ++r) {
                const int row = rbase + r;
                if (row >= M) continue;
                po[(size_t)row * N + col] = acc[mt][nt][r];
            }
        }
    }
}

__global__ void skred(const float* __restrict__ part, float* __restrict__ out,
                      int SK, int MN)
{
    int i = blockIdx.x * 256 + threadIdx.x;
    if (i >= MN) return;
    float s = 0.f;
    for (int z = 0; z < SK; ++z) s += part[(size_t)z * MN + i];
    out[i] = s;
}

// ---------------------------------------------------------------- batched 128x128 gram: X@X^T
// 5 matrices in one launch: m=0 sua(K2048) ->SA+16384, 1 xa(1024)->SA+32768,
// 2 dua(2048)->CA, 3 dpred(1024)->CA+16384, 4 dz(64)->CA+32768.
// grid (32, 5): z = K-chunk of 64 (same KC=64 order as the old skp's -> identical sums).
__global__ __launch_bounds__(256) void gram_bat(
    const bf16* __restrict__ X0, const bf16* __restrict__ X1,
    const bf16* __restrict__ X2, const bf16* __restrict__ X3,
    const bf16* __restrict__ X4, float* __restrict__ part)
{
    const int z = blockIdx.x, m = blockIdx.y;
    const bf16* A; int K;
    if      (m == 0) { A = X0; K = 2048; }
    else if (m == 1) { A = X1; K = 1024; }
    else if (m == 2) { A = X2; K = 2048; }
    else if (m == 3) { A = X3; K = 1024; }
    else             { A = X4; K = 64;   }
    if (z * 64 >= K) return;
    const int tid = threadIdx.x, w = tid >> 6, lane = tid & 63;
    const int lrow = lane & 15, quad = lane >> 4;
    const int bm = w * 32;
    f32x4 acc[2][8];
#pragma unroll
    for (int mt = 0; mt < 2; ++mt)
#pragma unroll
        for (int nt = 0; nt < 8; ++nt) { acc[mt][nt][0] = 0.f; acc[mt][nt][1] = 0.f; acc[mt][nt][2] = 0.f; acc[mt][nt][3] = 0.f; }
    const bf16* Abase = A + (size_t)(bm + lrow) * K + quad * 8;
    const bf16* Bbase = A + (size_t)lrow * K + quad * 8;
#pragma unroll 2
    for (int k0 = z * 64; k0 < z * 64 + 64; k0 += 32) {
        bf16x8 af0 = *(const bf16x8*)(Abase + k0);
        bf16x8 af1 = *(const bf16x8*)(Abase + (size_t)16 * K + k0);
#pragma unroll
        for (int nt = 0; nt < 8; ++nt) {
            bf16x8 bfr = *(const bf16x8*)(Bbase + (size_t)nt * 16 * K + k0);
            acc[0][nt] = __builtin_amdgcn_mfma_f32_16x16x32_bf16(af0, bfr, acc[0][nt], 0, 0, 0);
            acc[1][nt] = __builtin_amdgcn_mfma_f32_16x16x32_bf16(af1, bfr, acc[1][nt], 0, 0, 0);
        }
    }
    float* po = part + (size_t)(m * 32 + z) * 16384;
#pragma unroll
    for (int nt = 0; nt < 8; ++nt) {
        const int col = nt * 16 + lrow;
#pragma unroll
        for (int mt = 0; mt < 2; ++mt)
#pragma unroll
            for (int r = 0; r < 4; ++r)
                po[(size_t)(bm + mt * 16 + quad * 4 + r) * 128 + col] = acc[mt][nt][r];
    }
}

__global__ void gram_red(const float* __restrict__ part,
                         float* __restrict__ SA, float* __restrict__ CA)
{
    int idx = blockIdx.x * 256 + threadIdx.x;   // 5*16384
    if (idx >= 81920) return;
    int m = idx >> 14, e = idx & 16383;
    int SK = (m == 0 || m == 2) ? 32 : (m == 4 ? 1 : 16);
    float s = 0.f;
    for (int z = 0; z < SK; ++z) s += part[(size_t)(m * 32 + z) * 16384 + e];
    float* dst = (m == 0) ? SA + 16384 : (m == 1) ? SA + 32768 :
                 (m == 2) ? CA : (m == 3) ? CA + 16384 : CA + 32768;
    dst[e] = s;
}

// ---------------------------------------------------------------- polynomial-kernel gram
__global__ __launch_bounds__(256) void gram_trick(
    const float* __restrict__ za, float* __restrict__ S)
{
    __shared__ float z[128 * 65];
    for (int i = threadIdx.x; i < 8192; i += 256) {
        int r = i >> 6, d = i & 63;
        z[r * 65 + d] = za[i];
    }
    __syncthreads();
    for (int idx = threadIdx.x; idx < 16384; idx += 256) {
        int i = idx >> 7, j = idx & 127;
        float dot = 0.f;
#pragma unroll
        for (int d = 0; d < 64; ++d) dot += z[i * 65 + d] * z[j * 65 + d];
        S[idx] = dot + dot * dot * 0.015625f;
    }
}

__global__ __launch_bounds__(256) void ns_norm_kernel(
    const float* __restrict__ S, const float* __restrict__ C,
    bf16* __restrict__ Sb, bf16* __restrict__ Cb, float* __restrict__ invn)
{
    const int z = blockIdx.x;
    const float* s = S + (size_t)z * 16384;
    const float* c = C + (size_t)z * 16384;
    float acc = 0.f;
    for (int i = threadIdx.x; i < 16384; i += 256) acc += s[i] * c[i];
    __shared__ float red[256];
    red[threadIdx.x] = acc; __syncthreads();
    for (int st = 128; st; st >>= 1) {
        if (threadIdx.x < st) red[threadIdx.x] += red[threadIdx.x + st];
        __syncthreads();
    }
    float inv = 1.f / (sqrtf(red[0]) + 1e-7f);
    float inv2 = inv * inv;
    for (int i = threadIdx.x; i < 16384; i += 256) {
        Cb[(size_t)z * 16384 + i] = (bf16)(c[i] * inv2);
        Sb[(size_t)z * 16384 + i] = (bf16)s[i];
    }
    if (threadIdx.x == 0) invn[z] = inv;
}

// ---------------------------------------------------------------- fused Newton-Schulz (batched z=3)
__device__ __forceinline__ int swz(int row, int col) {
    return row * 128 + ((((col >> 3) ^ (row & 7)) << 3) | (col & 7));
}

__global__ __launch_bounds__(256) void ns_fused(
    const bf16* __restrict__ Sg, const bf16* __restrict__ Cg,
    bf16* __restrict__ Fcg, bf16* __restrict__ FcTg)
{
    __shared__ bf16 Cl[16384], Ml[16384], MTl[16384], FTl[16384];
    const int z = blockIdx.x;
    const bf16* S = Sg + (size_t)z * 16384;
    bf16* Fc = Fcg + (size_t)z * 16384;
    bf16* FcT = FcTg + (size_t)z * 16384;
    const int tid = threadIdx.x, w = tid >> 6, lane = tid & 63;
    const int lrow = lane & 15, quad = lane >> 4;
    const int bm = w * 32;
    for (int i = tid; i < 2048; i += 256) {
        const int row = i >> 4, c = i & 15;
        *(bf16x8*)&Cl[row * 128 + ((c ^ (row & 7)) << 3)] =
            *(const bf16x8*)(Cg + (size_t)z * 16384 + (size_t)row * 128 + c * 8);
    }
    __syncthreads();
    const int r0 = bm + lrow, r1 = r0 + 16;
    const int rx = lrow & 7;
    f32x4 acc[2][8];
    auto zacc = [&]() {
#pragma unroll
        for (int mt = 0; mt < 2; ++mt)
#pragma unroll
            for (int nt = 0; nt < 8; ++nt) { acc[mt][nt][0] = 0.f; acc[mt][nt][1] = 0.f; acc[mt][nt][2] = 0.f; acc[mt][nt][3] = 0.f; }
    };
    auto inner = [&](bf16x8 af0, bf16x8 af1, const bf16* Bt, int c) {
#pragma unroll
        for (int nt = 0; nt < 8; ++nt) {
            const int br = nt * 16 + lrow;
            bf16x8 bfr = *(const bf16x8*)&Bt[br * 128 + ((c ^ (br & 7)) << 3)];
            acc[0][nt] = __builtin_amdgcn_mfma_f32_16x16x32_bf16(af0, bfr, acc[0][nt], 0, 0, 0);
            acc[1][nt] = __builtin_amdgcn_mfma_f32_16x16x32_bf16(af1, bfr, acc[1][nt], 0, 0, 0);
        }
    };
    auto gemm_ll = [&](const bf16* Al, const bf16* Bt) {
        zacc();
#pragma unroll
        for (int k0 = 0; k0 < 128; k0 += 32) {
            const int c = (k0 >> 3) + quad;
            bf16x8 af0 = *(const bf16x8*)&Al[r0 * 128 + ((c ^ rx) << 3)];
            bf16x8 af1 = *(const bf16x8*)&Al[r1 * 128 + ((c ^ rx) << 3)];
            inner(af0, af1, Bt, c);
        }
    };
    auto gemm_gl = [&](const bf16* Ag, const bf16* Bt) {
        zacc();
#pragma unroll
        for (int k0 = 0; k0 < 128; k0 += 32) {
            const int c = (k0 >> 3) + quad;
            bf16x8 af0 = *(const bf16x8*)(Ag + (size_t)r0 * 128 + k0 + quad * 8);
            bf16x8 af1 = *(const bf16x8*)(Ag + (size_t)r1 * 128 + k0 + quad * 8);
            inner(af0, af1, Bt, c);
        }
    };

    for (int t = 0; t < 5; ++t) {
        gemm_gl(S, Cl);
#pragma unroll
        for (int mt = 0; mt < 2; ++mt)
#pragma unroll
            for (int nt = 0; nt < 8; ++nt)
#pragma unroll
                for (int r = 0; r < 4; ++r) {
                    const int row = bm + mt * 16 + quad * 4 + r, col = nt * 16 + lrow;
                    const bf16 v = (bf16)acc[mt][nt][r];
                    Ml[swz(row, col)] = v;
                    MTl[swz(col, row)] = v;
                }
        __syncthreads();
        gemm_ll(Ml, MTl);
#pragma unroll
        for (int mt = 0; mt < 2; ++mt)
#pragma unroll
            for (int nt = 0; nt < 8; ++nt)
#pragma unroll
                for (int r = 0; r < 4; ++r) {
                    const int row = bm + mt * 16 + quad * 4 + r, col = nt * 16 + lrow;
                    float v = 2.0315f * acc[mt][nt][r] - 4.775f * (float)Ml[swz(row, col)];
                    if (row == col) v += 3.4445f;
                    FTl[swz(col, row)] = (bf16)v;
                    if (t == 0) Fc[(size_t)row * 128 + col] = (bf16)v;
                }
        __syncthreads();
        if (t > 0) {
            gemm_gl(Fc, FTl);
            if (t == 4) {
#pragma unroll
                for (int mt = 0; mt < 2; ++mt)
#pragma unroll
                    for (int nt = 0; nt < 8; ++nt)
#pragma unroll
                        for (int r = 0; r < 4; ++r) {
                            const int row = bm + mt * 16 + quad * 4 + r, col = nt * 16 + lrow;
                            FcT[(size_t)col * 128 + row] = (bf16)acc[mt][nt][r];
                        }
                return;
            }
#pragma unroll
            for (int mt = 0; mt < 2; ++mt)
#pragma unroll
                for (int nt = 0; nt < 8; ++nt)
#pragma unroll
                    for (int r = 0; r < 4; ++r) {
                        const int row = bm + mt * 16 + quad * 4 + r, col = nt * 16 + lrow;
                        Fc[(size_t)row * 128 + col] = (bf16)acc[mt][nt][r];
                    }
        }
        gemm_ll(Cl, FTl);
#pragma unroll
        for (int mt = 0; mt < 2; ++mt)
#pragma unroll
            for (int nt = 0; nt < 8; ++nt)
#pragma unroll
                for (int r = 0; r < 4; ++r) {
                    const int row = bm + mt * 16 + quad * 4 + r, col = nt * 16 + lrow;
                    Ml[swz(col, row)] = (bf16)acc[mt][nt][r];
                }
        __syncthreads();
        gemm_ll(Ml, FTl);
#pragma unroll
        for (int mt = 0; mt < 2; ++mt)
#pragma unroll
            for (int nt = 0; nt < 8; ++nt)
#pragma unroll
                for (int r = 0; r < 4; ++r) {
                    const int row = bm + mt * 16 + quad * 4 + r, col = nt * 16 + lrow;
                    Cl[swz(row, col)] = (bf16)acc[mt][nt][r];
                }
        __syncthreads();
    }
}

// ---------------------------------------------------------------- converts
__global__ __launch_bounds__(256) void tconv_kernel(
    const float* __restrict__ W, bf16* __restrict__ Wt, int K, int N, int Kpad)
{
    __shared__ float t[32][33];
    const int k0 = blockIdx.x * 32, n0 = blockIdx.y * 32;
    const int tx = threadIdx.x & 31, ty = threadIdx.x >> 5;
#pragma unroll
    for (int r = 0; r < 4; ++r) {
        int gk = k0 + ty + r * 8, gn = n0 + tx;
        t[ty + r * 8][tx] = (gk < K && gn < N) ? W[(size_t)gk * N + gn] : 0.f;
    }
    __syncthreads();
#pragma unroll
    for (int r = 0; r < 4; ++r) {
        int gn = n0 + ty + r * 8, gk = k0 + tx;
        if (gn < N && gk < Kpad) Wt[(size_t)gn * Kpad + gk] = (bf16)t[tx][ty + r * 8];
    }
}

// six 128-row transposed bf16 copies in one launch (all K=128, Kpad=128)
__global__ __launch_bounds__(256) void tconv6_kernel(
    const float* __restrict__ s0, const float* __restrict__ s1,
    const float* __restrict__ s2, const float* __restrict__ s3,
    const float* __restrict__ s4, const float* __restrict__ s5,
    bf16* __restrict__ d0, bf16* __restrict__ d1, bf16* __restrict__ d2,
    bf16* __restrict__ d3, bf16* __restrict__ d4, bf16* __restrict__ d5)
{
    const int zz = blockIdx.z;
    const float* W; bf16* Wt; int N;
    if      (zz == 0) { W = s0; Wt = d0; N = 2048; }
    else if (zz == 1) { W = s1; Wt = d1; N = 1024; }
    else if (zz == 2) { W = s2; Wt = d2; N = 64;   }
    else if (zz == 3) { W = s3; Wt = d3; N = 1024; }
    else if (zz == 4) { W = s4; Wt = d4; N = 4160; }
    else              { W = s5; Wt = d5; N = 2048; }
    const int k0 = blockIdx.x * 32, n0 = blockIdx.y * 32;
    if (n0 >= N) return;
    __shared__ float t[32][33];
    const int tx = threadIdx.x & 31, ty = threadIdx.x >> 5;
#pragma unroll
    for (int r = 0; r < 4; ++r) {
        int gk = k0 + ty + r * 8, gn = n0 + tx;
        t[ty + r * 8][tx] = (gk < 128 && gn < N) ? W[(size_t)gk * N + gn] : 0.f;
    }
    __syncthreads();
#pragma unroll
    for (int r = 0; r < 4; ++r) {
        int gn = n0 + ty + r * 8, gk = k0 + tx;
        if (gn < N) Wt[(size_t)gn * 128 + gk] = (bf16)t[tx][ty + r * 8];
    }
}

__global__ void cvt_kernel(const float* __restrict__ in, bf16* __restrict__ out, int n)
{
    for (int i = blockIdx.x * 256 + threadIdx.x; i < n; i += gridDim.x * 256)
        out[i] = (bf16)in[i];
}

// qkv (b,s,3072) v-part -> vt (b,h,d,s)
__global__ __launch_bounds__(256) void vtrans_kernel(
    const bf16* __restrict__ qkv, bf16* __restrict__ vt)
{
    __shared__ bf16 t[32][33];
    const int s0 = blockIdx.x * 32, d0 = blockIdx.y * 32, bh = blockIdx.z;
    const int b = bh >> 4, h = bh & 15;
    const int tx = threadIdx.x & 31, ty = threadIdx.x >> 5;
#pragma unroll
    for (int r = 0; r < 4; ++r) {
        int s = s0 + ty + r * 8;
        t[ty + r * 8][tx] = qkv[((size_t)b * Sc + s) * 3072 + 2048 + h * 64 + d0 + tx];
    }
    __syncthreads();
#pragma unroll
    for (int r = 0; r < 4; ++r) {
        int d = d0 + ty + r * 8;
        vt[((size_t)bh * 64 + d) * Sc + s0 + tx] = t[tx][ty + r * 8];
    }
}

// ---------------------------------------------------------------- small kernels
__global__ __launch_bounds__(256) void rms_rows(
    const float* __restrict__ in, const float* __restrict__ w,
    bf16* __restrict__ out, int D)
{
    const int row = blockIdx.x;
    const float* r = in + (size_t)row * D;
    bf16* o = out + (size_t)row * D;
    float s = 0.f;
    for (int i = threadIdx.x; i < D; i += 256) { float v = r[i]; s += v * v; }
    __shared__ float red[256];
    red[threadIdx.x] = s;
    __syncthreads();
    for (int st = 128; st; st >>= 1) {
        if (threadIdx.x < st) red[threadIdx.x] += red[threadIdx.x + st];
        __syncthreads();
    }
    float rs = rsqrtf(red[0] / (float)D + 1e-6f);
    for (int i = threadIdx.x; i < D; i += 256) o[i] = (bf16)(r[i] * rs * w[i]);
}

__global__ __launch_bounds__(256) void gamma_kernel(
    const float* __restrict__ gg1, const float* __restrict__ w2,
    float* __restrict__ gamma)
{
    const int tid = threadIdx.x, w = tid >> 6, lane = tid & 63;
    const int t = blockIdx.x * 4 + w;
    float v = gg1[(size_t)t * GGH + lane];
    v = v / (1.f + expf(-v));
    v *= w2[lane];
#pragma unroll
    for (int off = 32; off; off >>= 1) v += __shfl_xor(v, off);
    if (lane == 0) gamma[t] = 1.f / (1.f + expf(-v));
}

// rmsnorm+rope for q AND k in one launch: blockIdx.y in [0,32): y>>4 selects q/k
__global__ __launch_bounds__(256) void snr_qk(
    const bf16* __restrict__ src, const float* __restrict__ qw, const float* __restrict__ kw,
    bf16* __restrict__ qd, bf16* __restrict__ kd)
{
    const int tid = threadIdx.x, wv = tid >> 6, lane = tid & 63;
    const int s = blockIdx.x * 4 + wv;
    const int y = blockIdx.y, b = blockIdx.z;
    const int h = y & 15, which = y >> 4;
    const float* w = which ? kw : qw;
    bf16* dst = which ? kd : qd;
    const size_t row = ((size_t)b * Sc + s) * 3072 + which * 1024 + h * 64;
    float v = (float)src[row + lane];
    float ss = v * v;
#pragma unroll
    for (int off = 32; off; off >>= 1) ss += __shfl_xor(ss, off);
    v = v * rsqrtf(ss / 64.f + 1e-6f) * w[lane];
    const int j = lane & 31;
    float inv = powf(10000.f, -(float)j / 32.f);
    float ang = (float)s * inv;
    float sn = sinf(ang), cs = cosf(ang);
    float p = __shfl_xor(v, 32);
    float o;
    if (lane < 32) o = v * cs - p * sn;
    else           o = p * sn + v * cs;
    const size_t od = (((size_t)b * Hc + h) * Sc + s) * 64 + lane;
    dst[od] = (bf16)o;
}

__global__ void kpsum_kernel(const bf16* __restrict__ kn, float* __restrict__ psum)
{
    const int bh = blockIdx.x, c = blockIdx.y, d = threadIdx.x;
    const size_t base = (size_t)bh * Sc * 64 + (size_t)c * 128 * 64 + d;
    float s = 0.f;
    for (int i = 0; i < 128; ++i) s += (float)kn[base + (size_t)i * 64];
    psum[((size_t)bh * 16 + c) * 64 + d] = s;
}

__global__ void qmem2_kernel(
    const bf16* __restrict__ qn, const bf16* __restrict__ kn,
    const float* __restrict__ gamma, const float* __restrict__ psum,
    float* __restrict__ qmem)
{
    const int bh = blockIdx.x, c = blockIdx.y;
    const int b = bh >> 4, hh = bh & 15;
    const int d = threadIdx.x;
    const size_t base = (size_t)bh * Sc * 64;
    float run = 0.f;
    for (int cc = 0; cc < c; ++cc) run += psum[((size_t)bh * 16 + cc) * 64 + d];
    for (int s = c * 128; s < c * 128 + 128; ++s) {
        run += (float)kn[base + (size_t)s * 64 + d];
        float cm = run / (float)(s + 1);
        float g = gamma[b * Sc + s];
        float qv = (float)qn[base + (size_t)s * 64 + d];
        qmem[((size_t)(b * Sc + s)) * Dc + hh * 64 + d] = g * qv + (1.f - g) * cm;
    }
}

// ---------------------------------------------------------------- MFMA flash attention
// (unchanged from R5: fixed-bound softmax, balanced pairs, k-parity split, XCD swizzle)
__global__ __launch_bounds__(256, 4) void attn_mfma(
    const bf16* __restrict__ qn, const bf16* __restrict__ kn,
    const bf16* __restrict__ vt, bf16* __restrict__ outp)
{
    const int flat = blockIdx.x;
    const int glow = flat & 7, t2 = flat >> 3;
    const int xq = t2 & 31, ghigh = t2 >> 5;
    const int g = glow | (ghigh << 3);
    const int h = g & 15, b = g >> 4;
    const int bh = b * Hc + h;
    const int tid = threadIdx.x, w = tid >> 6, lane = tid & 63;
    const int lrow = lane & 15, quad = lane >> 4;
    const int rhalf = w & 1, pgrp = w >> 1;
    __shared__ bf16 Ps[4][16][136];
    __shared__ float Ob[2][16][68];
    __shared__ float Lb[2][16];
    const bf16* kbase = kn + (size_t)bh * Sc * 64;
    const bf16* vtb = vt + (size_t)bh * 64 * Sc;
    const float SC = 0.1803368801f;   // 0.125 * log2(e)
#pragma unroll 1
    for (int ti = 0; ti < 2; ++ti) {
        const int zt = ti ? (63 - xq) : xq;
        const int qb = zt * 32;
        const int nc = (qb >> 7) + 1;
        const int par = pgrp ^ ti;
        const int rowg = qb + rhalf * 16 + quad * 4;
        bf16x8 qf[2];
        const bf16* qbase = qn + ((size_t)bh * Sc + qb + rhalf * 16) * 64;
#pragma unroll
        for (int ks = 0; ks < 2; ++ks)
            qf[ks] = *(const bf16x8*)(qbase + (size_t)lrow * 64 + ks * 32 + quad * 8);
        f32x4 oacc[4];
#pragma unroll
        for (int nt = 0; nt < 4; ++nt) { oacc[nt][0] = 0.f; oacc[nt][1] = 0.f; oacc[nt][2] = 0.f; oacc[nt][3] = 0.f; }
        float lsum[4] = {0.f, 0.f, 0.f, 0.f};
        for (int ci = par; ci < nc; ci += 2) {
            const int k0 = ci << 7;
            f32x4 sacc[8];
#pragma unroll
            for (int nt = 0; nt < 8; ++nt) { sacc[nt][0] = 0.f; sacc[nt][1] = 0.f; sacc[nt][2] = 0.f; sacc[nt][3] = 0.f; }
            __builtin_amdgcn_s_setprio(1);
#pragma unroll
            for (int ks = 0; ks < 2; ++ks) {
#pragma unroll
                for (int nh = 0; nh < 2; ++nh) {
                    bf16x8 kf[4];
#pragma unroll
                    for (int j = 0; j < 4; ++j)
                        kf[j] = *(const bf16x8*)(kbase + (size_t)(k0 + (nh * 4 + j) * 16 + lrow) * 64 + ks * 32 + quad * 8);
#pragma unroll
                    for (int j = 0; j < 4; ++j)
                        sacc[nh * 4 + j] = __builtin_amdgcn_mfma_f32_16x16x32_bf16(qf[ks], kf[j], sacc[nh * 4 + j], 0, 0, 0);
                }
            }
            __builtin_amdgcn_s_setprio(0);
#pragma unroll
            for (int nt = 0; nt < 8; ++nt) {
                const int kc = k0 + nt * 16 + lrow;
#pragma unroll
                for (int r = 0; r < 4; ++r) {
                    float p = (kc > rowg + r) ? 0.f : fexp2(fmaf(sacc[nt][r], SC, -12.f));
                    sacc[nt][r] = p;
                    lsum[r] += p;
                }
            }
#pragma unroll
            for (int nt = 0; nt < 8; ++nt)
#pragma unroll
                for (int r = 0; r < 4; ++r)
                    Ps[w][quad * 4 + r][nt * 16 + lrow] = (bf16)sacc[nt][r];
            __builtin_amdgcn_s_setprio(1);
#pragma unroll
            for (int ks2 = 0; ks2 < 4; ++ks2) {
                bf16x8 pf = *(const bf16x8*)&Ps[w][lrow][ks2 * 32 + quad * 8];
#pragma unroll
                for (int nt = 0; nt < 4; ++nt) {
                    bf16x8 vf = *(const bf16x8*)(vtb + (size_t)(nt * 16 + lrow) * Sc + k0 + ks2 * 32 + quad * 8);
                    oacc[nt] = __builtin_amdgcn_mfma_f32_16x16x32_bf16(pf, vf, oacc[nt], 0, 0, 0);
                }
            }
            __builtin_amdgcn_s_setprio(0);
        }
#pragma unroll
        for (int r = 0; r < 4; ++r)
#pragma unroll
            for (int off = 1; off < 16; off <<= 1) lsum[r] += __shfl_xor(lsum[r], off);
        if (pgrp == 1) {
#pragma unroll
            for (int nt = 0; nt < 4; ++nt)
#pragma unroll
                for (int r = 0; r < 4; ++r)
                    Ob[rhalf][quad * 4 + r][nt * 16 + lrow] = oacc[nt][r];
            if (lrow == 0)
#pragma unroll
                for (int r = 0; r < 4; ++r) Lb[rhalf][quad * 4 + r] = lsum[r];
        }
        __syncthreads();
        if (pgrp == 0) {
            float linv[4];
#pragma unroll
            for (int r = 0; r < 4; ++r)
                linv[r] = 1.f / (lsum[r] + Lb[rhalf][quad * 4 + r]);
#pragma unroll
            for (int nt = 0; nt < 4; ++nt)
#pragma unroll
                for (int r = 0; r < 4; ++r) {
                    const float o2 = Ob[rhalf][quad * 4 + r][nt * 16 + lrow];
                    outp[((size_t)b * Sc + rowg + r) * Dc + h * 64 + nt * 16 + lrow] =
                        (bf16)((oacc[nt][r] + o2) * linv[r]);
                }
        }
        __syncthreads();
    }
}

__global__ __launch_bounds__(256) void gather_active(
    const float* __restrict__ qmem, const bf16* __restrict__ qkv,
    float* __restrict__ xa, bf16* __restrict__ xab, float* __restrict__ va)
{
    const int t = blockIdx.x;
    const int b = t >> 6;
    const int s = Sc - 64 + (t & 63);
    const float* qrow = qmem + ((size_t)(b * Sc + s)) * Dc;
    const bf16* vrow = qkv + ((size_t)(b * Sc + s)) * 3072 + 2048;
    for (int i = threadIdx.x; i < Dc; i += 256) {
        float q = qrow[i];
        xa[(size_t)t * Dc + i] = q;
        xab[(size_t)t * Dc + i] = (bf16)q;
        va[(size_t)t * Dc + i] = (float)vrow[i];
    }
}

__global__ void wvec_kernel(const float* __restrict__ gamma,
                            float* __restrict__ wvec, float* __restrict__ wsum)
{
    const int t = threadIdx.x;
    const int b = t >> 6, si = t & 63;
    const int s = Sc - 64 + si;
    float v = gamma[b * Sc + s] * powf(0.95f, (float)(Sc - 1 - s));
    wvec[t] = v;
    __shared__ float red[128];
    red[t] = v; __syncthreads();
    for (int st = 64; st; st >>= 1) { if (t < st) red[t] += red[t + st]; __syncthreads(); }
    if (t == 0) wsum[0] = red[0];
}

__global__ __launch_bounds__(256) void phi2_f32(
    const float* __restrict__ z, float* __restrict__ feat, bf16* __restrict__ featb)
{
    const int f = blockIdx.x * 256 + threadIdx.x;
    const int t = blockIdx.y;
    if (f >= FPOLY) return;
    const float* zr = z + (size_t)t * 64;
    float v;
    if (f < 64) v = zr[f];
    else { int i = (f - 64) >> 6, j = (f - 64) & 63; v = zr[i] * zr[j] * 0.125f; }
    feat[(size_t)t * FPOLY + f] = v;
    featb[(size_t)t * FPOLY + f] = (bf16)v;
}

__global__ __launch_bounds__(256) void phi2_bf16(
    const float* __restrict__ z, bf16* __restrict__ feat)
{
    const int f = blockIdx.x * 256 + threadIdx.x;
    const int t = blockIdx.y;
    if (f >= FPOLY) return;
    const float* zr = z + (size_t)t * 64;
    float v;
    if (f < 64) v = zr[f];
    else { int i = (f - 64) >> 6, j = (f - 64) & 63; v = zr[i] * zr[j] * 0.125f; }
    feat[(size_t)t * FPOLY + f] = (bf16)v;
}

__global__ void silu_kernel(const float* __restrict__ in, float* __restrict__ out,
                            bf16* __restrict__ outb, int n)
{
    int i = blockIdx.x * 256 + threadIdx.x;
    if (i < n) {
        float v = in[i];
        float s = v / (1.f + expf(-v));
        out[i] = s; outb[i] = (bf16)s;
    }
}

__global__ void dpred_kernel(const float* __restrict__ pred, const float* __restrict__ va,
                             const float* __restrict__ wvec, const float* __restrict__ wsum,
                             float* __restrict__ dpred, bf16* __restrict__ dpredb)
{
    int i = blockIdx.x * 256 + threadIdx.x;
    if (i < NACT * Dc) {
        int t = i >> 10;
        float v = 2.f * wvec[t] / (wsum[0] + 1e-8f) * (pred[i] - va[i]);
        dpred[i] = v; dpredb[i] = (bf16)v;
    }
}

__global__ void dsilu_kernel(const float* __restrict__ dsu, const float* __restrict__ u,
                             float* __restrict__ du, bf16* __restrict__ dub, int n)
{
    int i = blockIdx.x * 256 + threadIdx.x;
    if (i < n) {
        float uv = u[i];
        float sg = 1.f / (1.f + expf(-uv));
        float v = dsu[i] * sg * (1.f + uv * (1.f - sg));
        du[i] = v; dub[i] = (bf16)v;
    }
}

__global__ void dz_kernel(const float* __restrict__ dfeat, const float* __restrict__ za,
                          float* __restrict__ dz, bf16* __restrict__ dzb)
{
    const int t = blockIdx.x;
    const int k = threadIdx.x;
    const float* df = dfeat + (size_t)t * FPOLY;
    const float* z = za + (size_t)t * 64;
    float s1 = 0.f, s2 = 0.f;
    for (int j = 0; j < 64; ++j) {
        float zj = z[j];
        s1 += df[64 + k * 64 + j] * zj;
        s2 += df[64 + j * 64 + k] * zj;
    }
    float v = df[k] + 0.125f * (s1 + s2);
    dz[(size_t)t * 64 + k] = v;
    dzb[(size_t)t * 64 + k] = (bf16)v;
}

__global__ void sgate_kernel(const float* __restrict__ mg, float* __restrict__ out)
{
    out[0] = 1.f / (1.f + expf(-mg[0]));
}

// read merged [4096][5504] GEMM output: a=cols[0..2730), b=cols[2752..5482);
// write packed silu(a)*b into [4096][2752] (zero K-pad)
__global__ void swiglu_pack(const bf16* __restrict__ u, bf16* __restrict__ o)
{
    int i = blockIdx.x * 256 + threadIdx.x;
    if (i >= NTOK * FFNHP) return;
    int t = i / FFNHP, k = i % FFNHP;
    if (k >= FFNH) { o[i] = (bf16)0.f; return; }
    float a = (float)u[(size_t)t * 5504 + k];
    float b = (float)u[(size_t)t * 5504 + 2752 + k];
    o[i] = (bf16)(a / (1.f + __expf(-a)) * b);
}

// ---------------------------------------------------------------- launch
extern "C" void kernel_launch(void* const* d_in, const int* in_sizes, int n_in,
                              void* d_out, int out_size, void* d_ws, size_t ws_size,
                              hipStream_t stream)
{
    const float* x     = (const float*)d_in[0];
    const float* n1w   = (const float*)d_in[1];
    const float* n2w   = (const float*)d_in[2];
    const float* qkvw  = (const float*)d_in[3];
    const float* qnw   = (const float*)d_in[4];
    const float* knw   = (const float*)d_in[5];
    const float* gw1   = (const float*)d_in[6];
    const float* gw2   = (const float*)d_in[7];
    const float* mwk   = (const float*)d_in[8];
    const float* mw1   = (const float*)d_in[9];
    const float* mw2   = (const float*)d_in[10];
    const float* mgate = (const float*)d_in[11];
    const float* wow   = (const float*)d_in[12];
    const float* fw1   = (const float*)d_in[13];
    const float* fw2   = (const float*)d_in[14];
    const float* fw3   = (const float*)d_in[15];
    float* outp = (float*)d_out;

    char* base = (char*)d_ws;
    size_t off = 0;
    auto takeB = [&](size_t bytes) { char* p = base + off; off += (bytes + 255) & ~(size_t)255; return p; };

    // slabs (liveness-overlaid). A+E adjacent: featC4 (34MB) and ff13b (45MB) span both.
    // D+F adjacent: t1b4 (16.8MB) spans both.
    char* slabA  = takeB(22544384);  // partials / vt -> featC4(lo) -> ff13b(lo)
    char* slabE  = takeB(22544384);  // qmem fp32 -> featC4(hi) -> ff13b(hi)
    char* slabBC = takeB(16777216);  // qnb+knb -> x2 fp32
    char* slabD  = takeB(8388608);   // qmemb -> t1b4(lo)
    char* slabF  = takeB(8388608);   // attnb -> t1b4(hi)
    char* slabG  = takeB(17301504);  // hb -> mw1b -> w1uT -> h2b
    float* partA = (float*)slabA;
    bf16* vt     = (bf16*)slabA;
    bf16* featC4 = (bf16*)slabA;  // 4096x4160x2 = 34.1MB (A+E)
    bf16* ff13b  = (bf16*)slabA;  // 4096x5504x2 = 45.1MB (A+E)
    float* qmem  = (float*)slabE;
    bf16* qnb = (bf16*)slabBC;    bf16* knb = (bf16*)(slabBC + 8388608);
    float* x2 = (float*)slabBC;
    bf16* qmemb = (bf16*)slabD;
    bf16* t1b4  = (bf16*)slabD;   // 4096x2048x2 = 16.8MB (D+F)
    bf16* attnb = (bf16*)slabF;
    bf16* hb = (bf16*)slabG;      bf16* mw1b = (bf16*)slabG;
    bf16* w1uT = (bf16*)slabG;    bf16* h2b = (bf16*)slabG;
    // merged qkv output (b,s,3072); dead after stage 4 -> reused as packed swiglu buf
    bf16* qkvb = (bf16*)takeB(25165824);
    bf16* ffpk = qkvb;            // 4096x2752x2 = 22.5MB <= 24MB

    // bf16 weights
    bf16* qkvwT = (bf16*)takeB(6291456);
    bf16* gw1T  = (bf16*)takeB(262144);    // 128 rows alloc / 64 real
    bf16* wowT  = (bf16*)takeB(2097152);
    bf16* mw1T  = (bf16*)takeB(17039360);
    bf16* mw2T  = (bf16*)takeB(4194304);
    bf16* fw13T = (bf16*)takeB(11272192);  // stacked: rows 0..2729=fw1, 2752..5481=fw3 (5504 rows)
    bf16* fw2T  = (bf16*)takeB(5636096);
    bf16* mw2b  = (bf16*)takeB(4194304);   // straight copy (2048,1024)
    bf16* mwkTb = (bf16*)takeB(262144);    // (64 real/128 alloc, 1024)
    bf16* wkuTb = (bf16*)takeB(262144);
    bf16* w2uT  = (bf16*)takeB(4194304);   // (1024, 2048)

    // fp32 misc
    float* zf    = (float*)takeB(1048576);
    float* gg1   = (float*)takeB(1048576);
    float* gamma = (float*)takeB(16384);
    float* wvec  = (float*)takeB(512);
    float* scal  = (float*)takeB(256);     // [0]=wsum [2]=sig(gate) [8..10]=invn
    float* psum  = (float*)takeB(131072);
    float* xa    = (float*)takeB(524288);
    float* va    = (float*)takeB(524288);
    float* za    = (float*)takeB(32768);
    float* featA = (float*)takeB(2129920);
    float* ua    = (float*)takeB(1048576);
    float* sua   = (float*)takeB(1048576);
    float* preda = (float*)takeB(524288);
    float* dpreda= (float*)takeB(524288);
    float* dsua  = (float*)takeB(1048576);
    float* dua   = (float*)takeB(1048576);
    float* dfeata= (float*)takeB(2129920);
    float* dza   = (float*)takeB(32768);
    float* SA    = (float*)takeB(196608);  // 3 x 128x128 fp32
    float* CA    = (float*)takeB(196608);
    // bf16 misc
    bf16* featAb = (bf16*)takeB(1064960);
    bf16* suab   = (bf16*)takeB(524288);
    bf16* xab    = (bf16*)takeB(262144);
    bf16* duab   = (bf16*)takeB(524288);
    bf16* dpredab= (bf16*)takeB(262144);
    bf16* dzab   = (bf16*)takeB(16384);
    bf16* PT1Tb  = (bf16*)takeB(524288);   // (2048,128)
    bf16* PT2Tb  = (bf16*)takeB(262144);   // (1024,128)
    bf16* PT3Tb  = (bf16*)takeB(32768);
    bf16* duaTb  = (bf16*)takeB(524288);
    bf16* dpredaTb=(bf16*)takeB(262144);
    bf16* dzaTb  = (bf16*)takeB(32768);
    bf16* xaTb   = (bf16*)takeB(262144);
    bf16* featATb= (bf16*)takeB(1081344);  // (4224 alloc/4160 real, 128)
    bf16* suaTb  = (bf16*)takeB(524288);   // (2048, 128)
    // NS bf16
    bf16* Sb16  = (bf16*)takeB(98304);
    bf16* Cb16  = (bf16*)takeB(98304);
    bf16* FcAb  = (bf16*)takeB(98304);
    bf16* FcTAb = (bf16*)takeB(98304);

    auto gemmB = [&](int outbf, int cinbf, const bf16* A, const bf16* Bt,
                     const void* Cin, void* C, int M, int N, int K, int ldc,
                     float alpha, float beta, int act, const float* sptr) {
        dim3 grid((N + 127) / 128, M / 128);
        if (outbf && cinbf) gemm_bt<1, 1><<<grid, 256, 0, stream>>>(A, Bt, Cin, C, M, N, K, ldc, alpha, beta, act, sptr);
        else if (outbf)     gemm_bt<1, 0><<<grid, 256, 0, stream>>>(A, Bt, Cin, C, M, N, K, ldc, alpha, beta, act, sptr);
        else                gemm_bt<0, 0><<<grid, 256, 0, stream>>>(A, Bt, Cin, C, M, N, K, ldc, alpha, beta, act, sptr);
    };
    auto gdir = [&](int outbf, int cinbf, const bf16* A, const bf16* Bt,
                    const void* Cin, void* C, int M, int N, int K, int ldc,
                    float alpha, float beta, int act, const float* sptr) {
        dim3 grid((N + 127) / 128, (M + 127) / 128);
        if (outbf && cinbf)      gemm_direct<1, 1><<<grid, 256, 0, stream>>>(A, Bt, Cin, C, M, N, K, ldc, alpha, beta, act, sptr);
        else if (outbf)          gemm_direct<1, 0><<<grid, 256, 0, stream>>>(A, Bt, Cin, C, M, N, K, ldc, alpha, beta, act, sptr);
        else if (cinbf)          gemm_direct<0, 1><<<grid, 256, 0, stream>>>(A, Bt, Cin, C, M, N, K, ldc, alpha, beta, act, sptr);
        else                     gemm_direct<0, 0><<<grid, 256, 0, stream>>>(A, Bt, Cin, C, M, N, K, ldc, alpha, beta, act, sptr);
    };
    auto skp = [&](const bf16* A, const bf16* Bt, float* out,
                   int M, int N, int K, int KC) {
        int SK = (K + KC - 1) / KC;
        gemm_skp<<<dim3((N + 127) / 128, (M + 127) / 128, SK), 256, 0, stream>>>(A, Bt, partA, M, N, K, KC);
        int MN = M * N;
        skred<<<(MN + 255) / 256, 256, 0, stream>>>(partA, out, SK, MN);
    };
    auto tconv = [&](const float* W, bf16* Wt, int K, int N, int Kpad) {
        tconv_kernel<<<dim3((Kpad + 31) / 32, (N + 31) / 32), 256, 0, stream>>>(W, Wt, K, N, Kpad);
    };

    // 0. weight converts
    tconv(qkvw, qkvwT, Dc, 3 * Dc, Dc);
    tconv(gw1, gw1T, Dc, GGH, Dc);
    tconv(wow, wowT, Dc, Dc, Dc);
    tconv(mw1, mw1T, FPOLY, MHID, FPOLY);
    tconv(mw2, mw2T, MHID, Dc, MHID);
    tconv(fw1, fw13T, Dc, FFNH, Dc);
    tconv(fw3, fw13T + (size_t)2752 * Dc, Dc, FFNH, Dc);
    tconv(fw2, fw2T, FFNH, Dc, FFNHP);
    tconv(mwk, mwkTb, Dc, HDc, Dc);
    cvt_kernel<<<2048, 256, 0, stream>>>(mw2, mw2b, MHID * Dc);
    sgate_kernel<<<1, 1, 0, stream>>>(mgate, scal + 2);

    // 1-2. rmsnorm, merged qkv, q/k norm+rope (one launch), gamma
    rms_rows<<<NTOK, 256, 0, stream>>>(x, n1w, hb, Dc);
    gemmB(1, 0, hb, qkvwT, nullptr, qkvb, NTOK, 3 * Dc, Dc, 3 * Dc, 1.f, 0.f, 0, nullptr);
    snr_qk<<<dim3(Sc / 4, 32, Bc), 256, 0, stream>>>(qkvb, qnw, knw, qnb, knb);
    skp(hb, gw1T, gg1, NTOK, GGH, Dc, 256);        // SK=4, 128 blocks
    gamma_kernel<<<NTOK / 4, 256, 0, stream>>>(gg1, gw2, gamma);
    cvt_kernel<<<2048, 256, 0, stream>>>(mw1, mw1b, FPOLY * MHID);   // hb dead

    // 3. V transpose, q_mem, attention (XCD-clustered 1D grid)
    vtrans_kernel<<<dim3(Sc / 32, 2, Bc * Hc), 256, 0, stream>>>(qkvb, vt);
    kpsum_kernel<<<dim3(Bc * Hc, 16), 64, 0, stream>>>(knb, psum);
    qmem2_kernel<<<dim3(Bc * Hc, 16), 64, 0, stream>>>(qnb, knb, gamma, psum, qmem);
    attn_mfma<<<dim3(1024), 256, 0, stream>>>(qnb, knb, vt, attnb);

    // 4. actives (vt dead -> slabA reusable as partials)
    gather_active<<<NACT, 256, 0, stream>>>(qmem, qkvb, xa, xab, va);
    wvec_kernel<<<1, 128, 0, stream>>>(gamma, wvec, scal);

    // 5. gradient chain (128 active tokens) -- split-K MFMA
    skp(xab, mwkTb, za, NACT, HDc, Dc, 64);                         // SK=16
    phi2_f32<<<dim3((FPOLY + 255) / 256, NACT), 256, 0, stream>>>(za, featA, featAb);
    skp(featAb, mw1T, ua, NACT, MHID, FPOLY, 288);                  // SK=15, 240 blocks
    silu_kernel<<<(NACT * MHID + 255) / 256, 256, 0, stream>>>(ua, sua, suab, NACT * MHID);
    skp(suab, mw2T, preda, NACT, Dc, MHID, 128);                    // SK=16, 128 blocks
    dpred_kernel<<<(NACT * Dc + 255) / 256, 256, 0, stream>>>(preda, va, wvec, scal, dpreda, dpredab);
    skp(dpredab, mw2b, dsua, NACT, MHID, Dc, 128);                  // SK=8, 128 blocks
    dsilu_kernel<<<(NACT * MHID + 255) / 256, 256, 0, stream>>>(dsua, ua, dua, duab, NACT * MHID);
    skp(duab, mw1b, dfeata, NACT, FPOLY, MHID, 256);                // SK=8, 264 blocks
    dz_kernel<<<NACT, 64, 0, stream>>>(dfeata, za, dza, dzab);

    // transposed bf16 copies (6-in-1)
    tconv6_kernel<<<dim3(4, 130, 6), 256, 0, stream>>>(
        dua, dpreda, dza, xa, featA, sua,
        duaTb, dpredaTb, dzaTb, xaTb, featATb, suaTb);

    // 6. Newton-Schulz: batched grams (2 launches) + fused 5-iter chain
    gram_trick<<<1, 256, 0, stream>>>(za, SA);
    gram_bat<<<dim3(32, 5), 256, 0, stream>>>(suab, xab, duab, dpredab, dzab, partA);
    gram_red<<<320, 256, 0, stream>>>(partA, SA, CA);
    ns_norm_kernel<<<3, 256, 0, stream>>>(SA, CA, Sb16, Cb16, scal + 8);
    ns_fused<<<3, 256, 0, stream>>>(Sb16, Cb16, FcAb, FcTAb);
    // P5 = PTraw^T @ Fc * invn
    gdir(1, 0, duaTb,    FcTAb,         nullptr, PT1Tb, MHID, 128, 128, 128, 1.f, 0.f, 0, scal + 8);
    gdir(1, 0, dpredaTb, FcTAb + 16384, nullptr, PT2Tb, Dc,   128, 128, 128, 1.f, 0.f, 0, scal + 9);
    gdir(1, 0, dzaTb,    FcTAb + 32768, nullptr, PT3Tb, HDc,  128, 128, 128, 1.f, 0.f, 0, scal + 10);

    // wkuT = 0.999*mwkT - 0.01*PT3T@xa
    gdir(1, 1, PT3Tb, xaTb, mwkTb, wkuTb, HDc, Dc, 128, Dc, -0.01f, 0.999f, 0, nullptr);
    //   w1uT = 0.999*mw1T - 0.01*PT1T@featA   (mw1b dead -> slabG reuse)
    gemmB(1, 1, PT1Tb, featATb, mw1T, w1uT, MHID, FPOLY, 128, FPOLY, -0.01f, 0.999f, 0, nullptr);
    //   w2uT = 0.999*mw2T - 0.01*PT2T@sua
    gemmB(1, 1, PT2Tb, suaTb, mw2T, w2uT, Dc, MHID, 128, MHID, -0.01f, 0.999f, 0, nullptr);

    // 7. x2 = x + attn@wo; zf = qmem@wku
    gemmB(0, 0, attnb, wowT, x, x2, NTOK, Dc, Dc, Dc, 1.f, 1.f, 0, nullptr);
    cvt_kernel<<<2048, 256, 0, stream>>>(qmem, qmemb, NTOK * Dc);
    gdir(0, 0, qmemb, wkuTb, nullptr, zf, NTOK, HDc, Dc, HDc, 1.f, 0.f, 0, nullptr);

    // 8. memory forward, de-chunked: M=4096 in one pass
    phi2_bf16<<<dim3((FPOLY + 255) / 256, NTOK), 256, 0, stream>>>(zf, featC4);
    gemmB(1, 0, featC4, w1uT, nullptr, t1b4, NTOK, MHID, FPOLY, MHID, 1.f, 0.f, 1, nullptr);
    gemmB(0, 0, t1b4, w2uT, x2, x2, NTOK, Dc, MHID, Dc, 1.f, 1.f, 0, scal + 2);

    // 9. FFN (swiglu): fw1+fw3 merged into one N=5482 GEMM (cols 0..2729 = fw1 path,
    //    2752..5481 = fw3 path; cols 2730..2751 garbage, never read), then fused pack.
    rms_rows<<<NTOK, 256, 0, stream>>>(x2, n2w, h2b, Dc);
    gemmB(1, 0, h2b, fw13T, nullptr, ff13b, NTOK, 5482, Dc, 5504, 1.f, 0.f, 0, nullptr);
    swiglu_pack<<<(NTOK * FFNHP + 255) / 256, 256, 0, stream>>>(ff13b, ffpk);
    gemmB(0, 0, ffpk, fw2T, x2, outp, NTOK, Dc, FFNHP, Dc, 1.f, 1.f, 0, nullptr);
}

// Round 7
// 1162.335 us; speedup vs baseline: 1.3000x; 1.1019x over previous
//
#include <hip/hip_runtime.h>
#include <math.h>

#define Bc 2
#define Sc 2048
#define Dc 1024
#define Hc 16
#define HDc 64
#define FPOLY 4160
#define MHID 2048
#define FFNH 2730
#define FFNHP 2752   // FFNH padded to mult of 32 (K pad, zero-filled)
#define GGH 64
#define NTOK 4096
#define NACT 128

typedef __bf16 bf16;
typedef __attribute__((ext_vector_type(8))) __bf16 bf16x8;
typedef __attribute__((ext_vector_type(4))) float f32x4;

#define AS1 __attribute__((address_space(1)))
#define AS3 __attribute__((address_space(3)))

__device__ __forceinline__ void gload16(const void* g, void* l) {
    __builtin_amdgcn_global_load_lds((AS1 const void*)g, (AS3 void*)l, 16, 0, 0);
}

__device__ __forceinline__ float fexp2(float x) { return __builtin_amdgcn_exp2f(x); }

// ---------------------------------------------------------------- bf16 MFMA GEMM (LDS, big tiles)
// C = act(alpha*[sptr]*A@Bt^T + beta*Cin).  A:(M,K) bf16 row-major, Bt:(N,K) bf16.
// K%32==0, M%128==0. N arbitrary; Bt rows allocated to ceil(N/128)*128.
// 2-phase stage-ahead pipeline (T3-min) + bijective XCD-clustering swizzle (T1/m204).
template<int OUTBF, int CINBF>
__global__ __launch_bounds__(256) void gemm_bt(
    const bf16* __restrict__ A, const bf16* __restrict__ Bt,
    const void* __restrict__ Cin, void* __restrict__ Cout,
    int M, int N, int K, int ldc,
    float alpha, float beta, int act, const float* __restrict__ sptr)
{
    __shared__ bf16 As[2][128 * 32];
    __shared__ bf16 Bs[2][128 * 32];
    const int tid = threadIdx.x;
    const int w = tid >> 6, lane = tid & 63;
    const int gridX = gridDim.x;
    const int nwg = gridX * gridDim.y;
    const int orig = blockIdx.y * gridX + blockIdx.x;
    const int q8 = nwg >> 3, r8 = nwg & 7;
    const int xcd = orig & 7, lid = orig >> 3;
    const int sbase = (xcd < r8) ? xcd * (q8 + 1) : r8 * (q8 + 1) + (xcd - r8) * q8;
    const int swzid = sbase + lid;
    const int bm = (swzid / gridX) * 128, bn = (swzid % gridX) * 128;
    const int wm = (w >> 1) * 64, wn = (w & 1) * 64;
    f32x4 acc[4][4];
#pragma unroll
    for (int i = 0; i < 4; ++i)
#pragma unroll
        for (int j = 0; j < 4; ++j) { acc[i][j][0] = 0.f; acc[i][j][1] = 0.f; acc[i][j][2] = 0.f; acc[i][j][3] = 0.f; }
    const int idx0 = tid, idx1 = tid + 256;
    const int r0 = idx0 >> 2, r1 = idx1 >> 2;
    const int g0 = ((idx0 & 3) ^ ((r0 >> 1) & 3)) * 8;
    const int g1 = ((idx1 & 3) ^ ((r1 >> 1) & 3)) * 8;
    const int lrow = lane & 15;
    const int q = lane >> 4;
    int aoff[4], boff[4];
#pragma unroll
    for (int t = 0; t < 4; ++t) {
        int ar = wm + t * 16 + lrow;
        aoff[t] = ar * 32 + ((q ^ ((ar >> 1) & 3)) * 8);
        int br = wn + t * 16 + lrow;
        boff[t] = br * 32 + ((q ^ ((br >> 1) & 3)) * 8);
    }
    const bf16* Arow0 = A + (size_t)(bm + r0) * K + g0;
    const bf16* Arow1 = A + (size_t)(bm + r1) * K + g1;
    const bf16* Brow0 = Bt + (size_t)(bn + r0) * K + g0;
    const bf16* Brow1 = Bt + (size_t)(bn + r1) * K + g1;
    auto stage = [&](int bi, int k0) {
        char* la = (char*)&As[bi][0] + w * 1024;
        char* lb = (char*)&Bs[bi][0] + w * 1024;
        gload16(Arow0 + k0, la);
        gload16(Arow1 + k0, la + 4096);
        gload16(Brow0 + k0, lb);
        gload16(Brow1 + k0, lb + 4096);
    };
    auto compute = [&](int bi) {
        bf16x8 af[4], bfr[4];
#pragma unroll
        for (int t = 0; t < 4; ++t) af[t] = *(const bf16x8*)&As[bi][aoff[t]];
#pragma unroll
        for (int t = 0; t < 4; ++t) bfr[t] = *(const bf16x8*)&Bs[bi][boff[t]];
#pragma unroll
        for (int mt = 0; mt < 4; ++mt)
#pragma unroll
            for (int nt = 0; nt < 4; ++nt)
                acc[mt][nt] = __builtin_amdgcn_mfma_f32_16x16x32_bf16(af[mt], bfr[nt], acc[mt][nt], 0, 0, 0);
    };
    stage(0, 0);
    __syncthreads();
    int buf = 0;
    for (int k0 = 32; k0 < K; k0 += 32) {
        stage(buf ^ 1, k0);
        compute(buf);
        __syncthreads();
        buf ^= 1;
    }
    compute(buf);
    const float amul = alpha * (sptr ? *sptr : 1.f);
#pragma unroll
    for (int nt = 0; nt < 4; ++nt) {
        const int col = bn + wn + nt * 16 + lrow;
        if (col >= N) continue;
#pragma unroll
        for (int mt = 0; mt < 4; ++mt) {
            const int rbase = bm + wm + mt * 16 + q * 4;
#pragma unroll
            for (int r = 0; r < 4; ++r) {
                const size_t o = (size_t)(rbase + r) * ldc + col;
                float v = amul * acc[mt][nt][r];
                if (beta != 0.f)
                    v += beta * (CINBF ? (float)((const bf16*)Cin)[o] : ((const float*)Cin)[o]);
                if (act == 1) v = v / (1.f + __expf(-v));
                if (OUTBF) ((bf16*)Cout)[o] = (bf16)v;
                else       ((float*)Cout)[o] = v;
            }
        }
    }
}

// ---------------------------------------------------------------- 128x64-tile pipelined GEMM
// For N=1024 GEMMs: grid (N/64, M/128) = 512 blocks (2/CU vs 1/CU at 128x128).
// fp32 Cin/Cout, beta=1, act=0, optional *sptr scale. Same staging + XCD swizzle.
__global__ __launch_bounds__(256) void gemm_bt64(
    const bf16* __restrict__ A, const bf16* __restrict__ Bt,
    const float* __restrict__ Cin, float* __restrict__ Cout,
    int M, int N, int K, int ldc, const float* __restrict__ sptr)
{
    __shared__ bf16 As[2][128 * 32];
    __shared__ bf16 Bs[2][64 * 32];
    const int tid = threadIdx.x;
    const int w = tid >> 6, lane = tid & 63;
    const int gridX = gridDim.x;
    const int nwg = gridX * gridDim.y;
    const int orig = blockIdx.y * gridX + blockIdx.x;
    const int q8 = nwg >> 3, r8 = nwg & 7;
    const int xcd = orig & 7, lid = orig >> 3;
    const int sbase = (xcd < r8) ? xcd * (q8 + 1) : r8 * (q8 + 1) + (xcd - r8) * q8;
    const int swzid = sbase + lid;
    const int bm = (swzid / gridX) * 128, bn = (swzid % gridX) * 64;
    const int wm = w * 32;
    f32x4 acc[2][4];
#pragma unroll
    for (int i = 0; i < 2; ++i)
#pragma unroll
        for (int j = 0; j < 4; ++j) { acc[i][j][0] = 0.f; acc[i][j][1] = 0.f; acc[i][j][2] = 0.f; acc[i][j][3] = 0.f; }
    const int idx0 = tid, idx1 = tid + 256;
    const int r0 = idx0 >> 2, r1 = idx1 >> 2;
    const int g0 = ((idx0 & 3) ^ ((r0 >> 1) & 3)) * 8;
    const int g1 = ((idx1 & 3) ^ ((r1 >> 1) & 3)) * 8;
    const int rB = tid >> 2;
    const int gB = ((tid & 3) ^ ((rB >> 1) & 3)) * 8;
    const int lrow = lane & 15;
    const int q = lane >> 4;
    int aoff[2], boff[4];
#pragma unroll
    for (int t = 0; t < 2; ++t) {
        int ar = wm + t * 16 + lrow;
        aoff[t] = ar * 32 + ((q ^ ((ar >> 1) & 3)) * 8);
    }
#pragma unroll
    for (int nt = 0; nt < 4; ++nt) {
        int br = nt * 16 + lrow;
        boff[nt] = br * 32 + ((q ^ ((br >> 1) & 3)) * 8);
    }
    const bf16* Arow0 = A + (size_t)(bm + r0) * K + g0;
    const bf16* Arow1 = A + (size_t)(bm + r1) * K + g1;
    const bf16* Brow  = Bt + (size_t)(bn + rB) * K + gB;
    auto stage = [&](int bi, int k0) {
        char* la = (char*)&As[bi][0] + w * 1024;
        char* lb = (char*)&Bs[bi][0] + w * 1024;
        gload16(Arow0 + k0, la);
        gload16(Arow1 + k0, la + 4096);
        gload16(Brow + k0, lb);
    };
    auto compute = [&](int bi) {
        bf16x8 af[2], bfr[4];
#pragma unroll
        for (int t = 0; t < 2; ++t) af[t] = *(const bf16x8*)&As[bi][aoff[t]];
#pragma unroll
        for (int nt = 0; nt < 4; ++nt) bfr[nt] = *(const bf16x8*)&Bs[bi][boff[nt]];
#pragma unroll
        for (int mt = 0; mt < 2; ++mt)
#pragma unroll
            for (int nt = 0; nt < 4; ++nt)
                acc[mt][nt] = __builtin_amdgcn_mfma_f32_16x16x32_bf16(af[mt], bfr[nt], acc[mt][nt], 0, 0, 0);
    };
    stage(0, 0);
    __syncthreads();
    int buf = 0;
    for (int k0 = 32; k0 < K; k0 += 32) {
        stage(buf ^ 1, k0);
        compute(buf);
        __syncthreads();
        buf ^= 1;
    }
    compute(buf);
    const float amul = sptr ? *sptr : 1.f;
#pragma unroll
    for (int nt = 0; nt < 4; ++nt) {
        const int col = bn + nt * 16 + lrow;
        if (col >= N) continue;
#pragma unroll
        for (int mt = 0; mt < 2; ++mt) {
            const int rbase = bm + wm + mt * 16 + q * 4;
#pragma unroll
            for (int r = 0; r < 4; ++r) {
                const size_t o = (size_t)(rbase + r) * ldc + col;
                Cout[o] = amul * acc[mt][nt][r] + Cin[o];
            }
        }
    }
}

// ---------------------------------------------------------------- barrier-free direct MFMA GEMM
template<int OUTBF, int CINBF>
__global__ __launch_bounds__(256) void gemm_direct(
    const bf16* __restrict__ A, const bf16* __restrict__ Bt,
    const void* __restrict__ Cin, void* __restrict__ Cout,
    int M, int N, int K, int ldc,
    float alpha, float beta, int act, const float* __restrict__ sptr)
{
    const int tid = threadIdx.x, w = tid >> 6, lane = tid & 63;
    const int lrow = lane & 15, quad = lane >> 4;
    const int bm = blockIdx.y * 128 + w * 32;
    const int bn = blockIdx.x * 128;
    f32x4 acc[2][8];
#pragma unroll
    for (int mt = 0; mt < 2; ++mt)
#pragma unroll
        for (int nt = 0; nt < 8; ++nt) { acc[mt][nt][0] = 0.f; acc[mt][nt][1] = 0.f; acc[mt][nt][2] = 0.f; acc[mt][nt][3] = 0.f; }
    const bf16* Abase = A + (size_t)(bm + lrow) * K + quad * 8;
    const bf16* Bbase = Bt + (size_t)(bn + lrow) * K + quad * 8;
#pragma unroll 2
    for (int k0 = 0; k0 < K; k0 += 32) {
        bf16x8 af0 = *(const bf16x8*)(Abase + k0);
        bf16x8 af1 = *(const bf16x8*)(Abase + (size_t)16 * K + k0);
#pragma unroll
        for (int nt = 0; nt < 8; ++nt) {
            bf16x8 bfr = *(const bf16x8*)(Bbase + (size_t)nt * 16 * K + k0);
            acc[0][nt] = __builtin_amdgcn_mfma_f32_16x16x32_bf16(af0, bfr, acc[0][nt], 0, 0, 0);
            acc[1][nt] = __builtin_amdgcn_mfma_f32_16x16x32_bf16(af1, bfr, acc[1][nt], 0, 0, 0);
        }
    }
    const float amul = alpha * (sptr ? *sptr : 1.f);
#pragma unroll
    for (int nt = 0; nt < 8; ++nt) {
        const int col = bn + nt * 16 + lrow;
        if (col >= N) continue;
#pragma unroll
        for (int mt = 0; mt < 2; ++mt) {
            const int rbase = bm + mt * 16 + quad * 4;
#pragma unroll
            for (int r = 0; r < 4; ++r) {
                const int row = rbase + r;
                if (row >= M) continue;
                const size_t o = (size_t)row * ldc + col;
                float v = amul * acc[mt][nt][r];
                if (beta != 0.f)
                    v += beta * (CINBF ? (float)((const bf16*)Cin)[o] : ((const float*)Cin)[o]);
                if (act == 1) v = v / (1.f + __expf(-v));
                if (OUTBF) ((bf16*)Cout)[o] = (bf16)v;
                else       ((float*)Cout)[o] = v;
            }
        }
    }
}

// batched P5 gdir: z=0 dua(M2048), z=1 dpred(M1024), z=2 dz(M64); N=K=ldc=128, bf16 out
__global__ __launch_bounds__(256) void gdir3_kernel(
    const bf16* __restrict__ A0, const bf16* __restrict__ A1, const bf16* __restrict__ A2,
    const bf16* __restrict__ B0, bf16* __restrict__ C0, bf16* __restrict__ C1,
    bf16* __restrict__ C2, const float* __restrict__ invn)
{
    const int z = blockIdx.z;
    const bf16* A; const bf16* Bt; bf16* C; int M;
    if      (z == 0) { A = A0; Bt = B0;         C = C0; M = 2048; }
    else if (z == 1) { A = A1; Bt = B0 + 16384; C = C1; M = 1024; }
    else             { A = A2; Bt = B0 + 32768; C = C2; M = 64;   }
    if (blockIdx.y * 128 >= M) return;
    const float s = invn[z];
    const int tid = threadIdx.x, w = tid >> 6, lane = tid & 63;
    const int lrow = lane & 15, quad = lane >> 4;
    const int bm = blockIdx.y * 128 + w * 32;
    f32x4 acc[2][8];
#pragma unroll
    for (int mt = 0; mt < 2; ++mt)
#pragma unroll
        for (int nt = 0; nt < 8; ++nt) { acc[mt][nt][0] = 0.f; acc[mt][nt][1] = 0.f; acc[mt][nt][2] = 0.f; acc[mt][nt][3] = 0.f; }
    const bf16* Abase = A + (size_t)(bm + lrow) * 128 + quad * 8;
    const bf16* Bbase = Bt + (size_t)lrow * 128 + quad * 8;
#pragma unroll
    for (int k0 = 0; k0 < 128; k0 += 32) {
        bf16x8 af0 = *(const bf16x8*)(Abase + k0);
        bf16x8 af1 = *(const bf16x8*)(Abase + (size_t)16 * 128 + k0);
#pragma unroll
        for (int nt = 0; nt < 8; ++nt) {
            bf16x8 bfr = *(const bf16x8*)(Bbase + (size_t)nt * 16 * 128 + k0);
            acc[0][nt] = __builtin_amdgcn_mfma_f32_16x16x32_bf16(af0, bfr, acc[0][nt], 0, 0, 0);
            acc[1][nt] = __builtin_amdgcn_mfma_f32_16x16x32_bf16(af1, bfr, acc[1][nt], 0, 0, 0);
        }
    }
#pragma unroll
    for (int nt = 0; nt < 8; ++nt) {
        const int col = nt * 16 + lrow;
#pragma unroll
        for (int mt = 0; mt < 2; ++mt) {
            const int rbase = bm + mt * 16 + quad * 4;
#pragma unroll
            for (int r = 0; r < 4; ++r) {
                const int row = rbase + r;
                if (row >= M) continue;
                C[(size_t)row * 128 + col] = (bf16)(s * acc[mt][nt][r]);
            }
        }
    }
}

// ---------------------------------------------------------------- split-K direct GEMM
__global__ __launch_bounds__(256) void gemm_skp(
    const bf16* __restrict__ A, const bf16* __restrict__ Bt,
    float* __restrict__ part, int M, int N, int K, int KC)
{
    const int tid = threadIdx.x, w = tid >> 6, lane = tid & 63;
    const int lrow = lane & 15, quad = lane >> 4;
    const int bm = blockIdx.y * 128 + w * 32;
    const int bn = blockIdx.x * 128;
    const int z = blockIdx.z;
    const int kb = z * KC;
    int ke = kb + KC; if (ke > K) ke = K;
    f32x4 acc[2][8];
#pragma unroll
    for (int mt = 0; mt < 2; ++mt)
#pragma unroll
        for (int nt = 0; nt < 8; ++nt) { acc[mt][nt][0] = 0.f; acc[mt][nt][1] = 0.f; acc[mt][nt][2] = 0.f; acc[mt][nt][3] = 0.f; }
    const bf16* Abase = A + (size_t)(bm + lrow) * K + quad * 8;
    const bf16* Bbase = Bt + (size_t)(bn + lrow) * K + quad * 8;
#pragma unroll 2
    for (int k0 = kb; k0 < ke; k0 += 32) {
        bf16x8 af0 = *(const bf16x8*)(Abase + k0);
        bf16x8 af1 = *(const bf16x8*)(Abase + (size_t)16 * K + k0);
#pragma unroll
        for (int nt = 0; nt < 8; ++nt) {
            bf16x8 bfr = *(const bf16x8*)(Bbase + (size_t)nt * 16 * K + k0);
            acc[0][nt] = __builtin_amdgcn_mfma_f32_16x16x32_bf16(af0, bfr, acc[0][nt], 0, 0, 0);
            acc[1][nt] = __builtin_amdgcn_mfma_f32_16x16x32_bf16(af1, bfr, acc[1][nt], 0, 0, 0);
        }
    }
    float* po = part + (size_t)z * M * N;
#pragma unroll
    for (int nt = 0; nt < 8; ++nt) {
        const int col = bn + nt * 16 + lrow;
        if (col >= N) continue;
#pragma unroll
        for (int mt = 0; mt < 2; ++mt) {
            const int rbase = bm + mt * 16 + quad * 4;
#pragma unroll
            for (int r = 0; r < 4; ++r) {
                const int row = rbase + r;
                if (row >= M) continue;
                po[(size_t)row * N + col] = acc[mt][nt][r];
            }
        }
    }
}

__global__ void skred(const float* __restrict__ part, float* __restrict__ out,
                      int SK, int MN)
{
    int i = blockIdx.x * 256 + threadIdx.x;
    if (i >= MN) return;
    float s = 0.f;
    for (int z = 0; z < SK; ++z) s += part[(size_t)z * MN + i];
    out[i] = s;
}

// fused split-K reduces for the gradient chain (NACT=128 rows)
__global__ void skred_silu(const float* __restrict__ part, float* __restrict__ ua,
                           float* __restrict__ sua, bf16* __restrict__ suab)
{
    int i = blockIdx.x * 256 + threadIdx.x;
    if (i >= NACT * MHID) return;
    float s = 0.f;
    for (int z = 0; z < 15; ++z) s += part[(size_t)z * NACT * MHID + i];
    ua[i] = s;
    float sg = s / (1.f + expf(-s));
    sua[i] = sg; suab[i] = (bf16)sg;
}

__global__ void skred_dpred(const float* __restrict__ part, const float* __restrict__ va,
                            const float* __restrict__ wvec, const float* __restrict__ wsum,
                            float* __restrict__ dpred, bf16* __restrict__ dpredb)
{
    int i = blockIdx.x * 256 + threadIdx.x;
    if (i >= NACT * Dc) return;
    float s = 0.f;
    for (int z = 0; z < 16; ++z) s += part[(size_t)z * NACT * Dc + i];
    int t = i >> 10;
    float v = 2.f * wvec[t] / (wsum[0] + 1e-8f) * (s - va[i]);
    dpred[i] = v; dpredb[i] = (bf16)v;
}

__global__ void skred_dsilu(const float* __restrict__ part, const float* __restrict__ u,
                            float* __restrict__ du, bf16* __restrict__ dub)
{
    int i = blockIdx.x * 256 + threadIdx.x;
    if (i >= NACT * MHID) return;
    float s = 0.f;
    for (int z = 0; z < 8; ++z) s += part[(size_t)z * NACT * MHID + i];
    float uv = u[i];
    float sg = 1.f / (1.f + expf(-uv));
    float v = s * sg * (1.f + uv * (1.f - sg));
    du[i] = v; dub[i] = (bf16)v;
}

// ---------------------------------------------------------------- batched 128x128 gram: X@X^T
__global__ __launch_bounds__(256) void gram_bat(
    const bf16* __restrict__ X0, const bf16* __restrict__ X1,
    const bf16* __restrict__ X2, const bf16* __restrict__ X3,
    const bf16* __restrict__ X4, float* __restrict__ part)
{
    const int z = blockIdx.x, m = blockIdx.y;
    const bf16* A; int K;
    if      (m == 0) { A = X0; K = 2048; }
    else if (m == 1) { A = X1; K = 1024; }
    else if (m == 2) { A = X2; K = 2048; }
    else if (m == 3) { A = X3; K = 1024; }
    else             { A = X4; K = 64;   }
    if (z * 64 >= K) return;
    const int tid = threadIdx.x, w = tid >> 6, lane = tid & 63;
    const int lrow = lane & 15, quad = lane >> 4;
    const int bm = w * 32;
    f32x4 acc[2][8];
#pragma unroll
    for (int mt = 0; mt < 2; ++mt)
#pragma unroll
        for (int nt = 0; nt < 8; ++nt) { acc[mt][nt][0] = 0.f; acc[mt][nt][1] = 0.f; acc[mt][nt][2] = 0.f; acc[mt][nt][3] = 0.f; }
    const bf16* Abase = A + (size_t)(bm + lrow) * K + quad * 8;
    const bf16* Bbase = A + (size_t)lrow * K + quad * 8;
#pragma unroll 2
    for (int k0 = z * 64; k0 < z * 64 + 64; k0 += 32) {
        bf16x8 af0 = *(const bf16x8*)(Abase + k0);
        bf16x8 af1 = *(const bf16x8*)(Abase + (size_t)16 * K + k0);
#pragma unroll
        for (int nt = 0; nt < 8; ++nt) {
            bf16x8 bfr = *(const bf16x8*)(Bbase + (size_t)nt * 16 * K + k0);
            acc[0][nt] = __builtin_amdgcn_mfma_f32_16x16x32_bf16(af0, bfr, acc[0][nt], 0, 0, 0);
            acc[1][nt] = __builtin_amdgcn_mfma_f32_16x16x32_bf16(af1, bfr, acc[1][nt], 0, 0, 0);
        }
    }
    float* po = part + (size_t)(m * 32 + z) * 16384;
#pragma unroll
    for (int nt = 0; nt < 8; ++nt) {
        const int col = nt * 16 + lrow;
#pragma unroll
        for (int mt = 0; mt < 2; ++mt)
#pragma unroll
            for (int r = 0; r < 4; ++r)
                po[(size_t)(bm + mt * 16 + quad * 4 + r) * 128 + col] = acc[mt][nt][r];
    }
}

__global__ void gram_red(const float* __restrict__ part,
                         float* __restrict__ SA, float* __restrict__ CA)
{
    int idx = blockIdx.x * 256 + threadIdx.x;   // 5*16384
    if (idx >= 81920) return;
    int m = idx >> 14, e = idx & 16383;
    int SK = (m == 0 || m == 2) ? 32 : (m == 4 ? 1 : 16);
    float s = 0.f;
    for (int z = 0; z < SK; ++z) s += part[(size_t)(m * 32 + z) * 16384 + e];
    float* dst = (m == 0) ? SA + 16384 : (m == 1) ? SA + 32768 :
                 (m == 2) ? CA : (m == 3) ? CA + 16384 : CA + 32768;
    dst[e] = s;
}

// ---------------------------------------------------------------- polynomial-kernel gram
__global__ __launch_bounds__(256) void gram_trick(
    const float* __restrict__ za, float* __restrict__ S)
{
    __shared__ float z[128 * 65];
    for (int i = threadIdx.x; i < 8192; i += 256) {
        int r = i >> 6, d = i & 63;
        z[r * 65 + d] = za[i];
    }
    __syncthreads();
    for (int idx = threadIdx.x; idx < 16384; idx += 256) {
        int i = idx >> 7, j = idx & 127;
        float dot = 0.f;
#pragma unroll
        for (int d = 0; d < 64; ++d) dot += z[i * 65 + d] * z[j * 65 + d];
        S[idx] = dot + dot * dot * 0.015625f;
    }
}

__global__ __launch_bounds__(256) void ns_norm_kernel(
    const float* __restrict__ S, const float* __restrict__ C,
    bf16* __restrict__ Sb, bf16* __restrict__ Cb, float* __restrict__ invn)
{
    const int z = blockIdx.x;
    const float* s = S + (size_t)z * 16384;
    const float* c = C + (size_t)z * 16384;
    float acc = 0.f;
    for (int i = threadIdx.x; i < 16384; i += 256) acc += s[i] * c[i];
    __shared__ float red[256];
    red[threadIdx.x] = acc; __syncthreads();
    for (int st = 128; st; st >>= 1) {
        if (threadIdx.x < st) red[threadIdx.x] += red[threadIdx.x + st];
        __syncthreads();
    }
    float inv = 1.f / (sqrtf(red[0]) + 1e-7f);
    float inv2 = inv * inv;
    for (int i = threadIdx.x; i < 16384; i += 256) {
        Cb[(size_t)z * 16384 + i] = (bf16)(c[i] * inv2);
        Sb[(size_t)z * 16384 + i] = (bf16)s[i];
    }
    if (threadIdx.x == 0) invn[z] = inv;
}

// ---------------------------------------------------------------- fused Newton-Schulz (batched z=3)
__device__ __forceinline__ int swz(int row, int col) {
    return row * 128 + ((((col >> 3) ^ (row & 7)) << 3) | (col & 7));
}

__global__ __launch_bounds__(256) void ns_fused(
    const bf16* __restrict__ Sg, const bf16* __restrict__ Cg,
    bf16* __restrict__ Fcg, bf16* __restrict__ FcTg)
{
    __shared__ bf16 Cl[16384], Ml[16384], MTl[16384], FTl[16384];
    const int z = blockIdx.x;
    const bf16* S = Sg + (size_t)z * 16384;
    bf16* Fc = Fcg + (size_t)z * 16384;
    bf16* FcT = FcTg + (size_t)z * 16384;
    const int tid = threadIdx.x, w = tid >> 6, lane = tid & 63;
    const int lrow = lane & 15, quad = lane >> 4;
    const int bm = w * 32;
    for (int i = tid; i < 2048; i += 256) {
        const int row = i >> 4, c = i & 15;
        *(bf16x8*)&Cl[row * 128 + ((c ^ (row & 7)) << 3)] =
            *(const bf16x8*)(Cg + (size_t)z * 16384 + (size_t)row * 128 + c * 8);
    }
    __syncthreads();
    const int r0 = bm + lrow, r1 = r0 + 16;
    const int rx = lrow & 7;
    f32x4 acc[2][8];
    auto zacc = [&]() {
#pragma unroll
        for (int mt = 0; mt < 2; ++mt)
#pragma unroll
            for (int nt = 0; nt < 8; ++nt) { acc[mt][nt][0] = 0.f; acc[mt][nt][1] = 0.f; acc[mt][nt][2] = 0.f; acc[mt][nt][3] = 0.f; }
    };
    auto inner = [&](bf16x8 af0, bf16x8 af1, const bf16* Bt, int c) {
#pragma unroll
        for (int nt = 0; nt < 8; ++nt) {
            const int br = nt * 16 + lrow;
            bf16x8 bfr = *(const bf16x8*)&Bt[br * 128 + ((c ^ (br & 7)) << 3)];
            acc[0][nt] = __builtin_amdgcn_mfma_f32_16x16x32_bf16(af0, bfr, acc[0][nt], 0, 0, 0);
            acc[1][nt] = __builtin_amdgcn_mfma_f32_16x16x32_bf16(af1, bfr, acc[1][nt], 0, 0, 0);
        }
    };
    auto gemm_ll = [&](const bf16* Al, const bf16* Bt) {
        zacc();
#pragma unroll
        for (int k0 = 0; k0 < 128; k0 += 32) {
            const int c = (k0 >> 3) + quad;
            bf16x8 af0 = *(const bf16x8*)&Al[r0 * 128 + ((c ^ rx) << 3)];
            bf16x8 af1 = *(const bf16x8*)&Al[r1 * 128 + ((c ^ rx) << 3)];
            inner(af0, af1, Bt, c);
        }
    };
    auto gemm_gl = [&](const bf16* Ag, const bf16* Bt) {
        zacc();
#pragma unroll
        for (int k0 = 0; k0 < 128; k0 += 32) {
            const int c = (k0 >> 3) + quad;
            bf16x8 af0 = *(const bf16x8*)(Ag + (size_t)r0 * 128 + k0 + quad * 8);
            bf16x8 af1 = *(const bf16x8*)(Ag + (size_t)r1 * 128 + k0 + quad * 8);
            inner(af0, af1, Bt, c);
        }
    };

    for (int t = 0; t < 5; ++t) {
        gemm_gl(S, Cl);
#pragma unroll
        for (int mt = 0; mt < 2; ++mt)
#pragma unroll
            for (int nt = 0; nt < 8; ++nt)
#pragma unroll
                for (int r = 0; r < 4; ++r) {
                    const int row = bm + mt * 16 + quad * 4 + r, col = nt * 16 + lrow;
                    const bf16 v = (bf16)acc[mt][nt][r];
                    Ml[swz(row, col)] = v;
                    MTl[swz(col, row)] = v;
                }
        __syncthreads();
        gemm_ll(Ml, MTl);
#pragma unroll
        for (int mt = 0; mt < 2; ++mt)
#pragma unroll
            for (int nt = 0; nt < 8; ++nt)
#pragma unroll
                for (int r = 0; r < 4; ++r) {
                    const int row = bm + mt * 16 + quad * 4 + r, col = nt * 16 + lrow;
                    float v = 2.0315f * acc[mt][nt][r] - 4.775f * (float)Ml[swz(row, col)];
                    if (row == col) v += 3.4445f;
                    FTl[swz(col, row)] = (bf16)v;
                    if (t == 0) Fc[(size_t)row * 128 + col] = (bf16)v;
                }
        __syncthreads();
        if (t > 0) {
            gemm_gl(Fc, FTl);
            if (t == 4) {
#pragma unroll
                for (int mt = 0; mt < 2; ++mt)
#pragma unroll
                    for (int nt = 0; nt < 8; ++nt)
#pragma unroll
                        for (int r = 0; r < 4; ++r) {
                            const int row = bm + mt * 16 + quad * 4 + r, col = nt * 16 + lrow;
                            FcT[(size_t)col * 128 + row] = (bf16)acc[mt][nt][r];
                        }
                return;
            }
#pragma unroll
            for (int mt = 0; mt < 2; ++mt)
#pragma unroll
                for (int nt = 0; nt < 8; ++nt)
#pragma unroll
                    for (int r = 0; r < 4; ++r) {
                        const int row = bm + mt * 16 + quad * 4 + r, col = nt * 16 + lrow;
                        Fc[(size_t)row * 128 + col] = (bf16)acc[mt][nt][r];
                    }
        }
        gemm_ll(Cl, FTl);
#pragma unroll
        for (int mt = 0; mt < 2; ++mt)
#pragma unroll
            for (int nt = 0; nt < 8; ++nt)
#pragma unroll
                for (int r = 0; r < 4; ++r) {
                    const int row = bm + mt * 16 + quad * 4 + r, col = nt * 16 + lrow;
                    Ml[swz(col, row)] = (bf16)acc[mt][nt][r];
                }
        __syncthreads();
        gemm_ll(Ml, FTl);
#pragma unroll
        for (int mt = 0; mt < 2; ++mt)
#pragma unroll
            for (int nt = 0; nt < 8; ++nt)
#pragma unroll
                for (int r = 0; r < 4; ++r) {
                    const int row = bm + mt * 16 + quad * 4 + r, col = nt * 16 + lrow;
                    Cl[swz(row, col)] = (bf16)acc[mt][nt][r];
                }
        __syncthreads();
    }
}

// ---------------------------------------------------------------- converts
// tconv with optional fused straight bf16 copy (Wc = bf16(W), same layout as W)
__global__ __launch_bounds__(256) void tconv_kernel(
    const float* __restrict__ W, bf16* __restrict__ Wt, int K, int N, int Kpad,
    bf16* __restrict__ Wc)
{
    __shared__ float t[32][33];
    const int k0 = blockIdx.x * 32, n0 = blockIdx.y * 32;
    const int tx = threadIdx.x & 31, ty = threadIdx.x >> 5;
#pragma unroll
    for (int r = 0; r < 4; ++r) {
        int gk = k0 + ty + r * 8, gn = n0 + tx;
        bool ok = (gk < K && gn < N);
        float v = ok ? W[(size_t)gk * N + gn] : 0.f;
        t[ty + r * 8][tx] = v;
        if (Wc && ok) Wc[(size_t)gk * N + gn] = (bf16)v;
    }
    __syncthreads();
#pragma unroll
    for (int r = 0; r < 4; ++r) {
        int gn = n0 + ty + r * 8, gk = k0 + tx;
        if (gn < N && gk < Kpad) Wt[(size_t)gn * Kpad + gk] = (bf16)t[tx][ty + r * 8];
    }
}

// six 128-row transposed bf16 copies in one launch (all K=128, Kpad=128)
__global__ __launch_bounds__(256) void tconv6_kernel(
    const float* __restrict__ s0, const float* __restrict__ s1,
    const float* __restrict__ s2, const float* __restrict__ s3,
    const float* __restrict__ s4, const float* __restrict__ s5,
    bf16* __restrict__ d0, bf16* __restrict__ d1, bf16* __restrict__ d2,
    bf16* __restrict__ d3, bf16* __restrict__ d4, bf16* __restrict__ d5)
{
    const int zz = blockIdx.z;
    const float* W; bf16* Wt; int N;
    if      (zz == 0) { W = s0; Wt = d0; N = 2048; }
    else if (zz == 1) { W = s1; Wt = d1; N = 1024; }
    else if (zz == 2) { W = s2; Wt = d2; N = 64;   }
    else if (zz == 3) { W = s3; Wt = d3; N = 1024; }
    else if (zz == 4) { W = s4; Wt = d4; N = 4160; }
    else              { W = s5; Wt = d5; N = 2048; }
    const int k0 = blockIdx.x * 32, n0 = blockIdx.y * 32;
    if (n0 >= N) return;
    __shared__ float t[32][33];
    const int tx = threadIdx.x & 31, ty = threadIdx.x >> 5;
#pragma unroll
    for (int r = 0; r < 4; ++r) {
        int gk = k0 + ty + r * 8, gn = n0 + tx;
        t[ty + r * 8][tx] = (gk < 128 && gn < N) ? W[(size_t)gk * N + gn] : 0.f;
    }
    __syncthreads();
#pragma unroll
    for (int r = 0; r < 4; ++r) {
        int gn = n0 + ty + r * 8, gk = k0 + tx;
        if (gn < N) Wt[(size_t)gn * 128 + gk] = (bf16)t[tx][ty + r * 8];
    }
}

// qkv (b,s,3072) v-part -> vt (b,h,d,s)
__global__ __launch_bounds__(256) void vtrans_kernel(
    const bf16* __restrict__ qkv, bf16* __restrict__ vt)
{
    __shared__ bf16 t[32][33];
    const int s0 = blockIdx.x * 32, d0 = blockIdx.y * 32, bh = blockIdx.z;
    const int b = bh >> 4, h = bh & 15;
    const int tx = threadIdx.x & 31, ty = threadIdx.x >> 5;
#pragma unroll
    for (int r = 0; r < 4; ++r) {
        int s = s0 + ty + r * 8;
        t[ty + r * 8][tx] = qkv[((size_t)b * Sc + s) * 3072 + 2048 + h * 64 + d0 + tx];
    }
    __syncthreads();
#pragma unroll
    for (int r = 0; r < 4; ++r) {
        int d = d0 + ty + r * 8;
        vt[((size_t)bh * 64 + d) * Sc + s0 + tx] = t[tx][ty + r * 8];
    }
}

// ---------------------------------------------------------------- small kernels
__global__ __launch_bounds__(256) void rms_rows(
    const float* __restrict__ in, const float* __restrict__ w,
    bf16* __restrict__ out, int D)
{
    const int row = blockIdx.x;
    const float* r = in + (size_t)row * D;
    bf16* o = out + (size_t)row * D;
    float s = 0.f;
    for (int i = threadIdx.x; i < D; i += 256) { float v = r[i]; s += v * v; }
    __shared__ float red[256];
    red[threadIdx.x] = s;
    __syncthreads();
    for (int st = 128; st; st >>= 1) {
        if (threadIdx.x < st) red[threadIdx.x] += red[threadIdx.x + st];
        __syncthreads();
    }
    float rs = rsqrtf(red[0] / (float)D + 1e-6f);
    for (int i = threadIdx.x; i < D; i += 256) o[i] = (bf16)(r[i] * rs * w[i]);
}

__global__ __launch_bounds__(256) void gamma_kernel(
    const float* __restrict__ gg1, const float* __restrict__ w2,
    float* __restrict__ gamma)
{
    const int tid = threadIdx.x, w = tid >> 6, lane = tid & 63;
    const int t = blockIdx.x * 4 + w;
    float v = gg1[(size_t)t * GGH + lane];
    v = v / (1.f + expf(-v));
    v *= w2[lane];
#pragma unroll
    for (int off = 32; off; off >>= 1) v += __shfl_xor(v, off);
    if (lane == 0) gamma[t] = 1.f / (1.f + expf(-v));
}

// rmsnorm+rope for q AND k in one launch: blockIdx.y in [0,32): y>>4 selects q/k
__global__ __launch_bounds__(256) void snr_qk(
    const bf16* __restrict__ src, const float* __restrict__ qw, const float* __restrict__ kw,
    bf16* __restrict__ qd, bf16* __restrict__ kd)
{
    const int tid = threadIdx.x, wv = tid >> 6, lane = tid & 63;
    const int s = blockIdx.x * 4 + wv;
    const int y = blockIdx.y, b = blockIdx.z;
    const int h = y & 15, which = y >> 4;
    const float* w = which ? kw : qw;
    bf16* dst = which ? kd : qd;
    const size_t row = ((size_t)b * Sc + s) * 3072 + which * 1024 + h * 64;
    float v = (float)src[row + lane];
    float ss = v * v;
#pragma unroll
    for (int off = 32; off; off >>= 1) ss += __shfl_xor(ss, off);
    v = v * rsqrtf(ss / 64.f + 1e-6f) * w[lane];
    const int j = lane & 31;
    float inv = powf(10000.f, -(float)j / 32.f);
    float ang = (float)s * inv;
    float sn = sinf(ang), cs = cosf(ang);
    float p = __shfl_xor(v, 32);
    float o;
    if (lane < 32) o = v * cs - p * sn;
    else           o = p * sn + v * cs;
    const size_t od = (((size_t)b * Hc + h) * Sc + s) * 64 + lane;
    dst[od] = (bf16)o;
}

__global__ void kpsum_kernel(const bf16* __restrict__ kn, float* __restrict__ psum)
{
    const int bh = blockIdx.x, c = blockIdx.y, d = threadIdx.x;
    const size_t base = (size_t)bh * Sc * 64 + (size_t)c * 128 * 64 + d;
    float s = 0.f;
    for (int i = 0; i < 128; ++i) s += (float)kn[base + (size_t)i * 64];
    psum[((size_t)bh * 16 + c) * 64 + d] = s;
}

// q_mem: writes fp32 qmem AND bf16 qmemb (kills the later cvt pass)
__global__ void qmem2_kernel(
    const bf16* __restrict__ qn, const bf16* __restrict__ kn,
    const float* __restrict__ gamma, const float* __restrict__ psum,
    float* __restrict__ qmem, bf16* __restrict__ qmemb)
{
    const int bh = blockIdx.x, c = blockIdx.y;
    const int b = bh >> 4, hh = bh & 15;
    const int d = threadIdx.x;
    const size_t base = (size_t)bh * Sc * 64;
    float run = 0.f;
    for (int cc = 0; cc < c; ++cc) run += psum[((size_t)bh * 16 + cc) * 64 + d];
    for (int s = c * 128; s < c * 128 + 128; ++s) {
        run += (float)kn[base + (size_t)s * 64 + d];
        float cm = run / (float)(s + 1);
        float g = gamma[b * Sc + s];
        float qv = (float)qn[base + (size_t)s * 64 + d];
        float val = g * qv + (1.f - g) * cm;
        const size_t o = ((size_t)(b * Sc + s)) * Dc + hh * 64 + d;
        qmem[o] = val;
        qmemb[o] = (bf16)val;
    }
}

// ---------------------------------------------------------------- MFMA flash attention
// (frozen since R5: fixed-bound softmax, balanced pairs, k-parity split, XCD swizzle)
__global__ __launch_bounds__(256, 4) void attn_mfma(
    const bf16* __restrict__ qn, const bf16* __restrict__ kn,
    const bf16* __restrict__ vt, bf16* __restrict__ outp)
{
    const int flat = blockIdx.x;
    const int glow = flat & 7, t2 = flat >> 3;
    const int xq = t2 & 31, ghigh = t2 >> 5;
    const int g = glow | (ghigh << 3);
    const int h = g & 15, b = g >> 4;
    const int bh = b * Hc + h;
    const int tid = threadIdx.x, w = tid >> 6, lane = tid & 63;
    const int lrow = lane & 15, quad = lane >> 4;
    const int rhalf = w & 1, pgrp = w >> 1;
    __shared__ bf16 Ps[4][16][136];
    __shared__ float Ob[2][16][68];
    __shared__ float Lb[2][16];
    const bf16* kbase = kn + (size_t)bh * Sc * 64;
    const bf16* vtb = vt + (size_t)bh * 64 * Sc;
    const float SC = 0.1803368801f;   // 0.125 * log2(e)
#pragma unroll 1
    for (int ti = 0; ti < 2; ++ti) {
        const int zt = ti ? (63 - xq) : xq;
        const int qb = zt * 32;
        const int nc = (qb >> 7) + 1;
        const int par = pgrp ^ ti;
        const int rowg = qb + rhalf * 16 + quad * 4;
        bf16x8 qf[2];
        const bf16* qbase = qn + ((size_t)bh * Sc + qb + rhalf * 16) * 64;
#pragma unroll
        for (int ks = 0; ks < 2; ++ks)
            qf[ks] = *(const bf16x8*)(qbase + (size_t)lrow * 64 + ks * 32 + quad * 8);
        f32x4 oacc[4];
#pragma unroll
        for (int nt = 0; nt < 4; ++nt) { oacc[nt][0] = 0.f; oacc[nt][1] = 0.f; oacc[nt][2] = 0.f; oacc[nt][3] = 0.f; }
        float lsum[4] = {0.f, 0.f, 0.f, 0.f};
        for (int ci = par; ci < nc; ci += 2) {
            const int k0 = ci << 7;
            f32x4 sacc[8];
#pragma unroll
            for (int nt = 0; nt < 8; ++nt) { sacc[nt][0] = 0.f; sacc[nt][1] = 0.f; sacc[nt][2] = 0.f; sacc[nt][3] = 0.f; }
            __builtin_amdgcn_s_setprio(1);
#pragma unroll
            for (int ks = 0; ks < 2; ++ks) {
#pragma unroll
                for (int nh = 0; nh < 2; ++nh) {
                    bf16x8 kf[4];
#pragma unroll
                    for (int j = 0; j < 4; ++j)
                        kf[j] = *(const bf16x8*)(kbase + (size_t)(k0 + (nh * 4 + j) * 16 + lrow) * 64 + ks * 32 + quad * 8);
#pragma unroll
                    for (int j = 0; j < 4; ++j)
                        sacc[nh * 4 + j] = __builtin_amdgcn_mfma_f32_16x16x32_bf16(qf[ks], kf[j], sacc[nh * 4 + j], 0, 0, 0);
                }
            }
            __builtin_amdgcn_s_setprio(0);
#pragma unroll
            for (int nt = 0; nt < 8; ++nt) {
                const int kc = k0 + nt * 16 + lrow;
#pragma unroll
                for (int r = 0; r < 4; ++r) {
                    float p = (kc > rowg + r) ? 0.f : fexp2(fmaf(sacc[nt][r], SC, -12.f));
                    sacc[nt][r] = p;
                    lsum[r] += p;
                }
            }
#pragma unroll
            for (int nt = 0; nt < 8; ++nt)
#pragma unroll
                for (int r = 0; r < 4; ++r)
                    Ps[w][quad * 4 + r][nt * 16 + lrow] = (bf16)sacc[nt][r];
            __builtin_amdgcn_s_setprio(1);
#pragma unroll
            for (int ks2 = 0; ks2 < 4; ++ks2) {
                bf16x8 pf = *(const bf16x8*)&Ps[w][lrow][ks2 * 32 + quad * 8];
#pragma unroll
                for (int nt = 0; nt < 4; ++nt) {
                    bf16x8 vf = *(const bf16x8*)(vtb + (size_t)(nt * 16 + lrow) * Sc + k0 + ks2 * 32 + quad * 8);
                    oacc[nt] = __builtin_amdgcn_mfma_f32_16x16x32_bf16(pf, vf, oacc[nt], 0, 0, 0);
                }
            }
            __builtin_amdgcn_s_setprio(0);
        }
#pragma unroll
        for (int r = 0; r < 4; ++r)
#pragma unroll
            for (int off = 1; off < 16; off <<= 1) lsum[r] += __shfl_xor(lsum[r], off);
        if (pgrp == 1) {
#pragma unroll
            for (int nt = 0; nt < 4; ++nt)
#pragma unroll
                for (int r = 0; r < 4; ++r)
                    Ob[rhalf][quad * 4 + r][nt * 16 + lrow] = oacc[nt][r];
            if (lrow == 0)
#pragma unroll
                for (int r = 0; r < 4; ++r) Lb[rhalf][quad * 4 + r] = lsum[r];
        }
        __syncthreads();
        if (pgrp == 0) {
            float linv[4];
#pragma unroll
            for (int r = 0; r < 4; ++r)
                linv[r] = 1.f / (lsum[r] + Lb[rhalf][quad * 4 + r]);
#pragma unroll
            for (int nt = 0; nt < 4; ++nt)
#pragma unroll
                for (int r = 0; r < 4; ++r) {
                    const float o2 = Ob[rhalf][quad * 4 + r][nt * 16 + lrow];
                    outp[((size_t)b * Sc + rowg + r) * Dc + h * 64 + nt * 16 + lrow] =
                        (bf16)((oacc[nt][r] + o2) * linv[r]);
                }
        }
        __syncthreads();
    }
}

__global__ __launch_bounds__(256) void gather_active(
    const float* __restrict__ qmem, const bf16* __restrict__ qkv,
    float* __restrict__ xa, bf16* __restrict__ xab, float* __restrict__ va)
{
    const int t = blockIdx.x;
    const int b = t >> 6;
    const int s = Sc - 64 + (t & 63);
    const float* qrow = qmem + ((size_t)(b * Sc + s)) * Dc;
    const bf16* vrow = qkv + ((size_t)(b * Sc + s)) * 3072 + 2048;
    for (int i = threadIdx.x; i < Dc; i += 256) {
        float q = qrow[i];
        xa[(size_t)t * Dc + i] = q;
        xab[(size_t)t * Dc + i] = (bf16)q;
        va[(size_t)t * Dc + i] = (float)vrow[i];
    }
}

__global__ void wvec_kernel(const float* __restrict__ gamma,
                            float* __restrict__ wvec, float* __restrict__ wsum)
{
    const int t = threadIdx.x;
    const int b = t >> 6, si = t & 63;
    const int s = Sc - 64 + si;
    float v = gamma[b * Sc + s] * powf(0.95f, (float)(Sc - 1 - s));
    wvec[t] = v;
    __shared__ float red[128];
    red[t] = v; __syncthreads();
    for (int st = 64; st; st >>= 1) { if (t < st) red[t] += red[t + st]; __syncthreads(); }
    if (t == 0) wsum[0] = red[0];
}

__global__ __launch_bounds__(256) void phi2_f32(
    const float* __restrict__ z, float* __restrict__ feat, bf16* __restrict__ featb)
{
    const int f = blockIdx.x * 256 + threadIdx.x;
    const int t = blockIdx.y;
    if (f >= FPOLY) return;
    const float* zr = z + (size_t)t * 64;
    float v;
    if (f < 64) v = zr[f];
    else { int i = (f - 64) >> 6, j = (f - 64) & 63; v = zr[i] * zr[j] * 0.125f; }
    feat[(size_t)t * FPOLY + f] = v;
    featb[(size_t)t * FPOLY + f] = (bf16)v;
}

__global__ __launch_bounds__(256) void phi2_bf16(
    const float* __restrict__ z, bf16* __restrict__ feat)
{
    const int f = blockIdx.x * 256 + threadIdx.x;
    const int t = blockIdx.y;
    if (f >= FPOLY) return;
    const float* zr = z + (size_t)t * 64;
    float v;
    if (f < 64) v = zr[f];
    else { int i = (f - 64) >> 6, j = (f - 64) & 63; v = zr[i] * zr[j] * 0.125f; }
    feat[(size_t)t * FPOLY + f] = (bf16)v;
}

__global__ void dz_kernel(const float* __restrict__ dfeat, const float* __restrict__ za,
                          float* __restrict__ dz, bf16* __restrict__ dzb)
{
    const int t = blockIdx.x;
    const int k = threadIdx.x;
    const float* df = dfeat + (size_t)t * FPOLY;
    const float* z = za + (size_t)t * 64;
    float s1 = 0.f, s2 = 0.f;
    for (int j = 0; j < 64; ++j) {
        float zj = z[j];
        s1 += df[64 + k * 64 + j] * zj;
        s2 += df[64 + j * 64 + k] * zj;
    }
    float v = df[k] + 0.125f * (s1 + s2);
    dz[(size_t)t * 64 + k] = v;
    dzb[(size_t)t * 64 + k] = (bf16)v;
}

__global__ void sgate_kernel(const float* __restrict__ mg, float* __restrict__ out)
{
    out[0] = 1.f / (1.f + expf(-mg[0]));
}

// read merged [4096][5504] GEMM output: a=cols[0..2730), b=cols[2752..5482);
// write packed silu(a)*b into [4096][2752] (zero K-pad)
__global__ void swiglu_pack(const bf16* __restrict__ u, bf16* __restrict__ o)
{
    int i = blockIdx.x * 256 + threadIdx.x;
    if (i >= NTOK * FFNHP) return;
    int t = i / FFNHP, k = i % FFNHP;
    if (k >= FFNH) { o[i] = (bf16)0.f; return; }
    float a = (float)u[(size_t)t * 5504 + k];
    float b = (float)u[(size_t)t * 5504 + 2752 + k];
    o[i] = (bf16)(a / (1.f + __expf(-a)) * b);
}

// ---------------------------------------------------------------- launch
extern "C" void kernel_launch(void* const* d_in, const int* in_sizes, int n_in,
                              void* d_out, int out_size, void* d_ws, size_t ws_size,
                              hipStream_t stream)
{
    const float* x     = (const float*)d_in[0];
    const float* n1w   = (const float*)d_in[1];
    const float* n2w   = (const float*)d_in[2];
    const float* qkvw  = (const float*)d_in[3];
    const float* qnw   = (const float*)d_in[4];
    const float* knw   = (const float*)d_in[5];
    const float* gw1   = (const float*)d_in[6];
    const float* gw2   = (const float*)d_in[7];
    const float* mwk   = (const float*)d_in[8];
    const float* mw1   = (const float*)d_in[9];
    const float* mw2   = (const float*)d_in[10];
    const float* mgate = (const float*)d_in[11];
    const float* wow   = (const float*)d_in[12];
    const float* fw1   = (const float*)d_in[13];
    const float* fw2   = (const float*)d_in[14];
    const float* fw3   = (const float*)d_in[15];
    float* outp = (float*)d_out;

    char* base = (char*)d_ws;
    size_t off = 0;
    auto takeB = [&](size_t bytes) { char* p = base + off; off += (bytes + 255) & ~(size_t)255; return p; };

    // slabs (liveness-overlaid). A+E adjacent: featC4 (34MB) and ff13b (45MB) span both.
    // D+F adjacent: t1b4 (16.8MB) spans both.
    char* slabA  = takeB(22544384);  // partials / vt -> featC4(lo) -> ff13b(lo)
    char* slabE  = takeB(22544384);  // qmem fp32 -> featC4(hi) -> ff13b(hi)
    char* slabBC = takeB(16777216);  // qnb+knb -> x2 fp32
    char* slabD  = takeB(8388608);   // qmemb (st 3-7) -> t1b4(lo)
    char* slabF  = takeB(8388608);   // attnb -> t1b4(hi)
    char* slabG  = takeB(17301504);  // hb -> mw1b -> w1uT -> h2b
    float* partA = (float*)slabA;
    bf16* vt     = (bf16*)slabA;
    bf16* featC4 = (bf16*)slabA;  // 4096x4160x2 = 34.1MB (A+E)
    bf16* ff13b  = (bf16*)slabA;  // 4096x5504x2 = 45.1MB (A+E)
    float* qmem  = (float*)slabE;
    bf16* qnb = (bf16*)slabBC;    bf16* knb = (bf16*)(slabBC + 8388608);
    float* x2 = (float*)slabBC;
    bf16* qmemb = (bf16*)slabD;
    bf16* t1b4  = (bf16*)slabD;   // 4096x2048x2 = 16.8MB (D+F)
    bf16* attnb = (bf16*)slabF;
    bf16* hb = (bf16*)slabG;      bf16* mw1b = (bf16*)slabG;
    bf16* w1uT = (bf16*)slabG;    bf16* h2b = (bf16*)slabG;
    // merged qkv output (b,s,3072); dead after stage 4 -> reused as packed swiglu buf
    bf16* qkvb = (bf16*)takeB(25165824);
    bf16* ffpk = qkvb;            // 4096x2752x2 = 22.5MB <= 24MB

    // bf16 weights
    bf16* qkvwT = (bf16*)takeB(6291456);
    bf16* gw1T  = (bf16*)takeB(262144);    // 128 rows alloc / 64 real
    bf16* wowT  = (bf16*)takeB(2097152);
    bf16* mw1T  = (bf16*)takeB(17039360);
    bf16* mw2T  = (bf16*)takeB(4194304);
    bf16* fw13T = (bf16*)takeB(11272192);  // stacked: rows 0..2729=fw1, 2752..5481=fw3
    bf16* fw2T  = (bf16*)takeB(5636096);
    bf16* mw2b  = (bf16*)takeB(4194304);   // straight copy (2048,1024), fused in tconv
    bf16* mwkTb = (bf16*)takeB(262144);    // (64 real/128 alloc, 1024)
    bf16* wkuTb = (bf16*)takeB(262144);
    bf16* w2uT  = (bf16*)takeB(4194304);   // (1024, 2048)

    // fp32 misc
    float* zf    = (float*)takeB(1048576);
    float* gg1   = (float*)takeB(1048576);
    float* gamma = (float*)takeB(16384);
    float* wvec  = (float*)takeB(512);
    float* scal  = (float*)takeB(256);     // [0]=wsum [2]=sig(gate) [8..10]=invn
    float* psum  = (float*)takeB(131072);
    float* xa    = (float*)takeB(524288);
    float* va    = (float*)takeB(524288);
    float* za    = (float*)takeB(32768);
    float* featA = (float*)takeB(2129920);
    float* ua    = (float*)takeB(1048576);
    float* sua   = (float*)takeB(1048576);
    float* dpreda= (float*)takeB(524288);
    float* dua   = (float*)takeB(1048576);
    float* dfeata= (float*)takeB(2129920);
    float* dza   = (float*)takeB(32768);
    float* SA    = (float*)takeB(196608);  // 3 x 128x128 fp32
    float* CA    = (float*)takeB(196608);
    // bf16 misc
    bf16* featAb = (bf16*)takeB(1064960);
    bf16* suab   = (bf16*)takeB(524288);
    bf16* xab    = (bf16*)takeB(262144);
    bf16* duab   = (bf16*)takeB(524288);
    bf16* dpredab= (bf16*)takeB(262144);
    bf16* dzab   = (bf16*)takeB(16384);
    bf16* PT1Tb  = (bf16*)takeB(524288);   // (2048,128)
    bf16* PT2Tb  = (bf16*)takeB(262144);   // (1024,128)
    bf16* PT3Tb  = (bf16*)takeB(32768);
    bf16* duaTb  = (bf16*)takeB(524288);
    bf16* dpredaTb=(bf16*)takeB(262144);
    bf16* dzaTb  = (bf16*)takeB(32768);
    bf16* xaTb   = (bf16*)takeB(262144);
    bf16* featATb= (bf16*)takeB(1081344);  // (4224 alloc/4160 real, 128)
    bf16* suaTb  = (bf16*)takeB(524288);   // (2048, 128)
    // NS bf16
    bf16* Sb16  = (bf16*)takeB(98304);
    bf16* Cb16  = (bf16*)takeB(98304);
    bf16* FcAb  = (bf16*)takeB(98304);
    bf16* FcTAb = (bf16*)takeB(98304);

    auto gemmB = [&](int outbf, int cinbf, const bf16* A, const bf16* Bt,
                     const void* Cin, void* C, int M, int N, int K, int ldc,
                     float alpha, float beta, int act, const float* sptr) {
        dim3 grid((N + 127) / 128, M / 128);
        if (outbf && cinbf) gemm_bt<1, 1><<<grid, 256, 0, stream>>>(A, Bt, Cin, C, M, N, K, ldc, alpha, beta, act, sptr);
        else if (outbf)     gemm_bt<1, 0><<<grid, 256, 0, stream>>>(A, Bt, Cin, C, M, N, K, ldc, alpha, beta, act, sptr);
        else                gemm_bt<0, 0><<<grid, 256, 0, stream>>>(A, Bt, Cin, C, M, N, K, ldc, alpha, beta, act, sptr);
    };
    auto gemm64 = [&](const bf16* A, const bf16* Bt, const float* Cin, float* C,
                      int M, int N, int K, int ldc, const float* sptr) {
        dim3 grid(N / 64, M / 128);
        gemm_bt64<<<grid, 256, 0, stream>>>(A, Bt, Cin, C, M, N, K, ldc, sptr);
    };
    auto gdir = [&](int outbf, int cinbf, const bf16* A, const bf16* Bt,
                    const void* Cin, void* C, int M, int N, int K, int ldc,
                    float alpha, float beta, int act, const float* sptr) {
        dim3 grid((N + 127) / 128, (M + 127) / 128);
        if (outbf && cinbf)      gemm_direct<1, 1><<<grid, 256, 0, stream>>>(A, Bt, Cin, C, M, N, K, ldc, alpha, beta, act, sptr);
        else if (outbf)          gemm_direct<1, 0><<<grid, 256, 0, stream>>>(A, Bt, Cin, C, M, N, K, ldc, alpha, beta, act, sptr);
        else if (cinbf)          gemm_direct<0, 1><<<grid, 256, 0, stream>>>(A, Bt, Cin, C, M, N, K, ldc, alpha, beta, act, sptr);
        else                     gemm_direct<0, 0><<<grid, 256, 0, stream>>>(A, Bt, Cin, C, M, N, K, ldc, alpha, beta, act, sptr);
    };
    auto skp = [&](const bf16* A, const bf16* Bt, float* out,
                   int M, int N, int K, int KC) {
        int SK = (K + KC - 1) / KC;
        gemm_skp<<<dim3((N + 127) / 128, (M + 127) / 128, SK), 256, 0, stream>>>(A, Bt, partA, M, N, K, KC);
        int MN = M * N;
        skred<<<(MN + 255) / 256, 256, 0, stream>>>(partA, out, SK, MN);
    };
    auto tconv = [&](const float* W, bf16* Wt, int K, int N, int Kpad, bf16* Wc) {
        tconv_kernel<<<dim3((Kpad + 31) / 32, (N + 31) / 32), 256, 0, stream>>>(W, Wt, K, N, Kpad, Wc);
    };

    // 0. weight converts (mw1 tconv deferred until hb is dead; mw2b fused here)
    tconv(qkvw, qkvwT, Dc, 3 * Dc, Dc, nullptr);
    tconv(gw1, gw1T, Dc, GGH, Dc, nullptr);
    tconv(wow, wowT, Dc, Dc, Dc, nullptr);
    tconv(mw2, mw2T, MHID, Dc, MHID, mw2b);
    tconv(fw1, fw13T, Dc, FFNH, Dc, nullptr);
    tconv(fw3, fw13T + (size_t)2752 * Dc, Dc, FFNH, Dc, nullptr);
    tconv(fw2, fw2T, FFNH, Dc, FFNHP, nullptr);
    tconv(mwk, mwkTb, Dc, HDc, Dc, nullptr);
    sgate_kernel<<<1, 1, 0, stream>>>(mgate, scal + 2);

    // 1-2. rmsnorm, merged qkv, q/k norm+rope, gamma; then mw1 -> mw1T + mw1b (hb dead)
    rms_rows<<<NTOK, 256, 0, stream>>>(x, n1w, hb, Dc);
    gemmB(1, 0, hb, qkvwT, nullptr, qkvb, NTOK, 3 * Dc, Dc, 3 * Dc, 1.f, 0.f, 0, nullptr);
    snr_qk<<<dim3(Sc / 4, 32, Bc), 256, 0, stream>>>(qkvb, qnw, knw, qnb, knb);
    skp(hb, gw1T, gg1, NTOK, GGH, Dc, 256);        // SK=4, 128 blocks
    gamma_kernel<<<NTOK / 4, 256, 0, stream>>>(gg1, gw2, gamma);
    tconv(mw1, mw1T, FPOLY, MHID, FPOLY, mw1b);    // hb dead -> slabG reusable

    // 3. V transpose, q_mem (+qmemb), attention (XCD-clustered 1D grid)
    vtrans_kernel<<<dim3(Sc / 32, 2, Bc * Hc), 256, 0, stream>>>(qkvb, vt);
    kpsum_kernel<<<dim3(Bc * Hc, 16), 64, 0, stream>>>(knb, psum);
    qmem2_kernel<<<dim3(Bc * Hc, 16), 64, 0, stream>>>(qnb, knb, gamma, psum, qmem, qmemb);
    attn_mfma<<<dim3(1024), 256, 0, stream>>>(qnb, knb, vt, attnb);

    // 4. actives (vt dead -> slabA reusable as partials)
    gather_active<<<NACT, 256, 0, stream>>>(qmem, qkvb, xa, xab, va);
    wvec_kernel<<<1, 128, 0, stream>>>(gamma, wvec, scal);

    // 5. gradient chain (128 active tokens) -- split-K MFMA, fused reduce epilogues
    skp(xab, mwkTb, za, NACT, HDc, Dc, 64);                         // SK=16
    phi2_f32<<<dim3((FPOLY + 255) / 256, NACT), 256, 0, stream>>>(za, featA, featAb);
    gemm_skp<<<dim3(16, 1, 15), 256, 0, stream>>>(featAb, mw1T, partA, NACT, MHID, FPOLY, 288);
    skred_silu<<<1024, 256, 0, stream>>>(partA, ua, sua, suab);
    gemm_skp<<<dim3(8, 1, 16), 256, 0, stream>>>(suab, mw2T, partA, NACT, Dc, MHID, 128);
    skred_dpred<<<512, 256, 0, stream>>>(partA, va, wvec, scal, dpreda, dpredab);
    gemm_skp<<<dim3(16, 1, 8), 256, 0, stream>>>(dpredab, mw2b, partA, NACT, MHID, Dc, 128);
    skred_dsilu<<<1024, 256, 0, stream>>>(partA, ua, dua, duab);
    skp(duab, mw1b, dfeata, NACT, FPOLY, MHID, 256);                // SK=8, 264 blocks
    dz_kernel<<<NACT, 64, 0, stream>>>(dfeata, za, dza, dzab);

    // transposed bf16 copies (6-in-1)
    tconv6_kernel<<<dim3(4, 130, 6), 256, 0, stream>>>(
        dua, dpreda, dza, xa, featA, sua,
        duaTb, dpredaTb, dzaTb, xaTb, featATb, suaTb);

    // 6. Newton-Schulz: batched grams + fused 5-iter chain + batched P5
    gram_trick<<<1, 256, 0, stream>>>(za, SA);
    gram_bat<<<dim3(32, 5), 256, 0, stream>>>(suab, xab, duab, dpredab, dzab, partA);
    gram_red<<<320, 256, 0, stream>>>(partA, SA, CA);
    ns_norm_kernel<<<3, 256, 0, stream>>>(SA, CA, Sb16, Cb16, scal + 8);
    ns_fused<<<3, 256, 0, stream>>>(Sb16, Cb16, FcAb, FcTAb);
    gdir3_kernel<<<dim3(1, 16, 3), 256, 0, stream>>>(
        duaTb, dpredaTb, dzaTb, FcTAb, PT1Tb, PT2Tb, PT3Tb, scal + 8);

    // wkuT = 0.999*mwkT - 0.01*PT3T@xa
    gdir(1, 1, PT3Tb, xaTb, mwkTb, wkuTb, HDc, Dc, 128, Dc, -0.01f, 0.999f, 0, nullptr);
    //   w1uT = 0.999*mw1T - 0.01*PT1T@featA   (mw1b dead -> slabG reuse)
    gemmB(1, 1, PT1Tb, featATb, mw1T, w1uT, MHID, FPOLY, 128, FPOLY, -0.01f, 0.999f, 0, nullptr);
    //   w2uT = 0.999*mw2T - 0.01*PT2T@sua
    gemmB(1, 1, PT2Tb, suaTb, mw2T, w2uT, Dc, MHID, 128, MHID, -0.01f, 0.999f, 0, nullptr);

    // 7. x2 = x + attn@wo (128x64 tiles, 512 blocks); zf = qmem@wku via split-K (256 blocks)
    gemm64(attnb, wowT, x, x2, NTOK, Dc, Dc, Dc, nullptr);
    skp(qmemb, wkuTb, zf, NTOK, HDc, Dc, 128);                      // SK=8
    // (partials in slabA are consumed before phi2 overwrites it below)

    // 8. memory forward, de-chunked: M=4096 in one pass
    phi2_bf16<<<dim3((FPOLY + 255) / 256, NTOK), 256, 0, stream>>>(zf, featC4);
    gemmB(1, 0, featC4, w1uT, nullptr, t1b4, NTOK, MHID, FPOLY, MHID, 1.f, 0.f, 1, nullptr);
    gemm64(t1b4, w2uT, x2, x2, NTOK, Dc, MHID, Dc, scal + 2);

    // 9. FFN (swiglu): merged fw1+fw3 GEMM, fused pack, 128x64-tile fw2
    rms_rows<<<NTOK, 256, 0, stream>>>(x2, n2w, h2b, Dc);
    gemmB(1, 0, h2b, fw13T, nullptr, ff13b, NTOK, 5482, Dc, 5504, 1.f, 0.f, 0, nullptr);
    swiglu_pack<<<(NTOK * FFNHP + 255) / 256, 256, 0, stream>>>(ff13b, ffpk);
    gemm64(ffpk, fw2T, x2, outp, NTOK, Dc, FFNHP, Dc, nullptr);
}

// Round 8
// 1072.065 us; speedup vs baseline: 1.4095x; 1.0842x over previous
//
#include <hip/hip_runtime.h>
#include <math.h>

#define Bc 2
#define Sc 2048
#define Dc 1024
#define Hc 16
#define HDc 64
#define FPOLY 4160
#define MHID 2048
#define FFNH 2730
#define FFNHP 2752   // FFNH padded to mult of 32 (K pad, zero-filled)
#define GGH 64
#define NTOK 4096
#define NACT 128

typedef __bf16 bf16;
typedef __attribute__((ext_vector_type(8))) __bf16 bf16x8;
typedef __attribute__((ext_vector_type(4))) float f32x4;

#define AS1 __attribute__((address_space(1)))
#define AS3 __attribute__((address_space(3)))

__device__ __forceinline__ void gload16(const void* g, void* l) {
    __builtin_amdgcn_global_load_lds((AS1 const void*)g, (AS3 void*)l, 16, 0, 0);
}

__device__ __forceinline__ float fexp2(float x) { return __builtin_amdgcn_exp2f(x); }

// ---------------------------------------------------------------- bf16 MFMA GEMM (LDS, big tiles)
// C = act(alpha*[sptr]*A@Bt^T + beta*Cin).  A:(M,K) bf16 row-major, Bt:(N,K) bf16.
// 2-phase stage-ahead pipeline (T3-min) + bijective XCD-clustering swizzle (T1/m204).
template<int OUTBF, int CINBF>
__global__ __launch_bounds__(256) void gemm_bt(
    const bf16* __restrict__ A, const bf16* __restrict__ Bt,
    const void* __restrict__ Cin, void* __restrict__ Cout,
    int M, int N, int K, int ldc,
    float alpha, float beta, int act, const float* __restrict__ sptr)
{
    __shared__ bf16 As[2][128 * 32];
    __shared__ bf16 Bs[2][128 * 32];
    const int tid = threadIdx.x;
    const int w = tid >> 6, lane = tid & 63;
    const int gridX = gridDim.x;
    const int nwg = gridX * gridDim.y;
    const int orig = blockIdx.y * gridX + blockIdx.x;
    const int q8 = nwg >> 3, r8 = nwg & 7;
    const int xcd = orig & 7, lid = orig >> 3;
    const int sbase = (xcd < r8) ? xcd * (q8 + 1) : r8 * (q8 + 1) + (xcd - r8) * q8;
    const int swzid = sbase + lid;
    const int bm = (swzid / gridX) * 128, bn = (swzid % gridX) * 128;
    const int wm = (w >> 1) * 64, wn = (w & 1) * 64;
    f32x4 acc[4][4];
#pragma unroll
    for (int i = 0; i < 4; ++i)
#pragma unroll
        for (int j = 0; j < 4; ++j) { acc[i][j][0] = 0.f; acc[i][j][1] = 0.f; acc[i][j][2] = 0.f; acc[i][j][3] = 0.f; }
    const int idx0 = tid, idx1 = tid + 256;
    const int r0 = idx0 >> 2, r1 = idx1 >> 2;
    const int g0 = ((idx0 & 3) ^ ((r0 >> 1) & 3)) * 8;
    const int g1 = ((idx1 & 3) ^ ((r1 >> 1) & 3)) * 8;
    const int lrow = lane & 15;
    const int q = lane >> 4;
    int aoff[4], boff[4];
#pragma unroll
    for (int t = 0; t < 4; ++t) {
        int ar = wm + t * 16 + lrow;
        aoff[t] = ar * 32 + ((q ^ ((ar >> 1) & 3)) * 8);
        int br = wn + t * 16 + lrow;
        boff[t] = br * 32 + ((q ^ ((br >> 1) & 3)) * 8);
    }
    const bf16* Arow0 = A + (size_t)(bm + r0) * K + g0;
    const bf16* Arow1 = A + (size_t)(bm + r1) * K + g1;
    const bf16* Brow0 = Bt + (size_t)(bn + r0) * K + g0;
    const bf16* Brow1 = Bt + (size_t)(bn + r1) * K + g1;
    auto stage = [&](int bi, int k0) {
        char* la = (char*)&As[bi][0] + w * 1024;
        char* lb = (char*)&Bs[bi][0] + w * 1024;
        gload16(Arow0 + k0, la);
        gload16(Arow1 + k0, la + 4096);
        gload16(Brow0 + k0, lb);
        gload16(Brow1 + k0, lb + 4096);
    };
    auto compute = [&](int bi) {
        bf16x8 af[4], bfr[4];
#pragma unroll
        for (int t = 0; t < 4; ++t) af[t] = *(const bf16x8*)&As[bi][aoff[t]];
#pragma unroll
        for (int t = 0; t < 4; ++t) bfr[t] = *(const bf16x8*)&Bs[bi][boff[t]];
#pragma unroll
        for (int mt = 0; mt < 4; ++mt)
#pragma unroll
            for (int nt = 0; nt < 4; ++nt)
                acc[mt][nt] = __builtin_amdgcn_mfma_f32_16x16x32_bf16(af[mt], bfr[nt], acc[mt][nt], 0, 0, 0);
    };
    stage(0, 0);
    __syncthreads();
    int buf = 0;
    for (int k0 = 32; k0 < K; k0 += 32) {
        stage(buf ^ 1, k0);
        compute(buf);
        __syncthreads();
        buf ^= 1;
    }
    compute(buf);
    const float amul = alpha * (sptr ? *sptr : 1.f);
#pragma unroll
    for (int nt = 0; nt < 4; ++nt) {
        const int col = bn + wn + nt * 16 + lrow;
        if (col >= N) continue;
#pragma unroll
        for (int mt = 0; mt < 4; ++mt) {
            const int rbase = bm + wm + mt * 16 + q * 4;
#pragma unroll
            for (int r = 0; r < 4; ++r) {
                const size_t o = (size_t)(rbase + r) * ldc + col;
                float v = amul * acc[mt][nt][r];
                if (beta != 0.f)
                    v += beta * (CINBF ? (float)((const bf16*)Cin)[o] : ((const float*)Cin)[o]);
                if (act == 1) v = v / (1.f + __expf(-v));
                if (OUTBF) ((bf16*)Cout)[o] = (bf16)v;
                else       ((float*)Cout)[o] = v;
            }
        }
    }
}

// ---------------------------------------------------------------- 128x64-tile pipelined GEMM
__global__ __launch_bounds__(256) void gemm_bt64(
    const bf16* __restrict__ A, const bf16* __restrict__ Bt,
    const float* __restrict__ Cin, float* __restrict__ Cout,
    int M, int N, int K, int ldc, const float* __restrict__ sptr)
{
    __shared__ bf16 As[2][128 * 32];
    __shared__ bf16 Bs[2][64 * 32];
    const int tid = threadIdx.x;
    const int w = tid >> 6, lane = tid & 63;
    const int gridX = gridDim.x;
    const int nwg = gridX * gridDim.y;
    const int orig = blockIdx.y * gridX + blockIdx.x;
    const int q8 = nwg >> 3, r8 = nwg & 7;
    const int xcd = orig & 7, lid = orig >> 3;
    const int sbase = (xcd < r8) ? xcd * (q8 + 1) : r8 * (q8 + 1) + (xcd - r8) * q8;
    const int swzid = sbase + lid;
    const int bm = (swzid / gridX) * 128, bn = (swzid % gridX) * 64;
    const int wm = w * 32;
    f32x4 acc[2][4];
#pragma unroll
    for (int i = 0; i < 2; ++i)
#pragma unroll
        for (int j = 0; j < 4; ++j) { acc[i][j][0] = 0.f; acc[i][j][1] = 0.f; acc[i][j][2] = 0.f; acc[i][j][3] = 0.f; }
    const int idx0 = tid, idx1 = tid + 256;
    const int r0 = idx0 >> 2, r1 = idx1 >> 2;
    const int g0 = ((idx0 & 3) ^ ((r0 >> 1) & 3)) * 8;
    const int g1 = ((idx1 & 3) ^ ((r1 >> 1) & 3)) * 8;
    const int rB = tid >> 2;
    const int gB = ((tid & 3) ^ ((rB >> 1) & 3)) * 8;
    const int lrow = lane & 15;
    const int q = lane >> 4;
    int aoff[2], boff[4];
#pragma unroll
    for (int t = 0; t < 2; ++t) {
        int ar = wm + t * 16 + lrow;
        aoff[t] = ar * 32 + ((q ^ ((ar >> 1) & 3)) * 8);
    }
#pragma unroll
    for (int nt = 0; nt < 4; ++nt) {
        int br = nt * 16 + lrow;
        boff[nt] = br * 32 + ((q ^ ((br >> 1) & 3)) * 8);
    }
    const bf16* Arow0 = A + (size_t)(bm + r0) * K + g0;
    const bf16* Arow1 = A + (size_t)(bm + r1) * K + g1;
    const bf16* Brow  = Bt + (size_t)(bn + rB) * K + gB;
    auto stage = [&](int bi, int k0) {
        char* la = (char*)&As[bi][0] + w * 1024;
        char* lb = (char*)&Bs[bi][0] + w * 1024;
        gload16(Arow0 + k0, la);
        gload16(Arow1 + k0, la + 4096);
        gload16(Brow + k0, lb);
    };
    auto compute = [&](int bi) {
        bf16x8 af[2], bfr[4];
#pragma unroll
        for (int t = 0; t < 2; ++t) af[t] = *(const bf16x8*)&As[bi][aoff[t]];
#pragma unroll
        for (int nt = 0; nt < 4; ++nt) bfr[nt] = *(const bf16x8*)&Bs[bi][boff[nt]];
#pragma unroll
        for (int mt = 0; mt < 2; ++mt)
#pragma unroll
            for (int nt = 0; nt < 4; ++nt)
                acc[mt][nt] = __builtin_amdgcn_mfma_f32_16x16x32_bf16(af[mt], bfr[nt], acc[mt][nt], 0, 0, 0);
    };
    stage(0, 0);
    __syncthreads();
    int buf = 0;
    for (int k0 = 32; k0 < K; k0 += 32) {
        stage(buf ^ 1, k0);
        compute(buf);
        __syncthreads();
        buf ^= 1;
    }
    compute(buf);
    const float amul = sptr ? *sptr : 1.f;
#pragma unroll
    for (int nt = 0; nt < 4; ++nt) {
        const int col = bn + nt * 16 + lrow;
        if (col >= N) continue;
#pragma unroll
        for (int mt = 0; mt < 2; ++mt) {
            const int rbase = bm + wm + mt * 16 + q * 4;
#pragma unroll
            for (int r = 0; r < 4; ++r) {
                const size_t o = (size_t)(rbase + r) * ldc + col;
                Cout[o] = amul * acc[mt][nt][r] + Cin[o];
            }
        }
    }
}

// ---------------------------------------------------------------- barrier-free direct MFMA GEMM
template<int OUTBF, int CINBF>
__global__ __launch_bounds__(256) void gemm_direct(
    const bf16* __restrict__ A, const bf16* __restrict__ Bt,
    const void* __restrict__ Cin, void* __restrict__ Cout,
    int M, int N, int K, int ldc,
    float alpha, float beta, int act, const float* __restrict__ sptr)
{
    const int tid = threadIdx.x, w = tid >> 6, lane = tid & 63;
    const int lrow = lane & 15, quad = lane >> 4;
    const int bm = blockIdx.y * 128 + w * 32;
    const int bn = blockIdx.x * 128;
    f32x4 acc[2][8];
#pragma unroll
    for (int mt = 0; mt < 2; ++mt)
#pragma unroll
        for (int nt = 0; nt < 8; ++nt) { acc[mt][nt][0] = 0.f; acc[mt][nt][1] = 0.f; acc[mt][nt][2] = 0.f; acc[mt][nt][3] = 0.f; }
    const bf16* Abase = A + (size_t)(bm + lrow) * K + quad * 8;
    const bf16* Bbase = Bt + (size_t)(bn + lrow) * K + quad * 8;
#pragma unroll 2
    for (int k0 = 0; k0 < K; k0 += 32) {
        bf16x8 af0 = *(const bf16x8*)(Abase + k0);
        bf16x8 af1 = *(const bf16x8*)(Abase + (size_t)16 * K + k0);
#pragma unroll
        for (int nt = 0; nt < 8; ++nt) {
            bf16x8 bfr = *(const bf16x8*)(Bbase + (size_t)nt * 16 * K + k0);
            acc[0][nt] = __builtin_amdgcn_mfma_f32_16x16x32_bf16(af0, bfr, acc[0][nt], 0, 0, 0);
            acc[1][nt] = __builtin_amdgcn_mfma_f32_16x16x32_bf16(af1, bfr, acc[1][nt], 0, 0, 0);
        }
    }
    const float amul = alpha * (sptr ? *sptr : 1.f);
#pragma unroll
    for (int nt = 0; nt < 8; ++nt) {
        const int col = bn + nt * 16 + lrow;
        if (col >= N) continue;
#pragma unroll
        for (int mt = 0; mt < 2; ++mt) {
            const int rbase = bm + mt * 16 + quad * 4;
#pragma unroll
            for (int r = 0; r < 4; ++r) {
                const int row = rbase + r;
                if (row >= M) continue;
                const size_t o = (size_t)row * ldc + col;
                float v = amul * acc[mt][nt][r];
                if (beta != 0.f)
                    v += beta * (CINBF ? (float)((const bf16*)Cin)[o] : ((const float*)Cin)[o]);
                if (act == 1) v = v / (1.f + __expf(-v));
                if (OUTBF) ((bf16*)Cout)[o] = (bf16)v;
                else       ((float*)Cout)[o] = v;
            }
        }
    }
}

// batched P5 gdir: z=0 dua(M2048), z=1 dpred(M1024), z=2 dz(M64); N=K=ldc=128, bf16 out
__global__ __launch_bounds__(256) void gdir3_kernel(
    const bf16* __restrict__ A0, const bf16* __restrict__ A1, const bf16* __restrict__ A2,
    const bf16* __restrict__ B0, bf16* __restrict__ C0, bf16* __restrict__ C1,
    bf16* __restrict__ C2, const float* __restrict__ invn)
{
    const int z = blockIdx.z;
    const bf16* A; const bf16* Bt; bf16* C; int M;
    if      (z == 0) { A = A0; Bt = B0;         C = C0; M = 2048; }
    else if (z == 1) { A = A1; Bt = B0 + 16384; C = C1; M = 1024; }
    else             { A = A2; Bt = B0 + 32768; C = C2; M = 64;   }
    if (blockIdx.y * 128 >= M) return;
    const float s = invn[z];
    const int tid = threadIdx.x, w = tid >> 6, lane = tid & 63;
    const int lrow = lane & 15, quad = lane >> 4;
    const int bm = blockIdx.y * 128 + w * 32;
    f32x4 acc[2][8];
#pragma unroll
    for (int mt = 0; mt < 2; ++mt)
#pragma unroll
        for (int nt = 0; nt < 8; ++nt) { acc[mt][nt][0] = 0.f; acc[mt][nt][1] = 0.f; acc[mt][nt][2] = 0.f; acc[mt][nt][3] = 0.f; }
    const bf16* Abase = A + (size_t)(bm + lrow) * 128 + quad * 8;
    const bf16* Bbase = Bt + (size_t)lrow * 128 + quad * 8;
#pragma unroll
    for (int k0 = 0; k0 < 128; k0 += 32) {
        bf16x8 af0 = *(const bf16x8*)(Abase + k0);
        bf16x8 af1 = *(const bf16x8*)(Abase + (size_t)16 * 128 + k0);
#pragma unroll
        for (int nt = 0; nt < 8; ++nt) {
            bf16x8 bfr = *(const bf16x8*)(Bbase + (size_t)nt * 16 * 128 + k0);
            acc[0][nt] = __builtin_amdgcn_mfma_f32_16x16x32_bf16(af0, bfr, acc[0][nt], 0, 0, 0);
            acc[1][nt] = __builtin_amdgcn_mfma_f32_16x16x32_bf16(af1, bfr, acc[1][nt], 0, 0, 0);
        }
    }
#pragma unroll
    for (int nt = 0; nt < 8; ++nt) {
        const int col = nt * 16 + lrow;
#pragma unroll
        for (int mt = 0; mt < 2; ++mt) {
            const int rbase = bm + mt * 16 + quad * 4;
#pragma unroll
            for (int r = 0; r < 4; ++r) {
                const int row = rbase + r;
                if (row >= M) continue;
                C[(size_t)row * 128 + col] = (bf16)(s * acc[mt][nt][r]);
            }
        }
    }
}

// ---------------------------------------------------------------- split-K direct GEMM
__global__ __launch_bounds__(256) void gemm_skp(
    const bf16* __restrict__ A, const bf16* __restrict__ Bt,
    float* __restrict__ part, int M, int N, int K, int KC)
{
    const int tid = threadIdx.x, w = tid >> 6, lane = tid & 63;
    const int lrow = lane & 15, quad = lane >> 4;
    const int bm = blockIdx.y * 128 + w * 32;
    const int bn = blockIdx.x * 128;
    const int z = blockIdx.z;
    const int kb = z * KC;
    int ke = kb + KC; if (ke > K) ke = K;
    f32x4 acc[2][8];
#pragma unroll
    for (int mt = 0; mt < 2; ++mt)
#pragma unroll
        for (int nt = 0; nt < 8; ++nt) { acc[mt][nt][0] = 0.f; acc[mt][nt][1] = 0.f; acc[mt][nt][2] = 0.f; acc[mt][nt][3] = 0.f; }
    const bf16* Abase = A + (size_t)(bm + lrow) * K + quad * 8;
    const bf16* Bbase = Bt + (size_t)(bn + lrow) * K + quad * 8;
#pragma unroll 2
    for (int k0 = kb; k0 < ke; k0 += 32) {
        bf16x8 af0 = *(const bf16x8*)(Abase + k0);
        bf16x8 af1 = *(const bf16x8*)(Abase + (size_t)16 * K + k0);
#pragma unroll
        for (int nt = 0; nt < 8; ++nt) {
            bf16x8 bfr = *(const bf16x8*)(Bbase + (size_t)nt * 16 * K + k0);
            acc[0][nt] = __builtin_amdgcn_mfma_f32_16x16x32_bf16(af0, bfr, acc[0][nt], 0, 0, 0);
            acc[1][nt] = __builtin_amdgcn_mfma_f32_16x16x32_bf16(af1, bfr, acc[1][nt], 0, 0, 0);
        }
    }
    float* po = part + (size_t)z * M * N;
#pragma unroll
    for (int nt = 0; nt < 8; ++nt) {
        const int col = bn + nt * 16 + lrow;
        if (col >= N) continue;
#pragma unroll
        for (int mt = 0; mt < 2; ++mt) {
            const int rbase = bm + mt * 16 + quad * 4;
#pragma unroll
            for (int r = 0; r < 4; ++r) {
                const int row = rbase + r;
                if (row >= M) continue;
                po[(size_t)row * N + col] = acc[mt][nt][r];
            }
        }
    }
}

__global__ void skred(const float* __restrict__ part, float* __restrict__ out,
                      int SK, int MN)
{
    int i = blockIdx.x * 256 + threadIdx.x;
    if (i >= MN) return;
    float s = 0.f;
    for (int z = 0; z < SK; ++z) s += part[(size_t)z * MN + i];
    out[i] = s;
}

// fused split-K reduces for the gradient chain (NACT=128 rows)
__global__ void skred_silu(const float* __restrict__ part, float* __restrict__ ua,
                           float* __restrict__ sua, bf16* __restrict__ suab)
{
    int i = blockIdx.x * 256 + threadIdx.x;
    if (i >= NACT * MHID) return;
    float s = 0.f;
    for (int z = 0; z < 15; ++z) s += part[(size_t)z * NACT * MHID + i];
    ua[i] = s;
    float sg = s / (1.f + expf(-s));
    sua[i] = sg; suab[i] = (bf16)sg;
}

__global__ void skred_dpred(const float* __restrict__ part, const float* __restrict__ va,
                            const float* __restrict__ wvec, const float* __restrict__ wsum,
                            float* __restrict__ dpred, bf16* __restrict__ dpredb)
{
    int i = blockIdx.x * 256 + threadIdx.x;
    if (i >= NACT * Dc) return;
    float s = 0.f;
    for (int z = 0; z < 16; ++z) s += part[(size_t)z * NACT * Dc + i];
    int t = i >> 10;
    float v = 2.f * wvec[t] / (wsum[0] + 1e-8f) * (s - va[i]);
    dpred[i] = v; dpredb[i] = (bf16)v;
}

__global__ void skred_dsilu(const float* __restrict__ part, const float* __restrict__ u,
                            float* __restrict__ du, bf16* __restrict__ dub)
{
    int i = blockIdx.x * 256 + threadIdx.x;
    if (i >= NACT * MHID) return;
    float s = 0.f;
    for (int z = 0; z < 8; ++z) s += part[(size_t)z * NACT * MHID + i];
    float uv = u[i];
    float sg = 1.f / (1.f + expf(-uv));
    float v = s * sg * (1.f + uv * (1.f - sg));
    du[i] = v; dub[i] = (bf16)v;
}

// ---------------------------------------------------------------- batched 128x128 gram: X@X^T
__global__ __launch_bounds__(256) void gram_bat(
    const bf16* __restrict__ X0, const bf16* __restrict__ X1,
    const bf16* __restrict__ X2, const bf16* __restrict__ X3,
    const bf16* __restrict__ X4, float* __restrict__ part)
{
    const int z = blockIdx.x, m = blockIdx.y;
    const bf16* A; int K;
    if      (m == 0) { A = X0; K = 2048; }
    else if (m == 1) { A = X1; K = 1024; }
    else if (m == 2) { A = X2; K = 2048; }
    else if (m == 3) { A = X3; K = 1024; }
    else             { A = X4; K = 64;   }
    if (z * 64 >= K) return;
    const int tid = threadIdx.x, w = tid >> 6, lane = tid & 63;
    const int lrow = lane & 15, quad = lane >> 4;
    const int bm = w * 32;
    f32x4 acc[2][8];
#pragma unroll
    for (int mt = 0; mt < 2; ++mt)
#pragma unroll
        for (int nt = 0; nt < 8; ++nt) { acc[mt][nt][0] = 0.f; acc[mt][nt][1] = 0.f; acc[mt][nt][2] = 0.f; acc[mt][nt][3] = 0.f; }
    const bf16* Abase = A + (size_t)(bm + lrow) * K + quad * 8;
    const bf16* Bbase = A + (size_t)lrow * K + quad * 8;
#pragma unroll 2
    for (int k0 = z * 64; k0 < z * 64 + 64; k0 += 32) {
        bf16x8 af0 = *(const bf16x8*)(Abase + k0);
        bf16x8 af1 = *(const bf16x8*)(Abase + (size_t)16 * K + k0);
#pragma unroll
        for (int nt = 0; nt < 8; ++nt) {
            bf16x8 bfr = *(const bf16x8*)(Bbase + (size_t)nt * 16 * K + k0);
            acc[0][nt] = __builtin_amdgcn_mfma_f32_16x16x32_bf16(af0, bfr, acc[0][nt], 0, 0, 0);
            acc[1][nt] = __builtin_amdgcn_mfma_f32_16x16x32_bf16(af1, bfr, acc[1][nt], 0, 0, 0);
        }
    }
    float* po = part + (size_t)(m * 32 + z) * 16384;
#pragma unroll
    for (int nt = 0; nt < 8; ++nt) {
        const int col = nt * 16 + lrow;
#pragma unroll
        for (int mt = 0; mt < 2; ++mt)
#pragma unroll
            for (int r = 0; r < 4; ++r)
                po[(size_t)(bm + mt * 16 + quad * 4 + r) * 128 + col] = acc[mt][nt][r];
    }
}

__global__ void gram_red(const float* __restrict__ part,
                         float* __restrict__ SA, float* __restrict__ CA)
{
    int idx = blockIdx.x * 256 + threadIdx.x;   // 5*16384
    if (idx >= 81920) return;
    int m = idx >> 14, e = idx & 16383;
    int SK = (m == 0 || m == 2) ? 32 : (m == 4 ? 1 : 16);
    float s = 0.f;
    for (int z = 0; z < SK; ++z) s += part[(size_t)(m * 32 + z) * 16384 + e];
    float* dst = (m == 0) ? SA + 16384 : (m == 1) ? SA + 32768 :
                 (m == 2) ? CA : (m == 3) ? CA + 16384 : CA + 32768;
    dst[e] = s;
}

// ---------------------------------------------------------------- polynomial-kernel gram
__global__ __launch_bounds__(256) void gram_trick(
    const float* __restrict__ za, float* __restrict__ S)
{
    __shared__ float z[128 * 65];
    for (int i = threadIdx.x; i < 8192; i += 256) {
        int r = i >> 6, d = i & 63;
        z[r * 65 + d] = za[i];
    }
    __syncthreads();
    for (int idx = threadIdx.x; idx < 16384; idx += 256) {
        int i = idx >> 7, j = idx & 127;
        float dot = 0.f;
#pragma unroll
        for (int d = 0; d < 64; ++d) dot += z[i * 65 + d] * z[j * 65 + d];
        S[idx] = dot + dot * dot * 0.015625f;
    }
}

__global__ __launch_bounds__(256) void ns_norm_kernel(
    const float* __restrict__ S, const float* __restrict__ C,
    bf16* __restrict__ Sb, bf16* __restrict__ Cb, float* __restrict__ invn)
{
    const int z = blockIdx.x;
    const float* s = S + (size_t)z * 16384;
    const float* c = C + (size_t)z * 16384;
    float acc = 0.f;
    for (int i = threadIdx.x; i < 16384; i += 256) acc += s[i] * c[i];
    __shared__ float red[256];
    red[threadIdx.x] = acc; __syncthreads();
    for (int st = 128; st; st >>= 1) {
        if (threadIdx.x < st) red[threadIdx.x] += red[threadIdx.x + st];
        __syncthreads();
    }
    float inv = 1.f / (sqrtf(red[0]) + 1e-7f);
    float inv2 = inv * inv;
    for (int i = threadIdx.x; i < 16384; i += 256) {
        Cb[(size_t)z * 16384 + i] = (bf16)(c[i] * inv2);
        Sb[(size_t)z * 16384 + i] = (bf16)s[i];
    }
    if (threadIdx.x == 0) invn[z] = inv;
}

// ---------------------------------------------------------------- fused Newton-Schulz (batched z=3)
__device__ __forceinline__ int swz(int row, int col) {
    return row * 128 + ((((col >> 3) ^ (row & 7)) << 3) | (col & 7));
}

__global__ __launch_bounds__(256) void ns_fused(
    const bf16* __restrict__ Sg, const bf16* __restrict__ Cg,
    bf16* __restrict__ Fcg, bf16* __restrict__ FcTg)
{
    __shared__ bf16 Cl[16384], Ml[16384], MTl[16384], FTl[16384];
    const int z = blockIdx.x;
    const bf16* S = Sg + (size_t)z * 16384;
    bf16* Fc = Fcg + (size_t)z * 16384;
    bf16* FcT = FcTg + (size_t)z * 16384;
    const int tid = threadIdx.x, w = tid >> 6, lane = tid & 63;
    const int lrow = lane & 15, quad = lane >> 4;
    const int bm = w * 32;
    for (int i = tid; i < 2048; i += 256) {
        const int row = i >> 4, c = i & 15;
        *(bf16x8*)&Cl[row * 128 + ((c ^ (row & 7)) << 3)] =
            *(const bf16x8*)(Cg + (size_t)z * 16384 + (size_t)row * 128 + c * 8);
    }
    __syncthreads();
    const int r0 = bm + lrow, r1 = r0 + 16;
    const int rx = lrow & 7;
    f32x4 acc[2][8];
    auto zacc = [&]() {
#pragma unroll
        for (int mt = 0; mt < 2; ++mt)
#pragma unroll
            for (int nt = 0; nt < 8; ++nt) { acc[mt][nt][0] = 0.f; acc[mt][nt][1] = 0.f; acc[mt][nt][2] = 0.f; acc[mt][nt][3] = 0.f; }
    };
    auto inner = [&](bf16x8 af0, bf16x8 af1, const bf16* Bt, int c) {
#pragma unroll
        for (int nt = 0; nt < 8; ++nt) {
            const int br = nt * 16 + lrow;
            bf16x8 bfr = *(const bf16x8*)&Bt[br * 128 + ((c ^ (br & 7)) << 3)];
            acc[0][nt] = __builtin_amdgcn_mfma_f32_16x16x32_bf16(af0, bfr, acc[0][nt], 0, 0, 0);
            acc[1][nt] = __builtin_amdgcn_mfma_f32_16x16x32_bf16(af1, bfr, acc[1][nt], 0, 0, 0);
        }
    };
    auto gemm_ll = [&](const bf16* Al, const bf16* Bt) {
        zacc();
#pragma unroll
        for (int k0 = 0; k0 < 128; k0 += 32) {
            const int c = (k0 >> 3) + quad;
            bf16x8 af0 = *(const bf16x8*)&Al[r0 * 128 + ((c ^ rx) << 3)];
            bf16x8 af1 = *(const bf16x8*)&Al[r1 * 128 + ((c ^ rx) << 3)];
            inner(af0, af1, Bt, c);
        }
    };
    auto gemm_gl = [&](const bf16* Ag, const bf16* Bt) {
        zacc();
#pragma unroll
        for (int k0 = 0; k0 < 128; k0 += 32) {
            const int c = (k0 >> 3) + quad;
            bf16x8 af0 = *(const bf16x8*)(Ag + (size_t)r0 * 128 + k0 + quad * 8);
            bf16x8 af1 = *(const bf16x8*)(Ag + (size_t)r1 * 128 + k0 + quad * 8);
            inner(af0, af1, Bt, c);
        }
    };

    for (int t = 0; t < 5; ++t) {
        gemm_gl(S, Cl);
#pragma unroll
        for (int mt = 0; mt < 2; ++mt)
#pragma unroll
            for (int nt = 0; nt < 8; ++nt)
#pragma unroll
                for (int r = 0; r < 4; ++r) {
                    const int row = bm + mt * 16 + quad * 4 + r, col = nt * 16 + lrow;
                    const bf16 v = (bf16)acc[mt][nt][r];
                    Ml[swz(row, col)] = v;
                    MTl[swz(col, row)] = v;
                }
        __syncthreads();
        gemm_ll(Ml, MTl);
#pragma unroll
        for (int mt = 0; mt < 2; ++mt)
#pragma unroll
            for (int nt = 0; nt < 8; ++nt)
#pragma unroll
                for (int r = 0; r < 4; ++r) {
                    const int row = bm + mt * 16 + quad * 4 + r, col = nt * 16 + lrow;
                    float v = 2.0315f * acc[mt][nt][r] - 4.775f * (float)Ml[swz(row, col)];
                    if (row == col) v += 3.4445f;
                    FTl[swz(col, row)] = (bf16)v;
                    if (t == 0) Fc[(size_t)row * 128 + col] = (bf16)v;
                }
        __syncthreads();
        if (t > 0) {
            gemm_gl(Fc, FTl);
            if (t == 4) {
#pragma unroll
                for (int mt = 0; mt < 2; ++mt)
#pragma unroll
                    for (int nt = 0; nt < 8; ++nt)
#pragma unroll
                        for (int r = 0; r < 4; ++r) {
                            const int row = bm + mt * 16 + quad * 4 + r, col = nt * 16 + lrow;
                            FcT[(size_t)col * 128 + row] = (bf16)acc[mt][nt][r];
                        }
                return;
            }
#pragma unroll
            for (int mt = 0; mt < 2; ++mt)
#pragma unroll
                for (int nt = 0; nt < 8; ++nt)
#pragma unroll
                    for (int r = 0; r < 4; ++r) {
                        const int row = bm + mt * 16 + quad * 4 + r, col = nt * 16 + lrow;
                        Fc[(size_t)row * 128 + col] = (bf16)acc[mt][nt][r];
                    }
        }
        gemm_ll(Cl, FTl);
#pragma unroll
        for (int mt = 0; mt < 2; ++mt)
#pragma unroll
            for (int nt = 0; nt < 8; ++nt)
#pragma unroll
                for (int r = 0; r < 4; ++r) {
                    const int row = bm + mt * 16 + quad * 4 + r, col = nt * 16 + lrow;
                    Ml[swz(col, row)] = (bf16)acc[mt][nt][r];
                }
        __syncthreads();
        gemm_ll(Ml, FTl);
#pragma unroll
        for (int mt = 0; mt < 2; ++mt)
#pragma unroll
            for (int nt = 0; nt < 8; ++nt)
#pragma unroll
                for (int r = 0; r < 4; ++r) {
                    const int row = bm + mt * 16 + quad * 4 + r, col = nt * 16 + lrow;
                    Cl[swz(row, col)] = (bf16)acc[mt][nt][r];
                }
        __syncthreads();
    }
}

// ---------------------------------------------------------------- converts
__global__ __launch_bounds__(256) void tconv_kernel(
    const float* __restrict__ W, bf16* __restrict__ Wt, int K, int N, int Kpad,
    bf16* __restrict__ Wc)
{
    __shared__ float t[32][33];
    const int k0 = blockIdx.x * 32, n0 = blockIdx.y * 32;
    const int tx = threadIdx.x & 31, ty = threadIdx.x >> 5;
#pragma unroll
    for (int r = 0; r < 4; ++r) {
        int gk = k0 + ty + r * 8, gn = n0 + tx;
        bool ok = (gk < K && gn < N);
        float v = ok ? W[(size_t)gk * N + gn] : 0.f;
        t[ty + r * 8][tx] = v;
        if (Wc && ok) Wc[(size_t)gk * N + gn] = (bf16)v;
    }
    __syncthreads();
#pragma unroll
    for (int r = 0; r < 4; ++r) {
        int gn = n0 + ty + r * 8, gk = k0 + tx;
        if (gn < N && gk < Kpad) Wt[(size_t)gn * Kpad + gk] = (bf16)t[tx][ty + r * 8];
    }
}

// six 128-row transposed bf16 copies in one launch (all K=128, Kpad=128)
__global__ __launch_bounds__(256) void tconv6_kernel(
    const float* __restrict__ s0, const float* __restrict__ s1,
    const float* __restrict__ s2, const float* __restrict__ s3,
    const float* __restrict__ s4, const float* __restrict__ s5,
    bf16* __restrict__ d0, bf16* __restrict__ d1, bf16* __restrict__ d2,
    bf16* __restrict__ d3, bf16* __restrict__ d4, bf16* __restrict__ d5)
{
    const int zz = blockIdx.z;
    const float* W; bf16* Wt; int N;
    if      (zz == 0) { W = s0; Wt = d0; N = 2048; }
    else if (zz == 1) { W = s1; Wt = d1; N = 1024; }
    else if (zz == 2) { W = s2; Wt = d2; N = 64;   }
    else if (zz == 3) { W = s3; Wt = d3; N = 1024; }
    else if (zz == 4) { W = s4; Wt = d4; N = 4160; }
    else              { W = s5; Wt = d5; N = 2048; }
    const int k0 = blockIdx.x * 32, n0 = blockIdx.y * 32;
    if (n0 >= N) return;
    __shared__ float t[32][33];
    const int tx = threadIdx.x & 31, ty = threadIdx.x >> 5;
#pragma unroll
    for (int r = 0; r < 4; ++r) {
        int gk = k0 + ty + r * 8, gn = n0 + tx;
        t[ty + r * 8][tx] = (gk < 128 && gn < N) ? W[(size_t)gk * N + gn] : 0.f;
    }
    __syncthreads();
#pragma unroll
    for (int r = 0; r < 4; ++r) {
        int gn = n0 + ty + r * 8, gk = k0 + tx;
        if (gn < N) Wt[(size_t)gn * 128 + gk] = (bf16)t[tx][ty + r * 8];
    }
}

// qkv (b,s,3072) v-part -> vt (b,h,d,s)
__global__ __launch_bounds__(256) void vtrans_kernel(
    const bf16* __restrict__ qkv, bf16* __restrict__ vt)
{
    __shared__ bf16 t[32][33];
    const int s0 = blockIdx.x * 32, d0 = blockIdx.y * 32, bh = blockIdx.z;
    const int b = bh >> 4, h = bh & 15;
    const int tx = threadIdx.x & 31, ty = threadIdx.x >> 5;
#pragma unroll
    for (int r = 0; r < 4; ++r) {
        int s = s0 + ty + r * 8;
        t[ty + r * 8][tx] = qkv[((size_t)b * Sc + s) * 3072 + 2048 + h * 64 + d0 + tx];
    }
    __syncthreads();
#pragma unroll
    for (int r = 0; r < 4; ++r) {
        int d = d0 + ty + r * 8;
        vt[((size_t)bh * 64 + d) * Sc + s0 + tx] = t[tx][ty + r * 8];
    }
}

// ---------------------------------------------------------------- small kernels
__global__ __launch_bounds__(256) void rms_rows(
    const float* __restrict__ in, const float* __restrict__ w,
    bf16* __restrict__ out, int D)
{
    const int row = blockIdx.x;
    const float* r = in + (size_t)row * D;
    bf16* o = out + (size_t)row * D;
    float s = 0.f;
    for (int i = threadIdx.x; i < D; i += 256) { float v = r[i]; s += v * v; }
    __shared__ float red[256];
    red[threadIdx.x] = s;
    __syncthreads();
    for (int st = 128; st; st >>= 1) {
        if (threadIdx.x < st) red[threadIdx.x] += red[threadIdx.x + st];
        __syncthreads();
    }
    float rs = rsqrtf(red[0] / (float)D + 1e-6f);
    for (int i = threadIdx.x; i < D; i += 256) o[i] = (bf16)(r[i] * rs * w[i]);
}

__global__ __launch_bounds__(256) void gamma_kernel(
    const float* __restrict__ gg1, const float* __restrict__ w2,
    float* __restrict__ gamma)
{
    const int tid = threadIdx.x, w = tid >> 6, lane = tid & 63;
    const int t = blockIdx.x * 4 + w;
    float v = gg1[(size_t)t * GGH + lane];
    v = v / (1.f + expf(-v));
    v *= w2[lane];
#pragma unroll
    for (int off = 32; off; off >>= 1) v += __shfl_xor(v, off);
    if (lane == 0) gamma[t] = 1.f / (1.f + expf(-v));
}

// rmsnorm+rope for q AND k in one launch: blockIdx.y in [0,32): y>>4 selects q/k
__global__ __launch_bounds__(256) void snr_qk(
    const bf16* __restrict__ src, const float* __restrict__ qw, const float* __restrict__ kw,
    bf16* __restrict__ qd, bf16* __restrict__ kd)
{
    const int tid = threadIdx.x, wv = tid >> 6, lane = tid & 63;
    const int s = blockIdx.x * 4 + wv;
    const int y = blockIdx.y, b = blockIdx.z;
    const int h = y & 15, which = y >> 4;
    const float* w = which ? kw : qw;
    bf16* dst = which ? kd : qd;
    const size_t row = ((size_t)b * Sc + s) * 3072 + which * 1024 + h * 64;
    float v = (float)src[row + lane];
    float ss = v * v;
#pragma unroll
    for (int off = 32; off; off >>= 1) ss += __shfl_xor(ss, off);
    v = v * rsqrtf(ss / 64.f + 1e-6f) * w[lane];
    const int j = lane & 31;
    float inv = powf(10000.f, -(float)j / 32.f);
    float ang = (float)s * inv;
    float sn = sinf(ang), cs = cosf(ang);
    float p = __shfl_xor(v, 32);
    float o;
    if (lane < 32) o = v * cs - p * sn;
    else           o = p * sn + v * cs;
    const size_t od = (((size_t)b * Hc + h) * Sc + s) * 64 + lane;
    dst[od] = (bf16)o;
}

__global__ void kpsum_kernel(const bf16* __restrict__ kn, float* __restrict__ psum)
{
    const int bh = blockIdx.x, c = blockIdx.y, d = threadIdx.x;
    const size_t base = (size_t)bh * Sc * 64 + (size_t)c * 128 * 64 + d;
    float s = 0.f;
    for (int i = 0; i < 128; ++i) s += (float)kn[base + (size_t)i * 64];
    psum[((size_t)bh * 16 + c) * 64 + d] = s;
}

// q_mem: writes fp32 qmem AND bf16 qmemb
__global__ void qmem2_kernel(
    const bf16* __restrict__ qn, const bf16* __restrict__ kn,
    const float* __restrict__ gamma, const float* __restrict__ psum,
    float* __restrict__ qmem, bf16* __restrict__ qmemb)
{
    const int bh = blockIdx.x, c = blockIdx.y;
    const int b = bh >> 4, hh = bh & 15;
    const int d = threadIdx.x;
    const size_t base = (size_t)bh * Sc * 64;
    float run = 0.f;
    for (int cc = 0; cc < c; ++cc) run += psum[((size_t)bh * 16 + cc) * 64 + d];
    for (int s = c * 128; s < c * 128 + 128; ++s) {
        run += (float)kn[base + (size_t)s * 64 + d];
        float cm = run / (float)(s + 1);
        float g = gamma[b * Sc + s];
        float qv = (float)qn[base + (size_t)s * 64 + d];
        float val = g * qv + (1.f - g) * cm;
        const size_t o = ((size_t)(b * Sc + s)) * Dc + hh * 64 + d;
        qmem[o] = val;
        qmemb[o] = (bf16)val;
    }
}

// ---------------------------------------------------------------- MFMA flash attention
// NEW: 64-row Q tiles, pairs (p, 31-p) per block (17 chunk-units const), all 4 waves
// share each 128-wide K/V chunk via cooperative double-buffered LDS staging
// (global_load_lds, linear dest + XOR-swizzled SOURCE so ds_read_b128 fragment reads
// are <=2-way bank-conflicted). Cuts global traffic 8x (was: each wave privately
// loaded its full chunk) and removes the divergent-load L1-transaction bottleneck.
// Fixed-bound softmax retained. 512 blocks, 73KB LDS -> 2 blocks/CU.
// XCD clustering: blocks of one (b,h) share flat%8 -> same XCD L2.
__global__ __launch_bounds__(256) void attn_mfma(
    const bf16* __restrict__ qn, const bf16* __restrict__ kn,
    const bf16* __restrict__ vt, bf16* __restrict__ outp)
{
    const int flat = blockIdx.x;
    const int glow = flat & 7, t2 = flat >> 3;
    const int p = t2 & 15, ghigh = t2 >> 4;
    const int g = glow | (ghigh << 3);
    const int h = g & 15, b = g >> 4;
    const int bh = b * Hc + h;
    const int tid = threadIdx.x, w = tid >> 6, lane = tid & 63;
    const int lrow = lane & 15, quad = lane >> 4;
    __shared__ bf16 Ks[2][128 * 64];   // [row 0..128)[unit16 0..8), swizzled units
    __shared__ bf16 Vs[2][64 * 128];   // [d 0..64)[unit16 0..16), swizzled units
    __shared__ bf16 Ps[4][16][72];
    const bf16* kbase = kn + (size_t)bh * Sc * 64;
    const bf16* vtb = vt + (size_t)bh * 64 * Sc;
    const float SC = 0.1803368801f;   // 0.125 * log2(e)
    const int zt0 = p, zt1 = 31 - p;
    const int nc0 = (zt0 >> 1) + 1, nc1 = (zt1 >> 1) + 1;
    const int nct = nc0 + nc1;
    const int krr = lane >> 3, kur = lane & 7;     // K stage: row-sub, unit
    const int vrr = lane >> 4, vur = lane & 15;    // V stage: row-sub, unit
    auto stage = [&](int bi, int k0) {
#pragma unroll
        for (int rr = 0; rr < 4; ++rr) {
            const int row = (rr * 4 + w) * 8 + krr;
            gload16(kbase + (size_t)(k0 + row) * 64 + ((kur ^ krr) << 3),
                    (char*)&Ks[bi][0] + (rr * 4 + w) * 1024);
        }
#pragma unroll
        for (int rr = 0; rr < 4; ++rr) {
            const int vrow = (rr * 4 + w) * 4 + vrr;
            gload16(vtb + (size_t)vrow * Sc + k0 + ((vur ^ (vrow & 7)) << 3),
                    (char*)&Vs[bi][0] + (rr * 4 + w) * 1024);
        }
    };
    int qb = zt0 * 64;
    int rowg = qb + w * 16 + quad * 4;
    bf16x8 qf[2];
    {
        const bf16* qbase = qn + ((size_t)bh * Sc + qb + w * 16) * 64;
#pragma unroll
        for (int ks = 0; ks < 2; ++ks)
            qf[ks] = *(const bf16x8*)(qbase + (size_t)lrow * 64 + ks * 32 + quad * 8);
    }
    f32x4 oacc[4];
#pragma unroll
    for (int nt = 0; nt < 4; ++nt) { oacc[nt][0] = 0.f; oacc[nt][1] = 0.f; oacc[nt][2] = 0.f; oacc[nt][3] = 0.f; }
    float lsum[4] = {0.f, 0.f, 0.f, 0.f};
    auto writeout = [&]() {
#pragma unroll
        for (int r = 0; r < 4; ++r)
#pragma unroll
            for (int off = 1; off < 16; off <<= 1) lsum[r] += __shfl_xor(lsum[r], off);
        float linv[4];
#pragma unroll
        for (int r = 0; r < 4; ++r) linv[r] = 1.f / lsum[r];
#pragma unroll
        for (int nt = 0; nt < 4; ++nt)
#pragma unroll
            for (int r = 0; r < 4; ++r)
                outp[((size_t)b * Sc + rowg + r) * Dc + h * 64 + nt * 16 + lrow] =
                    (bf16)(oacc[nt][r] * linv[r]);
    };
    int buf = 0;
    stage(0, 0);
    __syncthreads();
    for (int it = 0; it < nct; ++it) {
        const int nxt = it + 1;
        if (nxt < nct)
            stage(buf ^ 1, (nxt < nc0 ? nxt : nxt - nc0) * 128);
        const int k0 = (it < nc0 ? it : it - nc0) * 128;
        // ---- QK^T from LDS
        f32x4 sacc[8];
#pragma unroll
        for (int nt = 0; nt < 8; ++nt) { sacc[nt][0] = 0.f; sacc[nt][1] = 0.f; sacc[nt][2] = 0.f; sacc[nt][3] = 0.f; }
        __builtin_amdgcn_s_setprio(1);
#pragma unroll
        for (int ks = 0; ks < 2; ++ks)
#pragma unroll
            for (int nt = 0; nt < 8; ++nt) {
                const int krow = nt * 16 + lrow;
                bf16x8 kf = *(const bf16x8*)&Ks[buf][krow * 64 + (((ks * 4 + quad) ^ (lrow & 7)) << 3)];
                sacc[nt] = __builtin_amdgcn_mfma_f32_16x16x32_bf16(qf[ks], kf, sacc[nt], 0, 0, 0);
            }
        __builtin_amdgcn_s_setprio(0);
        // ---- fixed-bound softmax weights + causal mask
#pragma unroll
        for (int nt = 0; nt < 8; ++nt) {
            const int kc = k0 + nt * 16 + lrow;
#pragma unroll
            for (int r = 0; r < 4; ++r) {
                float pv = (kc > rowg + r) ? 0.f : fexp2(fmaf(sacc[nt][r], SC, -12.f));
                sacc[nt][r] = pv;
                lsum[r] += pv;
            }
        }
        // ---- PV in two 64-col halves (Ps wave-private, no barrier)
#pragma unroll
        for (int half = 0; half < 2; ++half) {
#pragma unroll
            for (int nt = 0; nt < 4; ++nt)
#pragma unroll
                for (int r = 0; r < 4; ++r)
                    Ps[w][quad * 4 + r][nt * 16 + lrow] = (bf16)sacc[half * 4 + nt][r];
            __builtin_amdgcn_s_setprio(1);
#pragma unroll
            for (int k2 = 0; k2 < 2; ++k2) {
                const int ks2 = half * 2 + k2;
                bf16x8 pf = *(const bf16x8*)&Ps[w][lrow][k2 * 32 + quad * 8];
#pragma unroll
                for (int nt = 0; nt < 4; ++nt) {
                    const int vrow = nt * 16 + lrow;
                    bf16x8 vf = *(const bf16x8*)&Vs[buf][vrow * 128 + (((ks2 * 4 + quad) ^ (lrow & 7)) << 3)];
                    oacc[nt] = __builtin_amdgcn_mfma_f32_16x16x32_bf16(pf, vf, oacc[nt], 0, 0, 0);
                }
            }
            __builtin_amdgcn_s_setprio(0);
        }
        __syncthreads();
        buf ^= 1;
        if (it == nc0 - 1) {
            // finish tile0, switch to tile1
            writeout();
            qb = zt1 * 64;
            rowg = qb + w * 16 + quad * 4;
            const bf16* qbase = qn + ((size_t)bh * Sc + qb + w * 16) * 64;
#pragma unroll
            for (int ks = 0; ks < 2; ++ks)
                qf[ks] = *(const bf16x8*)(qbase + (size_t)lrow * 64 + ks * 32 + quad * 8);
#pragma unroll
            for (int nt = 0; nt < 4; ++nt) { oacc[nt][0] = 0.f; oacc[nt][1] = 0.f; oacc[nt][2] = 0.f; oacc[nt][3] = 0.f; }
#pragma unroll
            for (int r = 0; r < 4; ++r) lsum[r] = 0.f;
        }
    }
    writeout();
}

__global__ __launch_bounds__(256) void gather_active(
    const float* __restrict__ qmem, const bf16* __restrict__ qkv,
    float* __restrict__ xa, bf16* __restrict__ xab, float* __restrict__ va)
{
    const int t = blockIdx.x;
    const int b = t >> 6;
    const int s = Sc - 64 + (t & 63);
    const float* qrow = qmem + ((size_t)(b * Sc + s)) * Dc;
    const bf16* vrow = qkv + ((size_t)(b * Sc + s)) * 3072 + 2048;
    for (int i = threadIdx.x; i < Dc; i += 256) {
        float q = qrow[i];
        xa[(size_t)t * Dc + i] = q;
        xab[(size_t)t * Dc + i] = (bf16)q;
        va[(size_t)t * Dc + i] = (float)vrow[i];
    }
}

__global__ void wvec_kernel(const float* __restrict__ gamma,
                            float* __restrict__ wvec, float* __restrict__ wsum)
{
    const int t = threadIdx.x;
    const int b = t >> 6, si = t & 63;
    const int s = Sc - 64 + si;
    float v = gamma[b * Sc + s] * powf(0.95f, (float)(Sc - 1 - s));
    wvec[t] = v;
    __shared__ float red[128];
    red[t] = v; __syncthreads();
    for (int st = 64; st; st >>= 1) { if (t < st) red[t] += red[t + st]; __syncthreads(); }
    if (t == 0) wsum[0] = red[0];
}

__global__ __launch_bounds__(256) void phi2_f32(
    const float* __restrict__ z, float* __restrict__ feat, bf16* __restrict__ featb)
{
    const int f = blockIdx.x * 256 + threadIdx.x;
    const int t = blockIdx.y;
    if (f >= FPOLY) return;
    const float* zr = z + (size_t)t * 64;
    float v;
    if (f < 64) v = zr[f];
    else { int i = (f - 64) >> 6, j = (f - 64) & 63; v = zr[i] * zr[j] * 0.125f; }
    feat[(size_t)t * FPOLY + f] = v;
    featb[(size_t)t * FPOLY + f] = (bf16)v;
}

__global__ __launch_bounds__(256) void phi2_bf16(
    const float* __restrict__ z, bf16* __restrict__ feat)
{
    const int f = blockIdx.x * 256 + threadIdx.x;
    const int t = blockIdx.y;
    if (f >= FPOLY) return;
    const float* zr = z + (size_t)t * 64;
    float v;
    if (f < 64) v = zr[f];
    else { int i = (f - 64) >> 6, j = (f - 64) & 63; v = zr[i] * zr[j] * 0.125f; }
    feat[(size_t)t * FPOLY + f] = (bf16)v;
}

__global__ void dz_kernel(const float* __restrict__ dfeat, const float* __restrict__ za,
                          float* __restrict__ dz, bf16* __restrict__ dzb)
{
    const int t = blockIdx.x;
    const int k = threadIdx.x;
    const float* df = dfeat + (size_t)t * FPOLY;
    const float* z = za + (size_t)t * 64;
    float s1 = 0.f, s2 = 0.f;
    for (int j = 0; j < 64; ++j) {
        float zj = z[j];
        s1 += df[64 + k * 64 + j] * zj;
        s2 += df[64 + j * 64 + k] * zj;
    }
    float v = df[k] + 0.125f * (s1 + s2);
    dz[(size_t)t * 64 + k] = v;
    dzb[(size_t)t * 64 + k] = (bf16)v;
}

__global__ void sgate_kernel(const float* __restrict__ mg, float* __restrict__ out)
{
    out[0] = 1.f / (1.f + expf(-mg[0]));
}

// read merged [4096][5504] GEMM output: a=cols[0..2730), b=cols[2752..5482);
// write packed silu(a)*b into [4096][2752] (zero K-pad)
__global__ void swiglu_pack(const bf16* __restrict__ u, bf16* __restrict__ o)
{
    int i = blockIdx.x * 256 + threadIdx.x;
    if (i >= NTOK * FFNHP) return;
    int t = i / FFNHP, k = i % FFNHP;
    if (k >= FFNH) { o[i] = (bf16)0.f; return; }
    float a = (float)u[(size_t)t * 5504 + k];
    float b = (float)u[(size_t)t * 5504 + 2752 + k];
    o[i] = (bf16)(a / (1.f + __expf(-a)) * b);
}

// ---------------------------------------------------------------- launch
extern "C" void kernel_launch(void* const* d_in, const int* in_sizes, int n_in,
                              void* d_out, int out_size, void* d_ws, size_t ws_size,
                              hipStream_t stream)
{
    const float* x     = (const float*)d_in[0];
    const float* n1w   = (const float*)d_in[1];
    const float* n2w   = (const float*)d_in[2];
    const float* qkvw  = (const float*)d_in[3];
    const float* qnw   = (const float*)d_in[4];
    const float* knw   = (const float*)d_in[5];
    const float* gw1   = (const float*)d_in[6];
    const float* gw2   = (const float*)d_in[7];
    const float* mwk   = (const float*)d_in[8];
    const float* mw1   = (const float*)d_in[9];
    const float* mw2   = (const float*)d_in[10];
    const float* mgate = (const float*)d_in[11];
    const float* wow   = (const float*)d_in[12];
    const float* fw1   = (const float*)d_in[13];
    const float* fw2   = (const float*)d_in[14];
    const float* fw3   = (const float*)d_in[15];
    float* outp = (float*)d_out;

    char* base = (char*)d_ws;
    size_t off = 0;
    auto takeB = [&](size_t bytes) { char* p = base + off; off += (bytes + 255) & ~(size_t)255; return p; };

    // slabs (liveness-overlaid). A+E adjacent: featC4 (34MB) and ff13b (45MB) span both.
    // D+F adjacent: t1b4 (16.8MB) spans both.
    char* slabA  = takeB(22544384);  // partials / vt -> featC4(lo) -> ff13b(lo)
    char* slabE  = takeB(22544384);  // qmem fp32 -> featC4(hi) -> ff13b(hi)
    char* slabBC = takeB(16777216);  // qnb+knb -> x2 fp32
    char* slabD  = takeB(8388608);   // qmemb (st 3-7) -> t1b4(lo)
    char* slabF  = takeB(8388608);   // attnb -> t1b4(hi)
    char* slabG  = takeB(17301504);  // hb -> mw1b -> w1uT -> h2b
    float* partA = (float*)slabA;
    bf16* vt     = (bf16*)slabA;
    bf16* featC4 = (bf16*)slabA;  // 4096x4160x2 = 34.1MB (A+E)
    bf16* ff13b  = (bf16*)slabA;  // 4096x5504x2 = 45.1MB (A+E)
    float* qmem  = (float*)slabE;
    bf16* qnb = (bf16*)slabBC;    bf16* knb = (bf16*)(slabBC + 8388608);
    float* x2 = (float*)slabBC;
    bf16* qmemb = (bf16*)slabD;
    bf16* t1b4  = (bf16*)slabD;   // 4096x2048x2 = 16.8MB (D+F)
    bf16* attnb = (bf16*)slabF;
    bf16* hb = (bf16*)slabG;      bf16* mw1b = (bf16*)slabG;
    bf16* w1uT = (bf16*)slabG;    bf16* h2b = (bf16*)slabG;
    // merged qkv output (b,s,3072); dead after stage 4 -> reused as packed swiglu buf
    bf16* qkvb = (bf16*)takeB(25165824);
    bf16* ffpk = qkvb;            // 4096x2752x2 = 22.5MB <= 24MB

    // bf16 weights
    bf16* qkvwT = (bf16*)takeB(6291456);
    bf16* gw1T  = (bf16*)takeB(262144);    // 128 rows alloc / 64 real
    bf16* wowT  = (bf16*)takeB(2097152);
    bf16* mw1T  = (bf16*)takeB(17039360);
    bf16* mw2T  = (bf16*)takeB(4194304);
    bf16* fw13T = (bf16*)takeB(11272192);  // stacked: rows 0..2729=fw1, 2752..5481=fw3
    bf16* fw2T  = (bf16*)takeB(5636096);
    bf16* mw2b  = (bf16*)takeB(4194304);   // straight copy (2048,1024), fused in tconv
    bf16* mwkTb = (bf16*)takeB(262144);    // (64 real/128 alloc, 1024)
    bf16* wkuTb = (bf16*)takeB(262144);
    bf16* w2uT  = (bf16*)takeB(4194304);   // (1024, 2048)

    // fp32 misc
    float* zf    = (float*)takeB(1048576);
    float* gg1   = (float*)takeB(1048576);
    float* gamma = (float*)takeB(16384);
    float* wvec  = (float*)takeB(512);
    float* scal  = (float*)takeB(256);     // [0]=wsum [2]=sig(gate) [8..10]=invn
    float* psum  = (float*)takeB(131072);
    float* xa    = (float*)takeB(524288);
    float* va    = (float*)takeB(524288);
    float* za    = (float*)takeB(32768);
    float* featA = (float*)takeB(2129920);
    float* ua    = (float*)takeB(1048576);
    float* sua   = (float*)takeB(1048576);
    float* dpreda= (float*)takeB(524288);
    float* dua   = (float*)takeB(1048576);
    float* dfeata= (float*)takeB(2129920);
    float* dza   = (float*)takeB(32768);
    float* SA    = (float*)takeB(196608);  // 3 x 128x128 fp32
    float* CA    = (float*)takeB(196608);
    // bf16 misc
    bf16* featAb = (bf16*)takeB(1064960);
    bf16* suab   = (bf16*)takeB(524288);
    bf16* xab    = (bf16*)takeB(262144);
    bf16* duab   = (bf16*)takeB(524288);
    bf16* dpredab= (bf16*)takeB(262144);
    bf16* dzab   = (bf16*)takeB(16384);
    bf16* PT1Tb  = (bf16*)takeB(524288);   // (2048,128)
    bf16* PT2Tb  = (bf16*)takeB(262144);   // (1024,128)
    bf16* PT3Tb  = (bf16*)takeB(32768);
    bf16* duaTb  = (bf16*)takeB(524288);
    bf16* dpredaTb=(bf16*)takeB(262144);
    bf16* dzaTb  = (bf16*)takeB(32768);
    bf16* xaTb   = (bf16*)takeB(262144);
    bf16* featATb= (bf16*)takeB(1081344);  // (4224 alloc/4160 real, 128)
    bf16* suaTb  = (bf16*)takeB(524288);   // (2048, 128)
    // NS bf16
    bf16* Sb16  = (bf16*)takeB(98304);
    bf16* Cb16  = (bf16*)takeB(98304);
    bf16* FcAb  = (bf16*)takeB(98304);
    bf16* FcTAb = (bf16*)takeB(98304);

    auto gemmB = [&](int outbf, int cinbf, const bf16* A, const bf16* Bt,
                     const void* Cin, void* C, int M, int N, int K, int ldc,
                     float alpha, float beta, int act, const float* sptr) {
        dim3 grid((N + 127) / 128, M / 128);
        if (outbf && cinbf) gemm_bt<1, 1><<<grid, 256, 0, stream>>>(A, Bt, Cin, C, M, N, K, ldc, alpha, beta, act, sptr);
        else if (outbf)     gemm_bt<1, 0><<<grid, 256, 0, stream>>>(A, Bt, Cin, C, M, N, K, ldc, alpha, beta, act, sptr);
        else                gemm_bt<0, 0><<<grid, 256, 0, stream>>>(A, Bt, Cin, C, M, N, K, ldc, alpha, beta, act, sptr);
    };
    auto gemm64 = [&](const bf16* A, const bf16* Bt, const float* Cin, float* C,
                      int M, int N, int K, int ldc, const float* sptr) {
        dim3 grid(N / 64, M / 128);
        gemm_bt64<<<grid, 256, 0, stream>>>(A, Bt, Cin, C, M, N, K, ldc, sptr);
    };
    auto gdir = [&](int outbf, int cinbf, const bf16* A, const bf16* Bt,
                    const void* Cin, void* C, int M, int N, int K, int ldc,
                    float alpha, float beta, int act, const float* sptr) {
        dim3 grid((N + 127) / 128, (M + 127) / 128);
        if (outbf && cinbf)      gemm_direct<1, 1><<<grid, 256, 0, stream>>>(A, Bt, Cin, C, M, N, K, ldc, alpha, beta, act, sptr);
        else if (outbf)          gemm_direct<1, 0><<<grid, 256, 0, stream>>>(A, Bt, Cin, C, M, N, K, ldc, alpha, beta, act, sptr);
        else if (cinbf)          gemm_direct<0, 1><<<grid, 256, 0, stream>>>(A, Bt, Cin, C, M, N, K, ldc, alpha, beta, act, sptr);
        else                     gemm_direct<0, 0><<<grid, 256, 0, stream>>>(A, Bt, Cin, C, M, N, K, ldc, alpha, beta, act, sptr);
    };
    auto skp = [&](const bf16* A, const bf16* Bt, float* out,
                   int M, int N, int K, int KC) {
        int SK = (K + KC - 1) / KC;
        gemm_skp<<<dim3((N + 127) / 128, (M + 127) / 128, SK), 256, 0, stream>>>(A, Bt, partA, M, N, K, KC);
        int MN = M * N;
        skred<<<(MN + 255) / 256, 256, 0, stream>>>(partA, out, SK, MN);
    };
    auto tconv = [&](const float* W, bf16* Wt, int K, int N, int Kpad, bf16* Wc) {
        tconv_kernel<<<dim3((Kpad + 31) / 32, (N + 31) / 32), 256, 0, stream>>>(W, Wt, K, N, Kpad, Wc);
    };

    // 0. weight converts (mw1 tconv deferred until hb is dead; mw2b fused here)
    tconv(qkvw, qkvwT, Dc, 3 * Dc, Dc, nullptr);
    tconv(gw1, gw1T, Dc, GGH, Dc, nullptr);
    tconv(wow, wowT, Dc, Dc, Dc, nullptr);
    tconv(mw2, mw2T, MHID, Dc, MHID, mw2b);
    tconv(fw1, fw13T, Dc, FFNH, Dc, nullptr);
    tconv(fw3, fw13T + (size_t)2752 * Dc, Dc, FFNH, Dc, nullptr);
    tconv(fw2, fw2T, FFNH, Dc, FFNHP, nullptr);
    tconv(mwk, mwkTb, Dc, HDc, Dc, nullptr);
    sgate_kernel<<<1, 1, 0, stream>>>(mgate, scal + 2);

    // 1-2. rmsnorm, merged qkv, q/k norm+rope, gamma; then mw1 -> mw1T + mw1b (hb dead)
    rms_rows<<<NTOK, 256, 0, stream>>>(x, n1w, hb, Dc);
    gemmB(1, 0, hb, qkvwT, nullptr, qkvb, NTOK, 3 * Dc, Dc, 3 * Dc, 1.f, 0.f, 0, nullptr);
    snr_qk<<<dim3(Sc / 4, 32, Bc), 256, 0, stream>>>(qkvb, qnw, knw, qnb, knb);
    skp(hb, gw1T, gg1, NTOK, GGH, Dc, 256);        // SK=4, 128 blocks
    gamma_kernel<<<NTOK / 4, 256, 0, stream>>>(gg1, gw2, gamma);
    tconv(mw1, mw1T, FPOLY, MHID, FPOLY, mw1b);    // hb dead -> slabG reusable

    // 3. V transpose, q_mem (+qmemb), attention (cooperative-LDS, XCD-clustered)
    vtrans_kernel<<<dim3(Sc / 32, 2, Bc * Hc), 256, 0, stream>>>(qkvb, vt);
    kpsum_kernel<<<dim3(Bc * Hc, 16), 64, 0, stream>>>(knb, psum);
    qmem2_kernel<<<dim3(Bc * Hc, 16), 64, 0, stream>>>(qnb, knb, gamma, psum, qmem, qmemb);
    attn_mfma<<<dim3(512), 256, 0, stream>>>(qnb, knb, vt, attnb);

    // 4. actives (vt dead -> slabA reusable as partials)
    gather_active<<<NACT, 256, 0, stream>>>(qmem, qkvb, xa, xab, va);
    wvec_kernel<<<1, 128, 0, stream>>>(gamma, wvec, scal);

    // 5. gradient chain (128 active tokens) -- split-K MFMA, fused reduce epilogues
    skp(xab, mwkTb, za, NACT, HDc, Dc, 64);                         // SK=16
    phi2_f32<<<dim3((FPOLY + 255) / 256, NACT), 256, 0, stream>>>(za, featA, featAb);
    gemm_skp<<<dim3(16, 1, 15), 256, 0, stream>>>(featAb, mw1T, partA, NACT, MHID, FPOLY, 288);
    skred_silu<<<1024, 256, 0, stream>>>(partA, ua, sua, suab);
    gemm_skp<<<dim3(8, 1, 16), 256, 0, stream>>>(suab, mw2T, partA, NACT, Dc, MHID, 128);
    skred_dpred<<<512, 256, 0, stream>>>(partA, va, wvec, scal, dpreda, dpredab);
    gemm_skp<<<dim3(16, 1, 8), 256, 0, stream>>>(dpredab, mw2b, partA, NACT, MHID, Dc, 128);
    skred_dsilu<<<1024, 256, 0, stream>>>(partA, ua, dua, duab);
    skp(duab, mw1b, dfeata, NACT, FPOLY, MHID, 256);                // SK=8, 264 blocks
    dz_kernel<<<NACT, 64, 0, stream>>>(dfeata, za, dza, dzab);

    // transposed bf16 copies (6-in-1)
    tconv6_kernel<<<dim3(4, 130, 6), 256, 0, stream>>>(
        dua, dpreda, dza, xa, featA, sua,
        duaTb, dpredaTb, dzaTb, xaTb, featATb, suaTb);

    // 6. Newton-Schulz: batched grams + fused 5-iter chain + batched P5
    gram_trick<<<1, 256, 0, stream>>>(za, SA);
    gram_bat<<<dim3(32, 5), 256, 0, stream>>>(suab, xab, duab, dpredab, dzab, partA);
    gram_red<<<320, 256, 0, stream>>>(partA, SA, CA);
    ns_norm_kernel<<<3, 256, 0, stream>>>(SA, CA, Sb16, Cb16, scal + 8);
    ns_fused<<<3, 256, 0, stream>>>(Sb16, Cb16, FcAb, FcTAb);
    gdir3_kernel<<<dim3(1, 16, 3), 256, 0, stream>>>(
        duaTb, dpredaTb, dzaTb, FcTAb, PT1Tb, PT2Tb, PT3Tb, scal + 8);

    // wkuT = 0.999*mwkT - 0.01*PT3T@xa
    gdir(1, 1, PT3Tb, xaTb, mwkTb, wkuTb, HDc, Dc, 128, Dc, -0.01f, 0.999f, 0, nullptr);
    //   w1uT = 0.999*mw1T - 0.01*PT1T@featA   (mw1b dead -> slabG reuse)
    gemmB(1, 1, PT1Tb, featATb, mw1T, w1uT, MHID, FPOLY, 128, FPOLY, -0.01f, 0.999f, 0, nullptr);
    //   w2uT = 0.999*mw2T - 0.01*PT2T@sua
    gemmB(1, 1, PT2Tb, suaTb, mw2T, w2uT, Dc, MHID, 128, MHID, -0.01f, 0.999f, 0, nullptr);

    // 7. x2 = x + attn@wo (128x64 tiles); zf = qmem@wku via split-K
    gemm64(attnb, wowT, x, x2, NTOK, Dc, Dc, Dc, nullptr);
    skp(qmemb, wkuTb, zf, NTOK, HDc, Dc, 128);                      // SK=8

    // 8. memory forward, de-chunked: M=4096 in one pass
    phi2_bf16<<<dim3((FPOLY + 255) / 256, NTOK), 256, 0, stream>>>(zf, featC4);
    gemmB(1, 0, featC4, w1uT, nullptr, t1b4, NTOK, MHID, FPOLY, MHID, 1.f, 0.f, 1, nullptr);
    gemm64(t1b4, w2uT, x2, x2, NTOK, Dc, MHID, Dc, scal + 2);

    // 9. FFN (swiglu): merged fw1+fw3 GEMM, fused pack, 128x64-tile fw2
    rms_rows<<<NTOK, 256, 0, stream>>>(x2, n2w, h2b, Dc);
    gemmB(1, 0, h2b, fw13T, nullptr, ff13b, NTOK, 5482, Dc, 5504, 1.f, 0.f, 0, nullptr);
    swiglu_pack<<<(NTOK * FFNHP + 255) / 256, 256, 0, stream>>>(ff13b, ffpk);
    gemm64(ffpk, fw2T, x2, outp, NTOK, Dc, FFNHP, Dc, nullptr);
}